// Round 1
// baseline (4702.671 us; speedup 1.0000x reference)
//
#include <hip/hip_runtime.h>
#include <hip/hip_bf16.h>

static constexpr int Bb  = 2;
static constexpr int Tt  = 2048;
static constexpr int Cc  = 1024;
static constexpr int Hh  = 16;
static constexpr int HDi = 64;
static constexpr int HID = 1365;
static constexpr int Mm  = Bb * Tt;   // 4096 rows

// ---------------- LayerNorm: one row (C=1024) per block, 256 threads ----------------
__global__ __launch_bounds__(256) void ln_k(const float* __restrict__ x,
                                            const float* __restrict__ g,
                                            const float* __restrict__ b,
                                            float* __restrict__ y) {
    int row = blockIdx.x;
    int tid = threadIdx.x;
    const float4* xr = (const float4*)(x + (size_t)row * Cc);
    float4 v = xr[tid];
    float s  = v.x + v.y + v.z + v.w;
    float ss = v.x*v.x + v.y*v.y + v.z*v.z + v.w*v.w;
    __shared__ float rs[256], rq[256];
    rs[tid] = s; rq[tid] = ss;
    __syncthreads();
    for (int o = 128; o > 0; o >>= 1) {
        if (tid < o) { rs[tid] += rs[tid+o]; rq[tid] += rq[tid+o]; }
        __syncthreads();
    }
    float mean = rs[0] * (1.f/Cc);
    float var  = rq[0] * (1.f/Cc) - mean*mean;
    float inv  = rsqrtf(var + 1e-5f);
    float4 gv = ((const float4*)g)[tid];
    float4 bv = ((const float4*)b)[tid];
    float4 o4;
    o4.x = (v.x-mean)*inv*gv.x + bv.x;
    o4.y = (v.y-mean)*inv*gv.y + bv.y;
    o4.z = (v.z-mean)*inv*gv.z + bv.z;
    o4.w = (v.w-mean)*inv*gv.w + bv.w;
    ((float4*)(y + (size_t)row * Cc))[tid] = o4;
}

// ---------------- mean over heads of rel_table -> mr[4095] ----------------
__global__ __launch_bounds__(256) void meanrel_k(const float* __restrict__ rel,
                                                 float* __restrict__ mr) {
    int j = blockIdx.x * 256 + threadIdx.x;
    if (j < 2*Tt - 1) {
        float s = 0.f;
        #pragma unroll
        for (int h = 0; h < Hh; h++) s += rel[(size_t)h * (2*Tt - 1) + j];
        mr[j] = s * (1.f/Hh);
    }
}

// ---------------- generic f32 GEMM: out[M,N] = A[M,K] @ W[N,K]^T + bias (+res) ----------------
// 64x64 tile, BK=16, 256 threads, 4x4 micro-tile each. M must be multiple of 64 (always 4096).
__global__ __launch_bounds__(256) void gemm_k(const float* __restrict__ A,
                                              const float* __restrict__ W,
                                              const float* __restrict__ bias,
                                              const float* __restrict__ res,
                                              float* __restrict__ out,
                                              int N, int K) {
    __shared__ float As[16][65];
    __shared__ float Ws[16][65];
    int bm = blockIdx.y * 64;
    int bn = blockIdx.x * 64;
    int tid = threadIdx.x;
    int tr = tid >> 4, tc = tid & 15;
    float acc[4][4] = {};
    for (int k0 = 0; k0 < K; k0 += 16) {
        int r  = tid >> 4;
        int kk = tid & 15;
        int gk = k0 + kk;
        bool kin = gk < K;
        #pragma unroll
        for (int l = 0; l < 4; l++) {
            int rr = r + l*16;
            As[kk][rr] = kin ? A[(size_t)(bm + rr) * K + gk] : 0.f;
            int wr = bn + rr;
            Ws[kk][rr] = (kin && wr < N) ? W[(size_t)wr * K + gk] : 0.f;
        }
        __syncthreads();
        #pragma unroll
        for (int k = 0; k < 16; k++) {
            float a[4], w[4];
            #pragma unroll
            for (int i = 0; i < 4; i++) a[i] = As[k][tr + i*16];
            #pragma unroll
            for (int j = 0; j < 4; j++) w[j] = Ws[k][tc + j*16];
            #pragma unroll
            for (int i = 0; i < 4; i++)
                #pragma unroll
                for (int j = 0; j < 4; j++)
                    acc[i][j] += a[i] * w[j];
        }
        __syncthreads();
    }
    #pragma unroll
    for (int i = 0; i < 4; i++) {
        int rr = bm + tr + i*16;
        #pragma unroll
        for (int j = 0; j < 4; j++) {
            int cc = bn + tc + j*16;
            if (cc < N) {
                float v = acc[i][j];
                if (bias) v += bias[cc];
                if (res)  v += res[(size_t)rr * N + cc];
                out[(size_t)rr * N + cc] = v;
            }
        }
    }
}

// ---------------- fused SwiGLU GEMM: out = silu(A@W1^T) * (A@W2^T), N=HID, K=C ----------------
__global__ __launch_bounds__(256) void swiglu_k(const float* __restrict__ A,
                                                const float* __restrict__ W1,
                                                const float* __restrict__ W2,
                                                float* __restrict__ out,
                                                int N, int K) {
    __shared__ float As[16][65];
    __shared__ float W1s[16][65];
    __shared__ float W2s[16][65];
    int bm = blockIdx.y * 64;
    int bn = blockIdx.x * 64;
    int tid = threadIdx.x;
    int tr = tid >> 4, tc = tid & 15;
    float acc1[4][4] = {};
    float acc2[4][4] = {};
    for (int k0 = 0; k0 < K; k0 += 16) {
        int r  = tid >> 4;
        int kk = tid & 15;
        int gk = k0 + kk;
        bool kin = gk < K;
        #pragma unroll
        for (int l = 0; l < 4; l++) {
            int rr = r + l*16;
            As[kk][rr] = kin ? A[(size_t)(bm + rr) * K + gk] : 0.f;
            int wr = bn + rr;
            bool win = kin && (wr < N);
            W1s[kk][rr] = win ? W1[(size_t)wr * K + gk] : 0.f;
            W2s[kk][rr] = win ? W2[(size_t)wr * K + gk] : 0.f;
        }
        __syncthreads();
        #pragma unroll
        for (int k = 0; k < 16; k++) {
            float a[4], w1[4], w2[4];
            #pragma unroll
            for (int i = 0; i < 4; i++) a[i] = As[k][tr + i*16];
            #pragma unroll
            for (int j = 0; j < 4; j++) { w1[j] = W1s[k][tc + j*16]; w2[j] = W2s[k][tc + j*16]; }
            #pragma unroll
            for (int i = 0; i < 4; i++)
                #pragma unroll
                for (int j = 0; j < 4; j++) {
                    acc1[i][j] += a[i] * w1[j];
                    acc2[i][j] += a[i] * w2[j];
                }
        }
        __syncthreads();
    }
    #pragma unroll
    for (int i = 0; i < 4; i++) {
        int rr = bm + tr + i*16;
        #pragma unroll
        for (int j = 0; j < 4; j++) {
            int cc = bn + tc + j*16;
            if (cc < N) {
                float a = acc1[i][j];
                float sig = 1.f / (1.f + __expf(-a));
                out[(size_t)rr * N + cc] = a * sig * acc2[i][j];
            }
        }
    }
}

// ---------------- attention: 4 q-rows per block for one (b,h) ----------------
// qp/kp/vp layout [B,T,C] with head h at col offset h*64. Scores in LDS, 2-pass softmax.
__global__ __launch_bounds__(256) void attn_k(const float* __restrict__ qp,
                                              const float* __restrict__ kp,
                                              const float* __restrict__ vp,
                                              const float* __restrict__ mr,
                                              float* __restrict__ ctx) {
    int blk  = blockIdx.x;                 // B*H*(T/4)
    int qblk = blk & 511;                  // T/4 = 512
    int h    = (blk >> 9) & 15;
    int b    = blk >> 13;
    int q0   = qblk * 4;
    int tid  = threadIdx.x;

    __shared__ float qs[4][64];
    __shared__ float s[4][Tt];
    __shared__ float red[256];

    const size_t bc = (size_t)b * Tt * Cc + (size_t)h * HDi;

    { // load 4 q rows, pre-scaled by 1/sqrt(64)
        int qi = tid >> 6, d = tid & 63;
        qs[qi][d] = qp[bc + (size_t)(q0 + qi) * Cc + d] * 0.125f;
    }
    __syncthreads();

    // scores: each thread handles 8 k-rows, 4 q-dots each
    for (int k = tid; k < Tt; k += 256) {
        const float4* k4 = (const float4*)(kp + bc + (size_t)k * Cc);
        float acc[4] = {0.f, 0.f, 0.f, 0.f};
        #pragma unroll
        for (int d4 = 0; d4 < 16; d4++) {
            float4 kv = k4[d4];
            #pragma unroll
            for (int q = 0; q < 4; q++) {
                float4 qv = ((const float4*)qs[q])[d4];
                acc[q] += qv.x*kv.x + qv.y*kv.y + qv.z*kv.z + qv.w*kv.w;
            }
        }
        #pragma unroll
        for (int q = 0; q < 4; q++)
            s[q][k] = acc[q] + mr[q0 + q - k + (Tt - 1)];
    }
    __syncthreads();

    // softmax per q row
    float inv_den[4];
    for (int q = 0; q < 4; q++) {
        float m = -1e30f;
        for (int k = tid; k < Tt; k += 256) m = fmaxf(m, s[q][k]);
        red[tid] = m; __syncthreads();
        for (int o = 128; o > 0; o >>= 1) {
            if (tid < o) red[tid] = fmaxf(red[tid], red[tid+o]);
            __syncthreads();
        }
        m = red[0];
        __syncthreads();
        float sum = 0.f;
        for (int k = tid; k < Tt; k += 256) {
            float e = __expf(s[q][k] - m);
            s[q][k] = e;
            sum += e;
        }
        red[tid] = sum; __syncthreads();
        for (int o = 128; o > 0; o >>= 1) {
            if (tid < o) red[tid] += red[tid+o];
            __syncthreads();
        }
        inv_den[q] = 1.f / red[0];
        __syncthreads();
    }

    // PV: d = tid%64, 4-way partition over k
    {
        int d = tid & 63, part = tid >> 6;
        float acc[4] = {0.f, 0.f, 0.f, 0.f};
        const float* vbase = vp + bc + d;
        int kend = (part + 1) * 512;
        for (int k = part * 512; k < kend; k++) {
            float v = vbase[(size_t)k * Cc];
            #pragma unroll
            for (int q = 0; q < 4; q++) acc[q] += s[q][k] * v;
        }
        #pragma unroll
        for (int q = 0; q < 4; q++) {
            red[tid] = acc[q]; __syncthreads();
            if (tid < 64) {
                float v = (red[tid] + red[tid+64] + red[tid+128] + red[tid+192]) * inv_den[q];
                ctx[bc + (size_t)(q0 + q) * Cc + tid] = v;
            }
            __syncthreads();
        }
    }
}

extern "C" void kernel_launch(void* const* d_in, const int* in_sizes, int n_in,
                              void* d_out, int out_size, void* d_ws, size_t ws_size,
                              hipStream_t stream) {
    const float* query     = (const float*)d_in[0];
    const float* key       = (const float*)d_in[1];
    const float* g_q       = (const float*)d_in[2];
    const float* b_q       = (const float*)d_in[3];
    const float* g_k       = (const float*)d_in[4];
    const float* b_k       = (const float*)d_in[5];
    const float* in_proj_w = (const float*)d_in[6];
    const float* in_proj_b = (const float*)d_in[7];
    const float* out_w     = (const float*)d_in[8];
    const float* out_b     = (const float*)d_in[9];
    const float* proj_w    = (const float*)d_in[10];
    const float* proj_b    = (const float*)d_in[11];
    const float* rel_table = (const float*)d_in[12];
    const float* g_ffn     = (const float*)d_in[13];
    const float* b_ffn     = (const float*)d_in[14];
    const float* w1        = (const float*)d_in[15];
    const float* w2        = (const float*)d_in[16];
    const float* w3        = (const float*)d_in[17];
    const float* g_out     = (const float*)d_in[18];
    const float* b_out     = (const float*)d_in[19];

    float* ws = (float*)d_ws;
    const size_t MC = (size_t)Mm * Cc;           // 4096*1024
    float* qn = ws;                               // LN(query)
    float* kn = qn + MC;                          // LN(key)
    float* qp = kn + MC;                          // q projection
    float* kp = qp + MC;                          // k projection
    float* vp = kp + MC;                          // v projection
    float* mr = vp + MC;                          // mean rel bias [4095] (rounded 4096)
    float* gf = mr + 4096;                        // SwiGLU gate output [M, HID]
    // reuse after earlier stages complete:
    float* ctx = qn;                              // attention output
    float* t1  = kn;                              // ctx @ out_w^T + out_b
    float* x   = qp;                              // residual stream
    float* h   = kp;                              // LN(x) for FFN
    float* x2  = vp;                              // x + FFN

    dim3 blk(256);
    ln_k<<<Mm, blk, 0, stream>>>(query, g_q, b_q, qn);
    ln_k<<<Mm, blk, 0, stream>>>(key,   g_k, b_k, kn);
    meanrel_k<<<16, blk, 0, stream>>>(rel_table, mr);

    dim3 g1(Cc/64, Mm/64);
    gemm_k<<<g1, blk, 0, stream>>>(qn, in_proj_w,                     in_proj_b,        nullptr, qp, Cc, Cc);
    gemm_k<<<g1, blk, 0, stream>>>(kn, in_proj_w + (size_t)Cc*Cc,     in_proj_b + Cc,   nullptr, kp, Cc, Cc);
    gemm_k<<<g1, blk, 0, stream>>>(kn, in_proj_w + (size_t)2*Cc*Cc,   in_proj_b + 2*Cc, nullptr, vp, Cc, Cc);

    attn_k<<<Bb*Hh*(Tt/4), blk, 0, stream>>>(qp, kp, vp, mr, ctx);

    gemm_k<<<g1, blk, 0, stream>>>(ctx, out_w,  out_b,  nullptr, t1, Cc, Cc);
    gemm_k<<<g1, blk, 0, stream>>>(t1,  proj_w, proj_b, query,   x,  Cc, Cc);

    ln_k<<<Mm, blk, 0, stream>>>(x, g_ffn, b_ffn, h);
    dim3 g2((HID + 63)/64, Mm/64);
    swiglu_k<<<g2, blk, 0, stream>>>(h, w1, w2, gf, HID, Cc);
    dim3 g3(Cc/64, Mm/64);
    gemm_k<<<g3, blk, 0, stream>>>(gf, w3, nullptr, x, x2, Cc, HID);

    ln_k<<<Mm, blk, 0, stream>>>(x2, g_out, b_out, (float*)d_out);
}

// Round 2
// 1985.107 us; speedup vs baseline: 2.3690x; 2.3690x over previous
//
#include <hip/hip_runtime.h>
#include <hip/hip_bf16.h>

static constexpr int Bb  = 2;
static constexpr int Tt  = 2048;
static constexpr int Cc  = 1024;
static constexpr int Hh  = 16;
static constexpr int HDi = 64;
static constexpr int HID = 1365;
static constexpr int Mm  = Bb * Tt;   // 4096 rows

typedef __attribute__((ext_vector_type(8))) short bf16x8;
typedef __attribute__((ext_vector_type(4))) float f32x4;

__device__ inline unsigned short f2bf(float f) {
    unsigned u = __builtin_bit_cast(unsigned, f);
    u += 0x7fffu + ((u >> 16) & 1u);
    return (unsigned short)(u >> 16);
}
__device__ inline unsigned pk2(float a, float b) {
    return (unsigned)f2bf(a) | ((unsigned)f2bf(b) << 16);
}

// ---------------- LayerNorm: one row (C=1024) per block, 256 threads ----------------
__global__ __launch_bounds__(256) void ln_k(const float* __restrict__ x,
                                            const float* __restrict__ g,
                                            const float* __restrict__ b,
                                            float* __restrict__ y) {
    int row = blockIdx.x;
    int tid = threadIdx.x;
    const float4* xr = (const float4*)(x + (size_t)row * Cc);
    float4 v = xr[tid];
    float s  = v.x + v.y + v.z + v.w;
    float ss = v.x*v.x + v.y*v.y + v.z*v.z + v.w*v.w;
    __shared__ float rs[256], rq[256];
    rs[tid] = s; rq[tid] = ss;
    __syncthreads();
    for (int o = 128; o > 0; o >>= 1) {
        if (tid < o) { rs[tid] += rs[tid+o]; rq[tid] += rq[tid+o]; }
        __syncthreads();
    }
    float mean = rs[0] * (1.f/Cc);
    float var  = rq[0] * (1.f/Cc) - mean*mean;
    float inv  = rsqrtf(var + 1e-5f);
    float4 gv = ((const float4*)g)[tid];
    float4 bv = ((const float4*)b)[tid];
    float4 o4;
    o4.x = (v.x-mean)*inv*gv.x + bv.x;
    o4.y = (v.y-mean)*inv*gv.y + bv.y;
    o4.z = (v.z-mean)*inv*gv.z + bv.z;
    o4.w = (v.w-mean)*inv*gv.w + bv.w;
    ((float4*)(y + (size_t)row * Cc))[tid] = o4;
}

// ---------------- mean over heads of rel_table -> mr[4095] ----------------
__global__ __launch_bounds__(256) void meanrel_k(const float* __restrict__ rel,
                                                 float* __restrict__ mr) {
    int j = blockIdx.x * 256 + threadIdx.x;
    if (j < 2*Tt - 1) {
        float s = 0.f;
        #pragma unroll
        for (int h = 0; h < Hh; h++) s += rel[(size_t)h * (2*Tt - 1) + j];
        mr[j] = s * (1.f/Hh);
    }
}

// ---------------- generic f32 GEMM: out[M,N] = A[M,K] @ W[N,K]^T + bias (+res) ----------------
__global__ __launch_bounds__(256) void gemm_k(const float* __restrict__ A,
                                              const float* __restrict__ W,
                                              const float* __restrict__ bias,
                                              const float* __restrict__ res,
                                              float* __restrict__ out,
                                              int N, int K) {
    __shared__ float As[16][65];
    __shared__ float Ws[16][65];
    int bm = blockIdx.y * 64;
    int bn = blockIdx.x * 64;
    int tid = threadIdx.x;
    int tr = tid >> 4, tc = tid & 15;
    float acc[4][4] = {};
    for (int k0 = 0; k0 < K; k0 += 16) {
        int r  = tid >> 4;
        int kk = tid & 15;
        int gk = k0 + kk;
        bool kin = gk < K;
        #pragma unroll
        for (int l = 0; l < 4; l++) {
            int rr = r + l*16;
            As[kk][rr] = kin ? A[(size_t)(bm + rr) * K + gk] : 0.f;
            int wr = bn + rr;
            Ws[kk][rr] = (kin && wr < N) ? W[(size_t)wr * K + gk] : 0.f;
        }
        __syncthreads();
        #pragma unroll
        for (int k = 0; k < 16; k++) {
            float a[4], w[4];
            #pragma unroll
            for (int i = 0; i < 4; i++) a[i] = As[k][tr + i*16];
            #pragma unroll
            for (int j = 0; j < 4; j++) w[j] = Ws[k][tc + j*16];
            #pragma unroll
            for (int i = 0; i < 4; i++)
                #pragma unroll
                for (int j = 0; j < 4; j++)
                    acc[i][j] += a[i] * w[j];
        }
        __syncthreads();
    }
    #pragma unroll
    for (int i = 0; i < 4; i++) {
        int rr = bm + tr + i*16;
        #pragma unroll
        for (int j = 0; j < 4; j++) {
            int cc = bn + tc + j*16;
            if (cc < N) {
                float v = acc[i][j];
                if (bias) v += bias[cc];
                if (res)  v += res[(size_t)rr * N + cc];
                out[(size_t)rr * N + cc] = v;
            }
        }
    }
}

// ---------------- fused SwiGLU GEMM: out = silu(A@W1^T) * (A@W2^T) ----------------
__global__ __launch_bounds__(256) void swiglu_k(const float* __restrict__ A,
                                                const float* __restrict__ W1,
                                                const float* __restrict__ W2,
                                                float* __restrict__ out,
                                                int N, int K) {
    __shared__ float As[16][65];
    __shared__ float W1s[16][65];
    __shared__ float W2s[16][65];
    int bm = blockIdx.y * 64;
    int bn = blockIdx.x * 64;
    int tid = threadIdx.x;
    int tr = tid >> 4, tc = tid & 15;
    float acc1[4][4] = {};
    float acc2[4][4] = {};
    for (int k0 = 0; k0 < K; k0 += 16) {
        int r  = tid >> 4;
        int kk = tid & 15;
        int gk = k0 + kk;
        bool kin = gk < K;
        #pragma unroll
        for (int l = 0; l < 4; l++) {
            int rr = r + l*16;
            As[kk][rr] = kin ? A[(size_t)(bm + rr) * K + gk] : 0.f;
            int wr = bn + rr;
            bool win = kin && (wr < N);
            W1s[kk][rr] = win ? W1[(size_t)wr * K + gk] : 0.f;
            W2s[kk][rr] = win ? W2[(size_t)wr * K + gk] : 0.f;
        }
        __syncthreads();
        #pragma unroll
        for (int k = 0; k < 16; k++) {
            float a[4], w1[4], w2[4];
            #pragma unroll
            for (int i = 0; i < 4; i++) a[i] = As[k][tr + i*16];
            #pragma unroll
            for (int j = 0; j < 4; j++) { w1[j] = W1s[k][tc + j*16]; w2[j] = W2s[k][tc + j*16]; }
            #pragma unroll
            for (int i = 0; i < 4; i++)
                #pragma unroll
                for (int j = 0; j < 4; j++) {
                    acc1[i][j] += a[i] * w1[j];
                    acc2[i][j] += a[i] * w2[j];
                }
        }
        __syncthreads();
    }
    #pragma unroll
    for (int i = 0; i < 4; i++) {
        int rr = bm + tr + i*16;
        #pragma unroll
        for (int j = 0; j < 4; j++) {
            int cc = bn + tc + j*16;
            if (cc < N) {
                float a = acc1[i][j];
                float sig = 1.f / (1.f + __expf(-a));
                out[(size_t)rr * N + cc] = a * sig * acc2[i][j];
            }
        }
    }
}

// ---------------- V transpose: vp[B,T,C](head h cols) -> vt[B*H, 64, T] ----------------
__global__ __launch_bounds__(256) void vt_k(const float* __restrict__ vp,
                                            float* __restrict__ vt) {
    int blk = blockIdx.x;             // bh*32 + kb
    int bh = blk >> 5, kb = blk & 31;
    int b = bh >> 4, h = bh & 15;
    __shared__ float t[64][65];
    int tid = threadIdx.x;
    size_t bc = (size_t)b*Tt*Cc + (size_t)h*HDi;
    #pragma unroll
    for (int i = 0; i < 16; i++) {
        int e = tid + i*256;
        int k = e >> 6, d = e & 63;
        t[d][k] = vp[bc + (size_t)(kb*64 + k)*Cc + d];
    }
    __syncthreads();
    #pragma unroll
    for (int i = 0; i < 16; i++) {
        int e = tid + i*256;
        int d = e >> 6, k = e & 63;
        vt[((size_t)bh*64 + d)*Tt + kb*64 + k] = t[d][k];
    }
}

// ---------------- MFMA flash attention ----------------
// grid: B*H*32 blocks; block: 256 thr (4 waves), each wave owns 16 q rows.
// Kt LDS [k][d] bf16 swizzled; Vts LDS [d][k] bf16 swizzled; P per-wave LDS.
__global__ __launch_bounds__(256) void fattn_k(const float* __restrict__ qp,
                                               const float* __restrict__ kp,
                                               const float* __restrict__ vt,
                                               const float* __restrict__ mr,
                                               float* __restrict__ ctx) {
    __shared__ unsigned short Kt[4096];        // 64x64 bf16
    __shared__ unsigned short Vts[4096];       // 64x64 bf16 (d-major)
    __shared__ unsigned short Pt[4][1024];     // per-wave 16x64 bf16
    __shared__ float mrw[2112];                // rel-bias window

    int blk = blockIdx.x;
    int qt = blk & 31, h = (blk >> 5) & 15, b = blk >> 9;
    int q0 = qt * 64;
    int tid = threadIdx.x, w = tid >> 6, l = tid & 63;
    int lr = l & 15, lh = l >> 4;
    size_t bc = (size_t)b * Tt * Cc + (size_t)h * HDi;

    for (int i = tid; i < 2111; i += 256) mrw[i] = mr[q0 + i];

    // Q fragments in registers, pre-scaled by 1/8
    bf16x8 qa[2];
    {
        const float* qrow = qp + bc + (size_t)(q0 + w*16 + lr) * Cc;
        #pragma unroll
        for (int c = 0; c < 2; c++) {
            const float* p = qrow + c*32 + lh*8;
            float4 x0 = *(const float4*)p;
            float4 x1 = *(const float4*)(p + 4);
            bf16x8 q8;
            q8[0]=(short)f2bf(x0.x*0.125f); q8[1]=(short)f2bf(x0.y*0.125f);
            q8[2]=(short)f2bf(x0.z*0.125f); q8[3]=(short)f2bf(x0.w*0.125f);
            q8[4]=(short)f2bf(x1.x*0.125f); q8[5]=(short)f2bf(x1.y*0.125f);
            q8[6]=(short)f2bf(x1.z*0.125f); q8[7]=(short)f2bf(x1.w*0.125f);
            qa[c] = q8;
        }
    }

    f32x4 oacc[4];
    float mrun[4], lrun[4];
    #pragma unroll
    for (int f = 0; f < 4; f++)
        #pragma unroll
        for (int r = 0; r < 4; r++) oacc[f][r] = 0.f;
    #pragma unroll
    for (int r = 0; r < 4; r++) { mrun[r] = -1e30f; lrun[r] = 0.f; }

    int sr  = tid >> 2;           // staging row 0..63
    int sd0 = (tid & 3) << 4;     // 0,16,32,48
    int ssw = (sr & 7) << 4;
    const float* vtbase = vt + ((size_t)(b*Hh + h) * HDi + sr) * Tt;

    for (int kt = 0; kt < 32; kt++) {
        __syncthreads();
        { // stage K tile
            const float* kr = kp + bc + (size_t)(kt*64 + sr) * Cc + sd0;
            float4 a0 = ((const float4*)kr)[0];
            float4 a1 = ((const float4*)kr)[1];
            float4 a2 = ((const float4*)kr)[2];
            float4 a3 = ((const float4*)kr)[3];
            uint4 w0 = { pk2(a0.x,a0.y), pk2(a0.z,a0.w), pk2(a1.x,a1.y), pk2(a1.z,a1.w) };
            uint4 w1 = { pk2(a2.x,a2.y), pk2(a2.z,a2.w), pk2(a3.x,a3.y), pk2(a3.z,a3.w) };
            int base = sr*128 + sd0*2;
            *(uint4*)((char*)Kt + ((base     ) ^ ssw)) = w0;
            *(uint4*)((char*)Kt + ((base + 16) ^ ssw)) = w1;
            // stage V tile (already d-major in global)
            const float* vr = vtbase + kt*64 + sd0;
            float4 b0 = ((const float4*)vr)[0];
            float4 b1 = ((const float4*)vr)[1];
            float4 b2 = ((const float4*)vr)[2];
            float4 b3 = ((const float4*)vr)[3];
            uint4 v0 = { pk2(b0.x,b0.y), pk2(b0.z,b0.w), pk2(b1.x,b1.y), pk2(b1.z,b1.w) };
            uint4 v1 = { pk2(b2.x,b2.y), pk2(b2.z,b2.w), pk2(b3.x,b3.y), pk2(b3.z,b3.w) };
            *(uint4*)((char*)Vts + ((base     ) ^ ssw)) = v0;
            *(uint4*)((char*)Vts + ((base + 16) ^ ssw)) = v1;
        }
        __syncthreads();

        // QK^T: S[16q x 64k] per wave
        f32x4 s[4];
        #pragma unroll
        for (int f = 0; f < 4; f++)
            #pragma unroll
            for (int r = 0; r < 4; r++) s[f][r] = 0.f;
        #pragma unroll
        for (int f = 0; f < 4; f++) {
            int kl = f*16 + lr;
            int ksw = (kl & 7) << 4;
            #pragma unroll
            for (int c = 0; c < 2; c++) {
                int off = (kl*128 + (c*32 + lh*8)*2) ^ ksw;
                bf16x8 kb = *(const bf16x8*)((const char*)Kt + off);
                s[f] = __builtin_amdgcn_mfma_f32_16x16x32_bf16(qa[c], kb, s[f], 0, 0, 0);
            }
        }
        // add rel-bias mask
        int mbase = w*16 + lh*4 + 2047 - kt*64 - lr;
        #pragma unroll
        for (int f = 0; f < 4; f++)
            #pragma unroll
            for (int r = 0; r < 4; r++)
                s[f][r] += mrw[mbase + r - f*16];

        // online softmax (rows live in 16-lane groups)
        float pvv[4][4];
        #pragma unroll
        for (int r = 0; r < 4; r++) {
            float tm = fmaxf(fmaxf(s[0][r], s[1][r]), fmaxf(s[2][r], s[3][r]));
            tm = fmaxf(tm, __shfl_xor(tm, 1));
            tm = fmaxf(tm, __shfl_xor(tm, 2));
            tm = fmaxf(tm, __shfl_xor(tm, 4));
            tm = fmaxf(tm, __shfl_xor(tm, 8));
            float mn = fmaxf(mrun[r], tm);
            float corr = __expf(mrun[r] - mn);
            mrun[r] = mn;
            float ts = 0.f;
            #pragma unroll
            for (int f = 0; f < 4; f++) {
                float e = __expf(s[f][r] - mn);
                pvv[f][r] = e; ts += e;
            }
            ts += __shfl_xor(ts, 1); ts += __shfl_xor(ts, 2);
            ts += __shfl_xor(ts, 4); ts += __shfl_xor(ts, 8);
            lrun[r] = lrun[r]*corr + ts;
            #pragma unroll
            for (int f = 0; f < 4; f++) oacc[f][r] *= corr;
        }
        // P -> per-wave LDS (bf16, swizzled)
        #pragma unroll
        for (int r = 0; r < 4; r++) {
            int q = lh*4 + r;
            int qsw = (q & 7) << 4;
            #pragma unroll
            for (int f = 0; f < 4; f++) {
                int k = f*16 + lr;
                int off = (q*128 + k*2) ^ qsw;
                *(unsigned short*)((char*)Pt[w] + off) = f2bf(pvv[f][r]);
            }
        }
        // PV: O += P @ V
        bf16x8 pa[2];
        int psw = (lr & 7) << 4;
        #pragma unroll
        for (int c = 0; c < 2; c++) {
            int off = (lr*128 + (c*32 + lh*8)*2) ^ psw;
            pa[c] = *(const bf16x8*)((const char*)Pt[w] + off);
        }
        #pragma unroll
        for (int f = 0; f < 4; f++) {
            int dl = f*16 + lr;
            int dsw = (dl & 7) << 4;
            #pragma unroll
            for (int c = 0; c < 2; c++) {
                int off = (dl*128 + (c*32 + lh*8)*2) ^ dsw;
                bf16x8 vb = *(const bf16x8*)((const char*)Vts + off);
                oacc[f] = __builtin_amdgcn_mfma_f32_16x16x32_bf16(pa[c], vb, oacc[f], 0, 0, 0);
            }
        }
    }

    // epilogue: normalize and store
    #pragma unroll
    for (int r = 0; r < 4; r++) {
        float inv = 1.f / lrun[r];
        int row = q0 + w*16 + lh*4 + r;
        #pragma unroll
        for (int f = 0; f < 4; f++)
            ctx[bc + (size_t)row * Cc + f*16 + lr] = oacc[f][r] * inv;
    }
}

extern "C" void kernel_launch(void* const* d_in, const int* in_sizes, int n_in,
                              void* d_out, int out_size, void* d_ws, size_t ws_size,
                              hipStream_t stream) {
    const float* query     = (const float*)d_in[0];
    const float* key       = (const float*)d_in[1];
    const float* g_q       = (const float*)d_in[2];
    const float* b_q       = (const float*)d_in[3];
    const float* g_k       = (const float*)d_in[4];
    const float* b_k       = (const float*)d_in[5];
    const float* in_proj_w = (const float*)d_in[6];
    const float* in_proj_b = (const float*)d_in[7];
    const float* out_w     = (const float*)d_in[8];
    const float* out_b     = (const float*)d_in[9];
    const float* proj_w    = (const float*)d_in[10];
    const float* proj_b    = (const float*)d_in[11];
    const float* rel_table = (const float*)d_in[12];
    const float* g_ffn     = (const float*)d_in[13];
    const float* b_ffn     = (const float*)d_in[14];
    const float* w1        = (const float*)d_in[15];
    const float* w2        = (const float*)d_in[16];
    const float* w3        = (const float*)d_in[17];
    const float* g_out     = (const float*)d_in[18];
    const float* b_out     = (const float*)d_in[19];

    float* ws = (float*)d_ws;
    const size_t MC = (size_t)Mm * Cc;           // 4096*1024
    float* qn = ws;                               // LN(query); later: vt
    float* kn = qn + MC;                          // LN(key); later: t1
    float* qp = kn + MC;                          // q projection; later: x
    float* kp = qp + MC;                          // k projection; later: h
    float* vp = kp + MC;                          // v projection; later: x2
    float* mr = vp + MC;                          // mean rel bias [4095]
    float* gf = mr + 4096;                        // ctx (attention out), later SwiGLU
    float* vt  = qn;                              // transposed V [B*H,64,T] (16 MB = MC)
    float* ctx = gf;
    float* t1  = kn;
    float* x   = qp;
    float* h   = kp;
    float* x2  = vp;

    dim3 blk(256);
    ln_k<<<Mm, blk, 0, stream>>>(query, g_q, b_q, qn);
    ln_k<<<Mm, blk, 0, stream>>>(key,   g_k, b_k, kn);
    meanrel_k<<<16, blk, 0, stream>>>(rel_table, mr);

    dim3 g1(Cc/64, Mm/64);
    gemm_k<<<g1, blk, 0, stream>>>(qn, in_proj_w,                   in_proj_b,        nullptr, qp, Cc, Cc);
    gemm_k<<<g1, blk, 0, stream>>>(kn, in_proj_w + (size_t)Cc*Cc,   in_proj_b + Cc,   nullptr, kp, Cc, Cc);
    gemm_k<<<g1, blk, 0, stream>>>(kn, in_proj_w + (size_t)2*Cc*Cc, in_proj_b + 2*Cc, nullptr, vp, Cc, Cc);

    vt_k<<<Bb*Hh*32, blk, 0, stream>>>(vp, vt);
    fattn_k<<<Bb*Hh*32, blk, 0, stream>>>(qp, kp, vt, mr, ctx);

    gemm_k<<<g1, blk, 0, stream>>>(ctx, out_w,  out_b,  nullptr, t1, Cc, Cc);
    gemm_k<<<g1, blk, 0, stream>>>(t1,  proj_w, proj_b, query,   x,  Cc, Cc);

    ln_k<<<Mm, blk, 0, stream>>>(x, g_ffn, b_ffn, h);
    dim3 g2((HID + 63)/64, Mm/64);
    swiglu_k<<<g2, blk, 0, stream>>>(h, w1, w2, gf, HID, Cc);
    dim3 g3(Cc/64, Mm/64);
    gemm_k<<<g3, blk, 0, stream>>>(gf, w3, nullptr, x, x2, Cc, HID);

    ln_k<<<Mm, blk, 0, stream>>>(x2, g_out, b_out, (float*)d_out);
}

// Round 3
// 428.926 us; speedup vs baseline: 10.9638x; 4.6281x over previous
//
#include <hip/hip_runtime.h>
#include <hip/hip_bf16.h>

static constexpr int Bb  = 2;
static constexpr int Tt  = 2048;
static constexpr int Cc  = 1024;
static constexpr int Hh  = 16;
static constexpr int HDi = 64;
static constexpr int HID = 1365;
static constexpr int HIDP = 1408;      // HID padded to multiple of 128
static constexpr int Mm  = Bb * Tt;    // 4096 rows

typedef unsigned short u16;
typedef __attribute__((ext_vector_type(8))) short bf16x8;
typedef __attribute__((ext_vector_type(4))) float f32x4;
typedef __attribute__((ext_vector_type(8))) unsigned short u16x8;
typedef __attribute__((ext_vector_type(4))) unsigned short u16x4;

__device__ inline u16 f2bf(float f) {
    unsigned u = __builtin_bit_cast(unsigned, f);
    u += 0x7fffu + ((u >> 16) & 1u);
    return (u16)(u >> 16);
}

__device__ inline void gl16(const void* g, void* l) {
    __builtin_amdgcn_global_load_lds(
        (const __attribute__((address_space(1))) unsigned*)g,
        (__attribute__((address_space(3))) unsigned*)l, 16, 0, 0);
}

// ---------------- LayerNorm: one row (C=1024) per block; OUTBF: bf16 out ----------------
template<int OUTBF>
__global__ __launch_bounds__(256) void ln_k(const float* __restrict__ x,
                                            const float* __restrict__ g,
                                            const float* __restrict__ b,
                                            void* __restrict__ yv) {
    int row = blockIdx.x;
    int tid = threadIdx.x;
    const float4* xr = (const float4*)(x + (size_t)row * Cc);
    float4 v = xr[tid];
    float s  = v.x + v.y + v.z + v.w;
    float ss = v.x*v.x + v.y*v.y + v.z*v.z + v.w*v.w;
    __shared__ float rs[256], rq[256];
    rs[tid] = s; rq[tid] = ss;
    __syncthreads();
    for (int o = 128; o > 0; o >>= 1) {
        if (tid < o) { rs[tid] += rs[tid+o]; rq[tid] += rq[tid+o]; }
        __syncthreads();
    }
    float mean = rs[0] * (1.f/Cc);
    float var  = rq[0] * (1.f/Cc) - mean*mean;
    float inv  = rsqrtf(var + 1e-5f);
    float4 gv = ((const float4*)g)[tid];
    float4 bv = ((const float4*)b)[tid];
    float o0 = (v.x-mean)*inv*gv.x + bv.x;
    float o1 = (v.y-mean)*inv*gv.y + bv.y;
    float o2 = (v.z-mean)*inv*gv.z + bv.z;
    float o3 = (v.w-mean)*inv*gv.w + bv.w;
    if (OUTBF) {
        u16x4 o4 = { f2bf(o0), f2bf(o1), f2bf(o2), f2bf(o3) };
        ((u16x4*)((u16*)yv + (size_t)row * Cc))[tid] = o4;
    } else {
        float4 o4 = { o0, o1, o2, o3 };
        ((float4*)((float*)yv + (size_t)row * Cc))[tid] = o4;
    }
}

// ---------------- mean over heads of rel_table -> mr[4095] ----------------
__global__ __launch_bounds__(256) void meanrel_k(const float* __restrict__ rel,
                                                 float* __restrict__ mr) {
    int j = blockIdx.x * 256 + threadIdx.x;
    if (j < 2*Tt - 1) {
        float s = 0.f;
        #pragma unroll
        for (int h = 0; h < Hh; h++) s += rel[(size_t)h * (2*Tt - 1) + j];
        mr[j] = s * (1.f/Hh);
    }
}

// ---------------- f32 -> bf16 with zero padding: src[Rs][Cs] -> dst[Rd][Cd] ----------------
__global__ __launch_bounds__(256) void cvt_k(const float* __restrict__ src,
                                             u16* __restrict__ dst,
                                             int Rs, int Cs, int Cd, int total8) {
    int idx = blockIdx.x * 256 + threadIdx.x;
    if (idx >= total8) return;
    int e0 = idx * 8;
    int r = e0 / Cd, c0 = e0 - r * Cd;
    u16x8 o;
    #pragma unroll
    for (int j = 0; j < 8; j++) {
        int c = c0 + j;
        float v = (r < Rs && c < Cs) ? src[(size_t)r * Cs + c] : 0.f;
        o[j] = f2bf(v);
    }
    *(u16x8*)(dst + (size_t)e0) = o;
}

// ---------------- bf16 MFMA GEMM: out[M,N] = A[M,K] @ W[N,K]^T (+bias)(+res) ----------------
// 128x128 tile, BK=32, 256 thr (4 waves 2x2, each 64x64 out).
// LDS linear [row][4 slots of 8 bf16]; source pre-swizzled slot^=(row&3); read with same XOR.
template<int OUTBF, int HASRES, int HASBIAS>
__global__ __launch_bounds__(256) void mgemm_k(const u16* __restrict__ A,
                                               const u16* __restrict__ W,
                                               const float* __restrict__ bias,
                                               const float* __restrict__ res,
                                               void* __restrict__ outv,
                                               int N, int K) {
    __shared__ u16 As[128*32];
    __shared__ u16 Ws[128*32];
    int bm = blockIdx.y * 128, bn = blockIdx.x * 128;
    int tid = threadIdx.x, w = tid >> 6, l = tid & 63;
    int lr = l & 15, lh = l >> 4;
    int wm = (w >> 1) * 64, wn = (w & 1) * 64;
    f32x4 acc[4][4] = {};

    for (int kt = 0; kt < K; kt += 32) {
        __syncthreads();
        #pragma unroll
        for (int c = 0; c < 2; c++) {
            int i = w*128 + c*64 + l;
            int row = i >> 2, slot = i & 3;
            int ko = kt + ((slot ^ (row & 3)) << 3);
            gl16(A + (size_t)(bm + row) * K + ko, (char*)As + (w*128 + c*64) * 16);
            gl16(W + (size_t)(bn + row) * K + ko, (char*)Ws + (w*128 + c*64) * 16);
        }
        __syncthreads();
        bf16x8 af[4], wf[4];
        #pragma unroll
        for (int f = 0; f < 4; f++) {
            int r = wm + f*16 + lr;
            af[f] = *(const bf16x8*)((const char*)As + r*64 + ((lh ^ (r & 3)) << 4));
            int rn = wn + f*16 + lr;
            wf[f] = *(const bf16x8*)((const char*)Ws + rn*64 + ((lh ^ (rn & 3)) << 4));
        }
        #pragma unroll
        for (int fm = 0; fm < 4; fm++)
            #pragma unroll
            for (int fn = 0; fn < 4; fn++)
                acc[fm][fn] = __builtin_amdgcn_mfma_f32_16x16x32_bf16(af[fm], wf[fn], acc[fm][fn], 0, 0, 0);
    }

    #pragma unroll
    for (int fm = 0; fm < 4; fm++) {
        #pragma unroll
        for (int r = 0; r < 4; r++) {
            int row = bm + wm + fm*16 + lh*4 + r;
            #pragma unroll
            for (int fn = 0; fn < 4; fn++) {
                int col = bn + wn + fn*16 + lr;
                float v = acc[fm][fn][r];
                if (HASBIAS) v += bias[col];
                if (HASRES)  v += res[(size_t)row * N + col];
                if (OUTBF) ((u16*)outv)[(size_t)row * N + col] = f2bf(v);
                else       ((float*)outv)[(size_t)row * N + col] = v;
            }
        }
    }
}

// ---------------- fused SwiGLU MFMA GEMM: gf = silu(A@W1^T) * (A@W2^T), bf16 out ----------------
__global__ __launch_bounds__(256) void mswiglu_k(const u16* __restrict__ A,
                                                 const u16* __restrict__ W1,
                                                 const u16* __restrict__ W2,
                                                 u16* __restrict__ out,
                                                 int N, int K) {
    __shared__ u16 As[128*32];
    __shared__ u16 W1s[128*32];
    __shared__ u16 W2s[128*32];
    int bm = blockIdx.y * 128, bn = blockIdx.x * 128;
    int tid = threadIdx.x, w = tid >> 6, l = tid & 63;
    int lr = l & 15, lh = l >> 4;
    int wm = (w >> 1) * 64, wn = (w & 1) * 64;
    f32x4 acc1[4][4] = {};
    f32x4 acc2[4][4] = {};

    for (int kt = 0; kt < K; kt += 32) {
        __syncthreads();
        #pragma unroll
        for (int c = 0; c < 2; c++) {
            int i = w*128 + c*64 + l;
            int row = i >> 2, slot = i & 3;
            int ko = kt + ((slot ^ (row & 3)) << 3);
            gl16(A  + (size_t)(bm + row) * K + ko, (char*)As  + (w*128 + c*64) * 16);
            gl16(W1 + (size_t)(bn + row) * K + ko, (char*)W1s + (w*128 + c*64) * 16);
            gl16(W2 + (size_t)(bn + row) * K + ko, (char*)W2s + (w*128 + c*64) * 16);
        }
        __syncthreads();
        bf16x8 af[4], w1f[4], w2f[4];
        #pragma unroll
        for (int f = 0; f < 4; f++) {
            int r = wm + f*16 + lr;
            af[f] = *(const bf16x8*)((const char*)As + r*64 + ((lh ^ (r & 3)) << 4));
            int rn = wn + f*16 + lr;
            int offn = rn*64 + ((lh ^ (rn & 3)) << 4);
            w1f[f] = *(const bf16x8*)((const char*)W1s + offn);
            w2f[f] = *(const bf16x8*)((const char*)W2s + offn);
        }
        #pragma unroll
        for (int fm = 0; fm < 4; fm++)
            #pragma unroll
            for (int fn = 0; fn < 4; fn++) {
                acc1[fm][fn] = __builtin_amdgcn_mfma_f32_16x16x32_bf16(af[fm], w1f[fn], acc1[fm][fn], 0, 0, 0);
                acc2[fm][fn] = __builtin_amdgcn_mfma_f32_16x16x32_bf16(af[fm], w2f[fn], acc2[fm][fn], 0, 0, 0);
            }
    }

    #pragma unroll
    for (int fm = 0; fm < 4; fm++) {
        #pragma unroll
        for (int r = 0; r < 4; r++) {
            int row = bm + wm + fm*16 + lh*4 + r;
            #pragma unroll
            for (int fn = 0; fn < 4; fn++) {
                int col = bn + wn + fn*16 + lr;
                float a = acc1[fm][fn][r];
                float sig = 1.f / (1.f + __expf(-a));
                out[(size_t)row * N + col] = f2bf(a * sig * acc2[fm][fn][r]);
            }
        }
    }
}

// ---------------- V transpose (bf16): vp[B,T,C](head cols) -> vt[B*H, 64, T] ----------------
__global__ __launch_bounds__(256) void vt_k(const u16* __restrict__ vp,
                                            u16* __restrict__ vt) {
    int blk = blockIdx.x;             // bh*32 + kb
    int bh = blk >> 5, kb = blk & 31;
    int b = bh >> 4, h = bh & 15;
    __shared__ u16 t[64][65];
    int tid = threadIdx.x;
    size_t bc = (size_t)b*Tt*Cc + (size_t)h*HDi;
    #pragma unroll
    for (int i = 0; i < 16; i++) {
        int e = tid + i*256;
        int k = e >> 6, d = e & 63;
        t[d][k] = vp[bc + (size_t)(kb*64 + k)*Cc + d];
    }
    __syncthreads();
    #pragma unroll
    for (int i = 0; i < 16; i++) {
        int e = tid + i*256;
        int d = e >> 6, k = e & 63;
        vt[((size_t)bh*64 + d)*Tt + kb*64 + k] = t[d][k];
    }
}

// ---------------- MFMA flash attention (bf16 in/out) ----------------
__global__ __launch_bounds__(256) void fattn_k(const u16* __restrict__ qp,
                                               const u16* __restrict__ kp,
                                               const u16* __restrict__ vt,
                                               const float* __restrict__ mr,
                                               u16* __restrict__ ctx) {
    __shared__ u16 Kt[4096];        // 64x64 bf16, swizzled
    __shared__ u16 Vts[4096];       // 64x64 bf16 (d-major), swizzled
    __shared__ u16 Pt[4][1024];     // per-wave 16x64 bf16
    __shared__ float mrw[2112];     // rel-bias window

    int blk = blockIdx.x;
    int qt = blk & 31, h = (blk >> 5) & 15, b = blk >> 9;
    int q0 = qt * 64;
    int tid = threadIdx.x, w = tid >> 6, l = tid & 63;
    int lr = l & 15, lh = l >> 4;
    size_t bc = (size_t)b * Tt * Cc + (size_t)h * HDi;

    for (int i = tid; i < 2111; i += 256) mrw[i] = mr[q0 + i];

    // Q fragments in registers (unscaled; 1/8 applied post-MFMA)
    bf16x8 qa[2];
    {
        const u16* qrow = qp + bc + (size_t)(q0 + w*16 + lr) * Cc;
        #pragma unroll
        for (int c = 0; c < 2; c++)
            qa[c] = *(const bf16x8*)(qrow + c*32 + lh*8);
    }

    f32x4 oacc[4];
    float mrun[4], lrun[4];
    #pragma unroll
    for (int f = 0; f < 4; f++)
        #pragma unroll
        for (int r = 0; r < 4; r++) oacc[f][r] = 0.f;
    #pragma unroll
    for (int r = 0; r < 4; r++) { mrun[r] = -1e30f; lrun[r] = 0.f; }

    int sr  = tid >> 2;           // staging row 0..63
    int sd0 = (tid & 3) << 4;     // element offset 0,16,32,48
    int ssw = (sr & 7) << 4;
    const u16* vtbase = vt + ((size_t)(b*Hh + h) * HDi + sr) * Tt;

    for (int kt = 0; kt < 32; kt++) {
        __syncthreads();
        { // stage K tile + V tile (bf16 copies, XOR-swizzled)
            const u16* kr = kp + bc + (size_t)(kt*64 + sr) * Cc + sd0;
            uint4 k0 = *(const uint4*)kr;
            uint4 k1 = *(const uint4*)(kr + 8);
            int base = sr*128 + sd0*2;
            *(uint4*)((char*)Kt + ((base     ) ^ ssw)) = k0;
            *(uint4*)((char*)Kt + ((base + 16) ^ ssw)) = k1;
            const u16* vr = vtbase + kt*64 + sd0;
            uint4 v0 = *(const uint4*)vr;
            uint4 v1 = *(const uint4*)(vr + 8);
            *(uint4*)((char*)Vts + ((base     ) ^ ssw)) = v0;
            *(uint4*)((char*)Vts + ((base + 16) ^ ssw)) = v1;
        }
        __syncthreads();

        // QK^T
        f32x4 s[4];
        #pragma unroll
        for (int f = 0; f < 4; f++)
            #pragma unroll
            for (int r = 0; r < 4; r++) s[f][r] = 0.f;
        #pragma unroll
        for (int f = 0; f < 4; f++) {
            int kl = f*16 + lr;
            int ksw = (kl & 7) << 4;
            #pragma unroll
            for (int c = 0; c < 2; c++) {
                int off = (kl*128 + (c*32 + lh*8)*2) ^ ksw;
                bf16x8 kb = *(const bf16x8*)((const char*)Kt + off);
                s[f] = __builtin_amdgcn_mfma_f32_16x16x32_bf16(qa[c], kb, s[f], 0, 0, 0);
            }
        }
        // scale + rel-bias
        int mbase = w*16 + lh*4 + 2047 - kt*64 - lr;
        #pragma unroll
        for (int f = 0; f < 4; f++)
            #pragma unroll
            for (int r = 0; r < 4; r++)
                s[f][r] = s[f][r]*0.125f + mrw[mbase + r - f*16];

        // online softmax
        float pvv[4][4];
        #pragma unroll
        for (int r = 0; r < 4; r++) {
            float tm = fmaxf(fmaxf(s[0][r], s[1][r]), fmaxf(s[2][r], s[3][r]));
            tm = fmaxf(tm, __shfl_xor(tm, 1));
            tm = fmaxf(tm, __shfl_xor(tm, 2));
            tm = fmaxf(tm, __shfl_xor(tm, 4));
            tm = fmaxf(tm, __shfl_xor(tm, 8));
            float mn = fmaxf(mrun[r], tm);
            float corr = __expf(mrun[r] - mn);
            mrun[r] = mn;
            float ts = 0.f;
            #pragma unroll
            for (int f = 0; f < 4; f++) {
                float e = __expf(s[f][r] - mn);
                pvv[f][r] = e; ts += e;
            }
            ts += __shfl_xor(ts, 1); ts += __shfl_xor(ts, 2);
            ts += __shfl_xor(ts, 4); ts += __shfl_xor(ts, 8);
            lrun[r] = lrun[r]*corr + ts;
            #pragma unroll
            for (int f = 0; f < 4; f++) oacc[f][r] *= corr;
        }
        // P -> per-wave LDS
        #pragma unroll
        for (int r = 0; r < 4; r++) {
            int q = lh*4 + r;
            int qsw = (q & 7) << 4;
            #pragma unroll
            for (int f = 0; f < 4; f++) {
                int k = f*16 + lr;
                int off = (q*128 + k*2) ^ qsw;
                *(u16*)((char*)Pt[w] + off) = f2bf(pvv[f][r]);
            }
        }
        // PV
        bf16x8 pa[2];
        int psw = (lr & 7) << 4;
        #pragma unroll
        for (int c = 0; c < 2; c++) {
            int off = (lr*128 + (c*32 + lh*8)*2) ^ psw;
            pa[c] = *(const bf16x8*)((const char*)Pt[w] + off);
        }
        #pragma unroll
        for (int f = 0; f < 4; f++) {
            int dl = f*16 + lr;
            int dsw = (dl & 7) << 4;
            #pragma unroll
            for (int c = 0; c < 2; c++) {
                int off = (dl*128 + (c*32 + lh*8)*2) ^ dsw;
                bf16x8 vb = *(const bf16x8*)((const char*)Vts + off);
                oacc[f] = __builtin_amdgcn_mfma_f32_16x16x32_bf16(pa[c], vb, oacc[f], 0, 0, 0);
            }
        }
    }

    // epilogue
    #pragma unroll
    for (int r = 0; r < 4; r++) {
        float inv = 1.f / lrun[r];
        int row = q0 + w*16 + lh*4 + r;
        #pragma unroll
        for (int f = 0; f < 4; f++)
            ctx[bc + (size_t)row * Cc + f*16 + lr] = f2bf(oacc[f][r] * inv);
    }
}

extern "C" void kernel_launch(void* const* d_in, const int* in_sizes, int n_in,
                              void* d_out, int out_size, void* d_ws, size_t ws_size,
                              hipStream_t stream) {
    const float* query     = (const float*)d_in[0];
    const float* key       = (const float*)d_in[1];
    const float* g_q       = (const float*)d_in[2];
    const float* b_q       = (const float*)d_in[3];
    const float* g_k       = (const float*)d_in[4];
    const float* b_k       = (const float*)d_in[5];
    const float* in_proj_w = (const float*)d_in[6];
    const float* in_proj_b = (const float*)d_in[7];
    const float* out_w     = (const float*)d_in[8];
    const float* out_b     = (const float*)d_in[9];
    const float* proj_w    = (const float*)d_in[10];
    const float* proj_b    = (const float*)d_in[11];
    const float* rel_table = (const float*)d_in[12];
    const float* g_ffn     = (const float*)d_in[13];
    const float* b_ffn     = (const float*)d_in[14];
    const float* w1        = (const float*)d_in[15];
    const float* w2        = (const float*)d_in[16];
    const float* w3        = (const float*)d_in[17];
    const float* g_out     = (const float*)d_in[18];
    const float* b_out     = (const float*)d_in[19];

    char* p = (char*)d_ws;
    auto alloc = [&](size_t bytes) { char* r = p; p += bytes; return r; };
    const size_t MCb = (size_t)Mm * Cc * 2;              // bf16 [4096][1024]
    u16* wA  = (u16*)alloc((size_t)3*Cc*Cc*2);           // in_proj bf16
    u16* wO  = (u16*)alloc((size_t)Cc*Cc*2);
    u16* wP  = (u16*)alloc((size_t)Cc*Cc*2);
    u16* w1b = (u16*)alloc((size_t)HIDP*Cc*2);
    u16* w2b = (u16*)alloc((size_t)HIDP*Cc*2);
    u16* w3b = (u16*)alloc((size_t)Cc*HIDP*2);
    float* mr = (float*)alloc(4096*4);
    u16* qn = (u16*)alloc(MCb);
    u16* kn = (u16*)alloc(MCb);
    u16* qp = (u16*)alloc(MCb);
    u16* kp = (u16*)alloc(MCb);
    u16* vp = (u16*)alloc(MCb);      // gf reuses vp..vt (16MB window)
    u16* vt = (u16*)alloc(MCb);
    float* x  = (float*)alloc((size_t)Mm*Cc*4);
    float* x2 = (float*)alloc((size_t)Mm*Cc*4);
    u16* ctx = qn;   // aliases (lifetimes disjoint)
    u16* t1  = kn;
    u16* h   = qp;
    u16* gf  = vp;   // [4096][1408] bf16 = 11.5MB fits vp+vt

    dim3 blk(256);
    // weight conversions
    cvt_k<<<(3*Cc*Cc/8 + 255)/256, blk, 0, stream>>>(in_proj_w, wA, 3*Cc, Cc, Cc, 3*Cc*Cc/8);
    cvt_k<<<(Cc*Cc/8 + 255)/256,   blk, 0, stream>>>(out_w,  wO, Cc, Cc, Cc, Cc*Cc/8);
    cvt_k<<<(Cc*Cc/8 + 255)/256,   blk, 0, stream>>>(proj_w, wP, Cc, Cc, Cc, Cc*Cc/8);
    cvt_k<<<(HIDP*Cc/8 + 255)/256, blk, 0, stream>>>(w1, w1b, HID, Cc, Cc, HIDP*Cc/8);
    cvt_k<<<(HIDP*Cc/8 + 255)/256, blk, 0, stream>>>(w2, w2b, HID, Cc, Cc, HIDP*Cc/8);
    cvt_k<<<(Cc*HIDP/8 + 255)/256, blk, 0, stream>>>(w3, w3b, Cc, HID, HIDP, Cc*HIDP/8);
    meanrel_k<<<16, blk, 0, stream>>>(rel_table, mr);

    ln_k<1><<<Mm, blk, 0, stream>>>(query, g_q, b_q, qn);
    ln_k<1><<<Mm, blk, 0, stream>>>(key,   g_k, b_k, kn);

    dim3 g1(Cc/128, Mm/128);
    mgemm_k<1,0,1><<<g1, blk, 0, stream>>>(qn, wA,                    in_proj_b,        nullptr, qp, Cc, Cc);
    mgemm_k<1,0,1><<<g1, blk, 0, stream>>>(kn, wA + (size_t)Cc*Cc,    in_proj_b + Cc,   nullptr, kp, Cc, Cc);
    mgemm_k<1,0,1><<<g1, blk, 0, stream>>>(kn, wA + (size_t)2*Cc*Cc,  in_proj_b + 2*Cc, nullptr, vp, Cc, Cc);

    vt_k<<<Bb*Hh*32, blk, 0, stream>>>(vp, vt);
    fattn_k<<<Bb*Hh*32, blk, 0, stream>>>(qp, kp, vt, mr, ctx);

    mgemm_k<1,0,1><<<g1, blk, 0, stream>>>(ctx, wO, out_b,  nullptr, t1, Cc, Cc);
    mgemm_k<0,1,1><<<g1, blk, 0, stream>>>(t1,  wP, proj_b, query,   x,  Cc, Cc);

    ln_k<1><<<Mm, blk, 0, stream>>>(x, g_ffn, b_ffn, h);
    dim3 g2(HIDP/128, Mm/128);
    mswiglu_k<<<g2, blk, 0, stream>>>(h, w1b, w2b, gf, HIDP, Cc);
    dim3 g3(Cc/128, Mm/128);
    mgemm_k<0,1,0><<<g3, blk, 0, stream>>>(gf, w3b, nullptr, x, x2, Cc, HIDP);

    ln_k<0><<<Mm, blk, 0, stream>>>(x2, g_out, b_out, d_out);
}

// Round 4
// 346.584 us; speedup vs baseline: 13.5686x; 1.2376x over previous
//
#include <hip/hip_runtime.h>
#include <hip/hip_bf16.h>

static constexpr int Bb  = 2;
static constexpr int Tt  = 2048;
static constexpr int Cc  = 1024;
static constexpr int Hh  = 16;
static constexpr int HDi = 64;
static constexpr int HID = 1365;
static constexpr int HIDP = 1408;      // HID padded to multiple of 128
static constexpr int Mm  = Bb * Tt;    // 4096 rows

typedef unsigned short u16;
typedef __attribute__((ext_vector_type(8))) short bf16x8;
typedef __attribute__((ext_vector_type(4))) float f32x4;
typedef __attribute__((ext_vector_type(8))) unsigned short u16x8;
typedef __attribute__((ext_vector_type(4))) unsigned short u16x4;

__device__ inline u16 f2bf(float f) {
    unsigned u = __builtin_bit_cast(unsigned, f);
    u += 0x7fffu + ((u >> 16) & 1u);
    return (u16)(u >> 16);
}

__device__ inline void gl16(const void* g, void* l) {
    __builtin_amdgcn_global_load_lds(
        (const __attribute__((address_space(1))) unsigned*)g,
        (__attribute__((address_space(3))) unsigned*)l, 16, 0, 0);
}

// ---------------- LayerNorm: one row (C=1024) per block; OUTBF: bf16 out ----------------
template<int OUTBF>
__global__ __launch_bounds__(256) void ln_k(const float* __restrict__ x,
                                            const float* __restrict__ g,
                                            const float* __restrict__ b,
                                            void* __restrict__ yv) {
    int row = blockIdx.x;
    int tid = threadIdx.x;
    const float4* xr = (const float4*)(x + (size_t)row * Cc);
    float4 v = xr[tid];
    float s  = v.x + v.y + v.z + v.w;
    float ss = v.x*v.x + v.y*v.y + v.z*v.z + v.w*v.w;
    __shared__ float rs[256], rq[256];
    rs[tid] = s; rq[tid] = ss;
    __syncthreads();
    for (int o = 128; o > 0; o >>= 1) {
        if (tid < o) { rs[tid] += rs[tid+o]; rq[tid] += rq[tid+o]; }
        __syncthreads();
    }
    float mean = rs[0] * (1.f/Cc);
    float var  = rq[0] * (1.f/Cc) - mean*mean;
    float inv  = rsqrtf(var + 1e-5f);
    float4 gv = ((const float4*)g)[tid];
    float4 bv = ((const float4*)b)[tid];
    float o0 = (v.x-mean)*inv*gv.x + bv.x;
    float o1 = (v.y-mean)*inv*gv.y + bv.y;
    float o2 = (v.z-mean)*inv*gv.z + bv.z;
    float o3 = (v.w-mean)*inv*gv.w + bv.w;
    if (OUTBF) {
        u16x4 o4 = { f2bf(o0), f2bf(o1), f2bf(o2), f2bf(o3) };
        ((u16x4*)((u16*)yv + (size_t)row * Cc))[tid] = o4;
    } else {
        float4 o4 = { o0, o1, o2, o3 };
        ((float4*)((float*)yv + (size_t)row * Cc))[tid] = o4;
    }
}

// ---------------- merged LN for query+key -> qn, kn (bf16) ----------------
__global__ __launch_bounds__(256) void ln2_k(const float* __restrict__ q,
                                             const float* __restrict__ k,
                                             const float* __restrict__ gq, const float* __restrict__ bq,
                                             const float* __restrict__ gk, const float* __restrict__ bk,
                                             u16* __restrict__ qn, u16* __restrict__ kn) {
    int row = blockIdx.x;
    const float* x; const float* g; const float* bb; u16* y; int r;
    if (row < Mm) { x = q; g = gq; bb = bq; y = qn; r = row; }
    else          { x = k; g = gk; bb = bk; y = kn; r = row - Mm; }
    int tid = threadIdx.x;
    float4 v = ((const float4*)(x + (size_t)r * Cc))[tid];
    float s  = v.x + v.y + v.z + v.w;
    float ss = v.x*v.x + v.y*v.y + v.z*v.z + v.w*v.w;
    __shared__ float rs[256], rq2[256];
    rs[tid] = s; rq2[tid] = ss;
    __syncthreads();
    for (int o = 128; o > 0; o >>= 1) {
        if (tid < o) { rs[tid] += rs[tid+o]; rq2[tid] += rq2[tid+o]; }
        __syncthreads();
    }
    float mean = rs[0] * (1.f/Cc);
    float var  = rq2[0] * (1.f/Cc) - mean*mean;
    float inv  = rsqrtf(var + 1e-5f);
    float4 gv = ((const float4*)g)[tid];
    float4 bv = ((const float4*)bb)[tid];
    u16x4 o4 = { f2bf((v.x-mean)*inv*gv.x + bv.x), f2bf((v.y-mean)*inv*gv.y + bv.y),
                 f2bf((v.z-mean)*inv*gv.z + bv.z), f2bf((v.w-mean)*inv*gv.w + bv.w) };
    ((u16x4*)(y + (size_t)r * Cc))[tid] = o4;
}

// ---------------- mean over heads of rel_table -> mr[4095] ----------------
__global__ __launch_bounds__(256) void meanrel_k(const float* __restrict__ rel,
                                                 float* __restrict__ mr) {
    int j = blockIdx.x * 256 + threadIdx.x;
    if (j < 2*Tt - 1) {
        float s = 0.f;
        #pragma unroll
        for (int h = 0; h < Hh; h++) s += rel[(size_t)h * (2*Tt - 1) + j];
        mr[j] = s * (1.f/Hh);
    }
}

// ---------------- f32 -> bf16 with zero padding ----------------
__global__ __launch_bounds__(256) void cvt_k(const float* __restrict__ src,
                                             u16* __restrict__ dst,
                                             int Rs, int Cs, int Cd, int total8) {
    int idx = blockIdx.x * 256 + threadIdx.x;
    if (idx >= total8) return;
    int e0 = idx * 8;
    int r = e0 / Cd, c0 = e0 - r * Cd;
    u16x8 o;
    #pragma unroll
    for (int j = 0; j < 8; j++) {
        int c = c0 + j;
        float v = (r < Rs && c < Cs) ? src[(size_t)r * Cs + c] : 0.f;
        o[j] = f2bf(v);
    }
    *(u16x8*)(dst + (size_t)e0) = o;
}

// ---------------- transposed cvt: dst[j][c] = src[c][j], 1024x1024 f32->bf16 ----------------
__global__ __launch_bounds__(256) void cvtT_k(const float* __restrict__ src,
                                              u16* __restrict__ dst) {
    __shared__ float t[64][65];
    int j0 = blockIdx.x * 64, c0 = blockIdx.y * 64;
    int tid = threadIdx.x;
    #pragma unroll
    for (int i = 0; i < 16; i++) {
        int e = tid + i*256;
        int c = e >> 6, j = e & 63;
        t[c][j] = src[(size_t)(c0 + c) * Cc + j0 + j];
    }
    __syncthreads();
    #pragma unroll
    for (int i = 0; i < 16; i++) {
        int e = tid + i*256;
        int j = e >> 6, c = e & 63;
        dst[(size_t)(j0 + j) * Cc + c0 + c] = f2bf(t[c][j]);
    }
}

// ---------------- combined bias: bc[i] = dot(proj_w[i,:], out_b) + proj_b[i] ----------------
__global__ __launch_bounds__(256) void bias_k(const float* __restrict__ wp,
                                              const float* __restrict__ bo,
                                              const float* __restrict__ bp,
                                              float* __restrict__ bc) {
    int i = blockIdx.x, tid = threadIdx.x;
    float4 w = ((const float4*)(wp + (size_t)i * Cc))[tid];
    float4 b = ((const float4*)bo)[tid];
    float s = w.x*b.x + w.y*b.y + w.z*b.z + w.w*b.w;
    __shared__ float red[256];
    red[tid] = s; __syncthreads();
    for (int o = 128; o > 0; o >>= 1) {
        if (tid < o) red[tid] += red[tid+o];
        __syncthreads();
    }
    if (tid == 0) bc[i] = red[0] + bp[i];
}

// ---------------- bf16 MFMA GEMM: out[M,N] = A[M,K] @ W[N,K]^T (+bias)(+res) ----------------
template<int OUTBF, int HASRES, int HASBIAS>
__global__ __launch_bounds__(256) void mgemm_k(const u16* __restrict__ A,
                                               const u16* __restrict__ W,
                                               const float* __restrict__ bias,
                                               const float* __restrict__ res,
                                               void* __restrict__ outv,
                                               int N, int K) {
    __shared__ u16 As[128*32];
    __shared__ u16 Ws[128*32];
    int bm = blockIdx.y * 128, bn = blockIdx.x * 128;
    int tid = threadIdx.x, w = tid >> 6, l = tid & 63;
    int lr = l & 15, lh = l >> 4;
    int wm = (w >> 1) * 64, wn = (w & 1) * 64;
    f32x4 acc[4][4] = {};

    for (int kt = 0; kt < K; kt += 32) {
        __syncthreads();
        #pragma unroll
        for (int c = 0; c < 2; c++) {
            int i = w*128 + c*64 + l;
            int row = i >> 2, slot = i & 3;
            int ko = kt + ((slot ^ (row & 3)) << 3);
            gl16(A + (size_t)(bm + row) * K + ko, (char*)As + (w*128 + c*64) * 16);
            gl16(W + (size_t)(bn + row) * K + ko, (char*)Ws + (w*128 + c*64) * 16);
        }
        __syncthreads();
        bf16x8 af[4], wf[4];
        #pragma unroll
        for (int f = 0; f < 4; f++) {
            int r = wm + f*16 + lr;
            af[f] = *(const bf16x8*)((const char*)As + r*64 + ((lh ^ (r & 3)) << 4));
            int rn = wn + f*16 + lr;
            wf[f] = *(const bf16x8*)((const char*)Ws + rn*64 + ((lh ^ (rn & 3)) << 4));
        }
        #pragma unroll
        for (int fm = 0; fm < 4; fm++)
            #pragma unroll
            for (int fn = 0; fn < 4; fn++)
                acc[fm][fn] = __builtin_amdgcn_mfma_f32_16x16x32_bf16(af[fm], wf[fn], acc[fm][fn], 0, 0, 0);
    }

    #pragma unroll
    for (int fm = 0; fm < 4; fm++) {
        #pragma unroll
        for (int r = 0; r < 4; r++) {
            int row = bm + wm + fm*16 + lh*4 + r;
            #pragma unroll
            for (int fn = 0; fn < 4; fn++) {
                int col = bn + wn + fn*16 + lr;
                float v = acc[fm][fn][r];
                if (HASBIAS) v += bias[col];
                if (HASRES)  v += res[(size_t)row * N + col];
                if (OUTBF) ((u16*)outv)[(size_t)row * N + col] = f2bf(v);
                else       ((float*)outv)[(size_t)row * N + col] = v;
            }
        }
    }
}

// ---------------- merged QKV projection: z in {0,1,2} selects (A, W-slice, out-slice) ----------------
__global__ __launch_bounds__(256) void mqkv_k(const u16* __restrict__ qn,
                                              const u16* __restrict__ kn,
                                              const u16* __restrict__ wA,
                                              const float* __restrict__ bias3,
                                              u16* __restrict__ out3) {
    int z = blockIdx.z;
    const u16* A = z ? kn : qn;
    const u16* W = wA + (size_t)z * Cc * Cc;
    const float* bias = bias3 + z * Cc;
    u16* out = out3 + (size_t)z * Mm * Cc;

    __shared__ u16 As[128*32];
    __shared__ u16 Ws[128*32];
    int bm = blockIdx.y * 128, bn = blockIdx.x * 128;
    int tid = threadIdx.x, w = tid >> 6, l = tid & 63;
    int lr = l & 15, lh = l >> 4;
    int wm = (w >> 1) * 64, wn = (w & 1) * 64;
    f32x4 acc[4][4] = {};

    for (int kt = 0; kt < Cc; kt += 32) {
        __syncthreads();
        #pragma unroll
        for (int c = 0; c < 2; c++) {
            int i = w*128 + c*64 + l;
            int row = i >> 2, slot = i & 3;
            int ko = kt + ((slot ^ (row & 3)) << 3);
            gl16(A + (size_t)(bm + row) * Cc + ko, (char*)As + (w*128 + c*64) * 16);
            gl16(W + (size_t)(bn + row) * Cc + ko, (char*)Ws + (w*128 + c*64) * 16);
        }
        __syncthreads();
        bf16x8 af[4], wf[4];
        #pragma unroll
        for (int f = 0; f < 4; f++) {
            int r = wm + f*16 + lr;
            af[f] = *(const bf16x8*)((const char*)As + r*64 + ((lh ^ (r & 3)) << 4));
            int rn = wn + f*16 + lr;
            wf[f] = *(const bf16x8*)((const char*)Ws + rn*64 + ((lh ^ (rn & 3)) << 4));
        }
        #pragma unroll
        for (int fm = 0; fm < 4; fm++)
            #pragma unroll
            for (int fn = 0; fn < 4; fn++)
                acc[fm][fn] = __builtin_amdgcn_mfma_f32_16x16x32_bf16(af[fm], wf[fn], acc[fm][fn], 0, 0, 0);
    }

    #pragma unroll
    for (int fm = 0; fm < 4; fm++) {
        #pragma unroll
        for (int r = 0; r < 4; r++) {
            int row = bm + wm + fm*16 + lh*4 + r;
            #pragma unroll
            for (int fn = 0; fn < 4; fn++) {
                int col = bn + wn + fn*16 + lr;
                out[(size_t)row * Cc + col] = f2bf(acc[fm][fn][r] + bias[col]);
            }
        }
    }
}

// ---------------- fused SwiGLU MFMA GEMM ----------------
__global__ __launch_bounds__(256) void mswiglu_k(const u16* __restrict__ A,
                                                 const u16* __restrict__ W1,
                                                 const u16* __restrict__ W2,
                                                 u16* __restrict__ out,
                                                 int N, int K) {
    __shared__ u16 As[128*32];
    __shared__ u16 W1s[128*32];
    __shared__ u16 W2s[128*32];
    int bm = blockIdx.y * 128, bn = blockIdx.x * 128;
    int tid = threadIdx.x, w = tid >> 6, l = tid & 63;
    int lr = l & 15, lh = l >> 4;
    int wm = (w >> 1) * 64, wn = (w & 1) * 64;
    f32x4 acc1[4][4] = {};
    f32x4 acc2[4][4] = {};

    for (int kt = 0; kt < K; kt += 32) {
        __syncthreads();
        #pragma unroll
        for (int c = 0; c < 2; c++) {
            int i = w*128 + c*64 + l;
            int row = i >> 2, slot = i & 3;
            int ko = kt + ((slot ^ (row & 3)) << 3);
            gl16(A  + (size_t)(bm + row) * K + ko, (char*)As  + (w*128 + c*64) * 16);
            gl16(W1 + (size_t)(bn + row) * K + ko, (char*)W1s + (w*128 + c*64) * 16);
            gl16(W2 + (size_t)(bn + row) * K + ko, (char*)W2s + (w*128 + c*64) * 16);
        }
        __syncthreads();
        bf16x8 af[4], w1f[4], w2f[4];
        #pragma unroll
        for (int f = 0; f < 4; f++) {
            int r = wm + f*16 + lr;
            af[f] = *(const bf16x8*)((const char*)As + r*64 + ((lh ^ (r & 3)) << 4));
            int rn = wn + f*16 + lr;
            int offn = rn*64 + ((lh ^ (rn & 3)) << 4);
            w1f[f] = *(const bf16x8*)((const char*)W1s + offn);
            w2f[f] = *(const bf16x8*)((const char*)W2s + offn);
        }
        #pragma unroll
        for (int fm = 0; fm < 4; fm++)
            #pragma unroll
            for (int fn = 0; fn < 4; fn++) {
                acc1[fm][fn] = __builtin_amdgcn_mfma_f32_16x16x32_bf16(af[fm], w1f[fn], acc1[fm][fn], 0, 0, 0);
                acc2[fm][fn] = __builtin_amdgcn_mfma_f32_16x16x32_bf16(af[fm], w2f[fn], acc2[fm][fn], 0, 0, 0);
            }
    }

    #pragma unroll
    for (int fm = 0; fm < 4; fm++) {
        #pragma unroll
        for (int r = 0; r < 4; r++) {
            int row = bm + wm + fm*16 + lh*4 + r;
            #pragma unroll
            for (int fn = 0; fn < 4; fn++) {
                int col = bn + wn + fn*16 + lr;
                float a = acc1[fm][fn][r];
                float sig = 1.f / (1.f + __expf(-a));
                out[(size_t)row * N + col] = f2bf(a * sig * acc2[fm][fn][r]);
            }
        }
    }
}

// ---------------- V transpose (bf16): vp[B,T,C](head cols) -> vt[B*H, 64, T] ----------------
__global__ __launch_bounds__(256) void vt_k(const u16* __restrict__ vp,
                                            u16* __restrict__ vt) {
    int blk = blockIdx.x;             // bh*32 + kb
    int bh = blk >> 5, kb = blk & 31;
    int b = bh >> 4, h = bh & 15;
    __shared__ u16 t[64][65];
    int tid = threadIdx.x;
    size_t bc = (size_t)b*Tt*Cc + (size_t)h*HDi;
    #pragma unroll
    for (int i = 0; i < 16; i++) {
        int e = tid + i*256;
        int k = e >> 6, d = e & 63;
        t[d][k] = vp[bc + (size_t)(kb*64 + k)*Cc + d];
    }
    __syncthreads();
    #pragma unroll
    for (int i = 0; i < 16; i++) {
        int e = tid + i*256;
        int d = e >> 6, k = e & 63;
        vt[((size_t)bh*64 + d)*Tt + kb*64 + k] = t[d][k];
    }
}

// ---------------- MFMA flash attention, swapped QK^T (D[k][q]), packed P ----------------
// grid: B*H*32 blocks; 4 waves, each 16 q rows. Staging via global_load_lds w/ pre-swizzled src.
__global__ __launch_bounds__(256) void fattn_k(const u16* __restrict__ qp,
                                               const u16* __restrict__ kp,
                                               const u16* __restrict__ vt,
                                               const float* __restrict__ mr,
                                               u16* __restrict__ ctx) {
    __shared__ u16 Kt[4096];        // [64 k][64 d], swizzled slot^=(k&7)
    __shared__ u16 Vts[4096];       // [64 d][64 k], swizzled slot^=(d&7)
    __shared__ u16 Pt[4][1024];     // per-wave [16 q][64 k], swizzled
    __shared__ float mrw[2112];     // rel-bias window

    int blk = blockIdx.x;
    int qt = blk & 31, h = (blk >> 5) & 15, b = blk >> 9;
    int q0 = qt * 64;
    int tid = threadIdx.x, w = tid >> 6, l = tid & 63;
    int lr = l & 15, lh = l >> 4;
    size_t bc = (size_t)b * Tt * Cc + (size_t)h * HDi;
    const u16* vtb = vt + (size_t)(b*Hh + h) * HDi * Tt;

    for (int i = tid; i < 2111; i += 256) mrw[i] = mr[q0 + i];

    // Q fragments (B-operand: col = q = lr, elems d = c*32+lh*8..)
    bf16x8 qa[2];
    {
        const u16* qrow = qp + bc + (size_t)(q0 + w*16 + lr) * Cc;
        qa[0] = *(const bf16x8*)(qrow + lh*8);
        qa[1] = *(const bf16x8*)(qrow + 32 + lh*8);
    }

    f32x4 oacc[4] = {};
    float mrun = -1e30f, lrun = 0.f;   // softmax state for q = q0 + w*16 + lr

    int wb = (tid & 192) * 16;         // wave-uniform staging base (bytes)

    for (int kt = 0; kt < 32; kt++) {
        __syncthreads();
        // stage K tile + V tile via global_load_lds (linear dest, pre-swizzled src)
        #pragma unroll
        for (int ps = 0; ps < 2; ps++) {
            int i = ps*256 + tid;
            int kr = i >> 3, sl = i & 7;
            int so = (sl ^ (kr & 7)) << 3;
            gl16(kp + bc + (size_t)(kt*64 + kr) * Cc + so, (char*)Kt + ps*4096 + wb);
            gl16(vtb + (size_t)kr * Tt + kt*64 + so,       (char*)Vts + ps*4096 + wb);
        }
        __syncthreads();

        // QK^T swapped: s[f] = D[k = f*16+lh*4+r][q = lr]
        f32x4 s[4] = {};
        #pragma unroll
        for (int f = 0; f < 4; f++) {
            int kl = f*16 + lr, ksw = (kl & 7) << 4;
            #pragma unroll
            for (int c = 0; c < 2; c++) {
                bf16x8 kb = *(const bf16x8*)((const char*)Kt + ((kl*128 + c*64 + lh*16) ^ ksw));
                s[f] = __builtin_amdgcn_mfma_f32_16x16x32_bf16(kb, qa[c], s[f], 0, 0, 0);
            }
        }

        // scale + rel-bias; tile max
        int ib = w*16 + lr - kt*64 - lh*4 + 2047;
        float pv[4][4];
        float tm = -1e30f;
        #pragma unroll
        for (int f = 0; f < 4; f++)
            #pragma unroll
            for (int r = 0; r < 4; r++) {
                float v = s[f][r]*0.125f + mrw[ib - f*16 - r];
                s[f][r] = v;
                tm = fmaxf(tm, v);
            }
        tm = fmaxf(tm, __shfl_xor(tm, 16));
        tm = fmaxf(tm, __shfl_xor(tm, 32));

        float mn = fmaxf(mrun, tm);
        float corr = __expf(mrun - mn);
        mrun = mn;
        float ts = 0.f;
        #pragma unroll
        for (int f = 0; f < 4; f++)
            #pragma unroll
            for (int r = 0; r < 4; r++) {
                float e = __expf(s[f][r] - mn);
                pv[f][r] = e; ts += e;
            }
        ts += __shfl_xor(ts, 16);
        ts += __shfl_xor(ts, 32);
        lrun = lrun*corr + ts;

        // packed P write: row q=lr, cols k = f*16+lh*4..+3 (consecutive)
        #pragma unroll
        for (int f = 0; f < 4; f++) {
            u16x4 p4 = { f2bf(pv[f][0]), f2bf(pv[f][1]), f2bf(pv[f][2]), f2bf(pv[f][3]) };
            *(u16x4*)((char*)Pt[w] + ((lr*128 + f*32 + lh*8) ^ ((lr & 7) << 4))) = p4;
        }

        // rescale O accumulator (rows q = lh*4 + r): broadcast corr from lane lh*4+r
        float cr0 = __shfl(corr, lh*4 + 0);
        float cr1 = __shfl(corr, lh*4 + 1);
        float cr2 = __shfl(corr, lh*4 + 2);
        float cr3 = __shfl(corr, lh*4 + 3);
        #pragma unroll
        for (int f = 0; f < 4; f++) {
            oacc[f][0] *= cr0; oacc[f][1] *= cr1;
            oacc[f][2] *= cr2; oacc[f][3] *= cr3;
        }

        // PV: O[q][d] += P @ V^T-tile
        bf16x8 pa[2];
        int psw = (lr & 7) << 4;
        pa[0] = *(const bf16x8*)((const char*)Pt[w] + ((lr*128 + lh*16) ^ psw));
        pa[1] = *(const bf16x8*)((const char*)Pt[w] + ((lr*128 + 64 + lh*16) ^ psw));
        #pragma unroll
        for (int f = 0; f < 4; f++) {
            int dl = f*16 + lr, dsw = (dl & 7) << 4;
            #pragma unroll
            for (int c = 0; c < 2; c++) {
                bf16x8 vb = *(const bf16x8*)((const char*)Vts + ((dl*128 + c*64 + lh*16) ^ dsw));
                oacc[f] = __builtin_amdgcn_mfma_f32_16x16x32_bf16(pa[c], vb, oacc[f], 0, 0, 0);
            }
        }
    }

    // epilogue: rows q = q0 + w*16 + lh*4 + r; lrun lives in lane lh*4+r
    float li0 = __shfl(lrun, lh*4 + 0);
    float li1 = __shfl(lrun, lh*4 + 1);
    float li2 = __shfl(lrun, lh*4 + 2);
    float li3 = __shfl(lrun, lh*4 + 3);
    float iv[4] = { 1.f/li0, 1.f/li1, 1.f/li2, 1.f/li3 };
    #pragma unroll
    for (int r = 0; r < 4; r++) {
        int row = q0 + w*16 + lh*4 + r;
        #pragma unroll
        for (int f = 0; f < 4; f++)
            ctx[bc + (size_t)row * Cc + f*16 + lr] = f2bf(oacc[f][r] * iv[r]);
    }
}

extern "C" void kernel_launch(void* const* d_in, const int* in_sizes, int n_in,
                              void* d_out, int out_size, void* d_ws, size_t ws_size,
                              hipStream_t stream) {
    const float* query     = (const float*)d_in[0];
    const float* key       = (const float*)d_in[1];
    const float* g_q       = (const float*)d_in[2];
    const float* b_q       = (const float*)d_in[3];
    const float* g_k       = (const float*)d_in[4];
    const float* b_k       = (const float*)d_in[5];
    const float* in_proj_w = (const float*)d_in[6];
    const float* in_proj_b = (const float*)d_in[7];
    const float* out_w     = (const float*)d_in[8];
    const float* out_b     = (const float*)d_in[9];
    const float* proj_w    = (const float*)d_in[10];
    const float* proj_b    = (const float*)d_in[11];
    const float* rel_table = (const float*)d_in[12];
    const float* g_ffn     = (const float*)d_in[13];
    const float* b_ffn     = (const float*)d_in[14];
    const float* w1        = (const float*)d_in[15];
    const float* w2        = (const float*)d_in[16];
    const float* w3        = (const float*)d_in[17];
    const float* g_out     = (const float*)d_in[18];
    const float* b_out     = (const float*)d_in[19];

    char* p = (char*)d_ws;
    auto alloc = [&](size_t bytes) { char* r = p; p += bytes; return r; };
    const size_t MCb = (size_t)Mm * Cc * 2;
    u16* wA  = (u16*)alloc((size_t)3*Cc*Cc*2);
    u16* wPb = (u16*)alloc((size_t)Cc*Cc*2);
    u16* wOt = (u16*)alloc((size_t)Cc*Cc*2);
    u16* wCb = (u16*)alloc((size_t)Cc*Cc*2);
    u16* w1b = (u16*)alloc((size_t)HIDP*Cc*2);
    u16* w2b = (u16*)alloc((size_t)HIDP*Cc*2);
    u16* w3b = (u16*)alloc((size_t)Cc*HIDP*2);
    float* bc = (float*)alloc(Cc*4);
    float* mr = (float*)alloc(4096*4);
    u16* qn = (u16*)alloc(MCb);
    u16* kn = (u16*)alloc(MCb);
    u16* qp = (u16*)alloc(MCb);      // qp,kp,vp contiguous (mqkv out3)
    u16* kp = (u16*)alloc(MCb);
    u16* vp = (u16*)alloc(MCb);
    u16* vt = (u16*)alloc(MCb);
    float* x  = (float*)alloc((size_t)Mm*Cc*4);
    float* x2 = (float*)alloc((size_t)Mm*Cc*4);
    u16* ctx = qn;   // aliases (lifetimes disjoint)
    u16* h   = qp;
    u16* gf  = vp;   // [4096][1408] bf16 spans vp+part of vt (vt consumed)

    dim3 blk(256);
    // ---- per-launch weight prep ----
    cvt_k<<<(3*Cc*Cc/8 + 255)/256, blk, 0, stream>>>(in_proj_w, wA, 3*Cc, Cc, Cc, 3*Cc*Cc/8);
    cvt_k<<<(Cc*Cc/8 + 255)/256,   blk, 0, stream>>>(proj_w, wPb, Cc, Cc, Cc, Cc*Cc/8);
    cvtT_k<<<dim3(16,16), blk, 0, stream>>>(out_w, wOt);
    cvt_k<<<(HIDP*Cc/8 + 255)/256, blk, 0, stream>>>(w1, w1b, HID, Cc, Cc, HIDP*Cc/8);
    cvt_k<<<(HIDP*Cc/8 + 255)/256, blk, 0, stream>>>(w2, w2b, HID, Cc, Cc, HIDP*Cc/8);
    cvt_k<<<(Cc*HIDP/8 + 255)/256, blk, 0, stream>>>(w3, w3b, Cc, HID, HIDP, Cc*HIDP/8);
    // Wc = proj_w @ out_w  (bf16), bc = proj_w @ out_b + proj_b
    mgemm_k<1,0,0><<<dim3(Cc/128, Cc/128), blk, 0, stream>>>(wPb, wOt, nullptr, nullptr, wCb, Cc, Cc);
    bias_k<<<Cc, blk, 0, stream>>>(proj_w, out_b, proj_b, bc);
    meanrel_k<<<16, blk, 0, stream>>>(rel_table, mr);

    // ---- main chain ----
    ln2_k<<<2*Mm, blk, 0, stream>>>(query, key, g_q, b_q, g_k, b_k, qn, kn);

    dim3 gqkv(Cc/128, Mm/128, 3);
    mqkv_k<<<gqkv, blk, 0, stream>>>(qn, kn, wA, in_proj_b, qp);

    vt_k<<<Bb*Hh*32, blk, 0, stream>>>(vp, vt);
    fattn_k<<<Bb*Hh*32, blk, 0, stream>>>(qp, kp, vt, mr, ctx);

    dim3 g1(Cc/128, Mm/128);
    mgemm_k<0,1,1><<<g1, blk, 0, stream>>>(ctx, wCb, bc, query, x, Cc, Cc);

    ln_k<1><<<Mm, blk, 0, stream>>>(x, g_ffn, b_ffn, h);
    dim3 g2(HIDP/128, Mm/128);
    mswiglu_k<<<g2, blk, 0, stream>>>(h, w1b, w2b, gf, HIDP, Cc);
    dim3 g3(Cc/128, Mm/128);
    mgemm_k<0,1,0><<<g3, blk, 0, stream>>>(gf, w3b, nullptr, x, x2, Cc, HIDP);

    ln_k<0><<<Mm, blk, 0, stream>>>(x2, g_out, b_out, d_out);
}

// Round 5
// 322.582 us; speedup vs baseline: 14.5782x; 1.0744x over previous
//
#include <hip/hip_runtime.h>
#include <hip/hip_bf16.h>

static constexpr int Bb  = 2;
static constexpr int Tt  = 2048;
static constexpr int Cc  = 1024;
static constexpr int Hh  = 16;
static constexpr int HDi = 64;
static constexpr int HID = 1365;
static constexpr int HIDP = 1408;      // HID padded to multiple of 128
static constexpr int Mm  = Bb * Tt;    // 4096 rows

typedef unsigned short u16;
typedef __attribute__((ext_vector_type(8))) short bf16x8;
typedef __attribute__((ext_vector_type(4))) float f32x4;
typedef __attribute__((ext_vector_type(8))) unsigned short u16x8;
typedef __attribute__((ext_vector_type(4))) unsigned short u16x4;

__device__ inline u16 f2bf(float f) {
    unsigned u = __builtin_bit_cast(unsigned, f);
    u += 0x7fffu + ((u >> 16) & 1u);
    return (u16)(u >> 16);
}

__device__ inline unsigned cvtpk(float lo, float hi) {
    unsigned r;
    asm("v_cvt_pk_bf16_f32 %0, %1, %2" : "=v"(r) : "v"(lo), "v"(hi));
    return r;
}

__device__ inline void gl16(const void* g, void* l) {
    __builtin_amdgcn_global_load_lds(
        (const __attribute__((address_space(1))) unsigned*)g,
        (__attribute__((address_space(3))) unsigned*)l, 16, 0, 0);
}

// ---------------- LayerNorm: one row (C=1024) per block; OUTBF: bf16 out ----------------
template<int OUTBF>
__global__ __launch_bounds__(256) void ln_k(const float* __restrict__ x,
                                            const float* __restrict__ g,
                                            const float* __restrict__ b,
                                            void* __restrict__ yv) {
    int row = blockIdx.x;
    int tid = threadIdx.x;
    const float4* xr = (const float4*)(x + (size_t)row * Cc);
    float4 v = xr[tid];
    float s  = v.x + v.y + v.z + v.w;
    float ss = v.x*v.x + v.y*v.y + v.z*v.z + v.w*v.w;
    __shared__ float rs[256], rq[256];
    rs[tid] = s; rq[tid] = ss;
    __syncthreads();
    for (int o = 128; o > 0; o >>= 1) {
        if (tid < o) { rs[tid] += rs[tid+o]; rq[tid] += rq[tid+o]; }
        __syncthreads();
    }
    float mean = rs[0] * (1.f/Cc);
    float var  = rq[0] * (1.f/Cc) - mean*mean;
    float inv  = rsqrtf(var + 1e-5f);
    float4 gv = ((const float4*)g)[tid];
    float4 bv = ((const float4*)b)[tid];
    float o0 = (v.x-mean)*inv*gv.x + bv.x;
    float o1 = (v.y-mean)*inv*gv.y + bv.y;
    float o2 = (v.z-mean)*inv*gv.z + bv.z;
    float o3 = (v.w-mean)*inv*gv.w + bv.w;
    if (OUTBF) {
        u16x4 o4 = { f2bf(o0), f2bf(o1), f2bf(o2), f2bf(o3) };
        ((u16x4*)((u16*)yv + (size_t)row * Cc))[tid] = o4;
    } else {
        float4 o4 = { o0, o1, o2, o3 };
        ((float4*)((float*)yv + (size_t)row * Cc))[tid] = o4;
    }
}

// ---------------- merged LN for query+key -> qn, kn (bf16) ----------------
__global__ __launch_bounds__(256) void ln2_k(const float* __restrict__ q,
                                             const float* __restrict__ k,
                                             const float* __restrict__ gq, const float* __restrict__ bq,
                                             const float* __restrict__ gk, const float* __restrict__ bk,
                                             u16* __restrict__ qn, u16* __restrict__ kn) {
    int row = blockIdx.x;
    const float* x; const float* g; const float* bb; u16* y; int r;
    if (row < Mm) { x = q; g = gq; bb = bq; y = qn; r = row; }
    else          { x = k; g = gk; bb = bk; y = kn; r = row - Mm; }
    int tid = threadIdx.x;
    float4 v = ((const float4*)(x + (size_t)r * Cc))[tid];
    float s  = v.x + v.y + v.z + v.w;
    float ss = v.x*v.x + v.y*v.y + v.z*v.z + v.w*v.w;
    __shared__ float rs[256], rq2[256];
    rs[tid] = s; rq2[tid] = ss;
    __syncthreads();
    for (int o = 128; o > 0; o >>= 1) {
        if (tid < o) { rs[tid] += rs[tid+o]; rq2[tid] += rq2[tid+o]; }
        __syncthreads();
    }
    float mean = rs[0] * (1.f/Cc);
    float var  = rq2[0] * (1.f/Cc) - mean*mean;
    float inv  = rsqrtf(var + 1e-5f);
    float4 gv = ((const float4*)g)[tid];
    float4 bv = ((const float4*)bb)[tid];
    u16x4 o4 = { f2bf((v.x-mean)*inv*gv.x + bv.x), f2bf((v.y-mean)*inv*gv.y + bv.y),
                 f2bf((v.z-mean)*inv*gv.z + bv.z), f2bf((v.w-mean)*inv*gv.w + bv.w) };
    ((u16x4*)(y + (size_t)r * Cc))[tid] = o4;
}

// ---------------- mean over heads of rel_table -> mr[4095] ----------------
__global__ __launch_bounds__(256) void meanrel_k(const float* __restrict__ rel,
                                                 float* __restrict__ mr) {
    int j = blockIdx.x * 256 + threadIdx.x;
    if (j < 2*Tt - 1) {
        float s = 0.f;
        #pragma unroll
        for (int h = 0; h < Hh; h++) s += rel[(size_t)h * (2*Tt - 1) + j];
        mr[j] = s * (1.f/Hh);
    }
}

// ---------------- f32 -> bf16 with zero padding ----------------
__global__ __launch_bounds__(256) void cvt_k(const float* __restrict__ src,
                                             u16* __restrict__ dst,
                                             int Rs, int Cs, int Cd, int total8) {
    int idx = blockIdx.x * 256 + threadIdx.x;
    if (idx >= total8) return;
    int e0 = idx * 8;
    int r = e0 / Cd, c0 = e0 - r * Cd;
    u16x8 o;
    #pragma unroll
    for (int j = 0; j < 8; j++) {
        int c = c0 + j;
        float v = (r < Rs && c < Cs) ? src[(size_t)r * Cs + c] : 0.f;
        o[j] = f2bf(v);
    }
    *(u16x8*)(dst + (size_t)e0) = o;
}

// ---------------- transposed cvt: dst[j][c] = src[c][j], 1024x1024 f32->bf16 ----------------
__global__ __launch_bounds__(256) void cvtT_k(const float* __restrict__ src,
                                              u16* __restrict__ dst) {
    __shared__ float t[64][65];
    int j0 = blockIdx.x * 64, c0 = blockIdx.y * 64;
    int tid = threadIdx.x;
    #pragma unroll
    for (int i = 0; i < 16; i++) {
        int e = tid + i*256;
        int c = e >> 6, j = e & 63;
        t[c][j] = src[(size_t)(c0 + c) * Cc + j0 + j];
    }
    __syncthreads();
    #pragma unroll
    for (int i = 0; i < 16; i++) {
        int e = tid + i*256;
        int j = e >> 6, c = e & 63;
        dst[(size_t)(j0 + j) * Cc + c0 + c] = f2bf(t[c][j]);
    }
}

// ---------------- combined bias: bc[i] = dot(proj_w[i,:], out_b) + proj_b[i] ----------------
__global__ __launch_bounds__(256) void bias_k(const float* __restrict__ wp,
                                              const float* __restrict__ bo,
                                              const float* __restrict__ bp,
                                              float* __restrict__ bc) {
    int i = blockIdx.x, tid = threadIdx.x;
    float4 w = ((const float4*)(wp + (size_t)i * Cc))[tid];
    float4 b = ((const float4*)bo)[tid];
    float s = w.x*b.x + w.y*b.y + w.z*b.z + w.w*b.w;
    __shared__ float red[256];
    red[tid] = s; __syncthreads();
    for (int o = 128; o > 0; o >>= 1) {
        if (tid < o) red[tid] += red[tid+o];
        __syncthreads();
    }
    if (tid == 0) bc[i] = red[0] + bp[i];
}

// ---------------- bf16 MFMA GEMM 128x128 tile ----------------
template<int OUTBF, int HASRES, int HASBIAS>
__global__ __launch_bounds__(256) void mgemm_k(const u16* __restrict__ A,
                                               const u16* __restrict__ W,
                                               const float* __restrict__ bias,
                                               const float* __restrict__ res,
                                               void* __restrict__ outv,
                                               int N, int K) {
    __shared__ u16 As[128*32];
    __shared__ u16 Ws[128*32];
    int bm = blockIdx.y * 128, bn = blockIdx.x * 128;
    int tid = threadIdx.x, w = tid >> 6, l = tid & 63;
    int lr = l & 15, lh = l >> 4;
    int wm = (w >> 1) * 64, wn = (w & 1) * 64;
    f32x4 acc[4][4] = {};

    for (int kt = 0; kt < K; kt += 32) {
        __syncthreads();
        #pragma unroll
        for (int c = 0; c < 2; c++) {
            int i = w*128 + c*64 + l;
            int row = i >> 2, slot = i & 3;
            int ko = kt + ((slot ^ (row & 3)) << 3);
            gl16(A + (size_t)(bm + row) * K + ko, (char*)As + (w*128 + c*64) * 16);
            gl16(W + (size_t)(bn + row) * K + ko, (char*)Ws + (w*128 + c*64) * 16);
        }
        __syncthreads();
        bf16x8 af[4], wf[4];
        #pragma unroll
        for (int f = 0; f < 4; f++) {
            int r = wm + f*16 + lr;
            af[f] = *(const bf16x8*)((const char*)As + r*64 + ((lh ^ (r & 3)) << 4));
            int rn = wn + f*16 + lr;
            wf[f] = *(const bf16x8*)((const char*)Ws + rn*64 + ((lh ^ (rn & 3)) << 4));
        }
        #pragma unroll
        for (int fm = 0; fm < 4; fm++)
            #pragma unroll
            for (int fn = 0; fn < 4; fn++)
                acc[fm][fn] = __builtin_amdgcn_mfma_f32_16x16x32_bf16(af[fm], wf[fn], acc[fm][fn], 0, 0, 0);
    }

    #pragma unroll
    for (int fm = 0; fm < 4; fm++) {
        #pragma unroll
        for (int r = 0; r < 4; r++) {
            int row = bm + wm + fm*16 + lh*4 + r;
            #pragma unroll
            for (int fn = 0; fn < 4; fn++) {
                int col = bn + wn + fn*16 + lr;
                float v = acc[fm][fn][r];
                if (HASBIAS) v += bias[col];
                if (HASRES)  v += res[(size_t)row * N + col];
                if (OUTBF) ((u16*)outv)[(size_t)row * N + col] = f2bf(v);
                else       ((float*)outv)[(size_t)row * N + col] = v;
            }
        }
    }
}

// ---------------- bf16 MFMA GEMM 64x128 tile (2 blocks/CU occupancy variant) ----------------
template<int OUTBF, int HASRES, int HASBIAS>
__global__ __launch_bounds__(256) void mgemm64_k(const u16* __restrict__ A,
                                                 const u16* __restrict__ W,
                                                 const float* __restrict__ bias,
                                                 const float* __restrict__ res,
                                                 void* __restrict__ outv,
                                                 int N, int K) {
    __shared__ u16 As[64*32];
    __shared__ u16 Ws[128*32];
    int bm = blockIdx.y * 64, bn = blockIdx.x * 128;
    int tid = threadIdx.x, w = tid >> 6, l = tid & 63;
    int lr = l & 15, lh = l >> 4;
    int wm = (w >> 1) * 32, wn = (w & 1) * 64;
    f32x4 acc[2][4] = {};

    for (int kt = 0; kt < K; kt += 32) {
        __syncthreads();
        {
            int row = tid >> 2, slot = tid & 3;
            int ko = kt + ((slot ^ (row & 3)) << 3);
            gl16(A + (size_t)(bm + row) * K + ko, (char*)As + tid * 16);
        }
        #pragma unroll
        for (int c = 0; c < 2; c++) {
            int i = c*256 + tid;
            int row = i >> 2, slot = i & 3;
            int ko = kt + ((slot ^ (row & 3)) << 3);
            gl16(W + (size_t)(bn + row) * K + ko, (char*)Ws + (c*256 + tid) * 16);
        }
        __syncthreads();
        bf16x8 af[2], wf[4];
        #pragma unroll
        for (int f = 0; f < 2; f++) {
            int r = wm + f*16 + lr;
            af[f] = *(const bf16x8*)((const char*)As + r*64 + ((lh ^ (r & 3)) << 4));
        }
        #pragma unroll
        for (int f = 0; f < 4; f++) {
            int rn = wn + f*16 + lr;
            wf[f] = *(const bf16x8*)((const char*)Ws + rn*64 + ((lh ^ (rn & 3)) << 4));
        }
        #pragma unroll
        for (int fm = 0; fm < 2; fm++)
            #pragma unroll
            for (int fn = 0; fn < 4; fn++)
                acc[fm][fn] = __builtin_amdgcn_mfma_f32_16x16x32_bf16(af[fm], wf[fn], acc[fm][fn], 0, 0, 0);
    }

    #pragma unroll
    for (int fm = 0; fm < 2; fm++) {
        #pragma unroll
        for (int r = 0; r < 4; r++) {
            int row = bm + wm + fm*16 + lh*4 + r;
            #pragma unroll
            for (int fn = 0; fn < 4; fn++) {
                int col = bn + wn + fn*16 + lr;
                float v = acc[fm][fn][r];
                if (HASBIAS) v += bias[col];
                if (HASRES)  v += res[(size_t)row * N + col];
                if (OUTBF) ((u16*)outv)[(size_t)row * N + col] = f2bf(v);
                else       ((float*)outv)[(size_t)row * N + col] = v;
            }
        }
    }
}

// ---------------- merged QKV projection ----------------
__global__ __launch_bounds__(256) void mqkv_k(const u16* __restrict__ qn,
                                              const u16* __restrict__ kn,
                                              const u16* __restrict__ wA,
                                              const float* __restrict__ bias3,
                                              u16* __restrict__ out3) {
    int z = blockIdx.z;
    const u16* A = z ? kn : qn;
    const u16* W = wA + (size_t)z * Cc * Cc;
    const float* bias = bias3 + z * Cc;
    u16* out = out3 + (size_t)z * Mm * Cc;

    __shared__ u16 As[128*32];
    __shared__ u16 Ws[128*32];
    int bm = blockIdx.y * 128, bn = blockIdx.x * 128;
    int tid = threadIdx.x, w = tid >> 6, l = tid & 63;
    int lr = l & 15, lh = l >> 4;
    int wm = (w >> 1) * 64, wn = (w & 1) * 64;
    f32x4 acc[4][4] = {};

    for (int kt = 0; kt < Cc; kt += 32) {
        __syncthreads();
        #pragma unroll
        for (int c = 0; c < 2; c++) {
            int i = w*128 + c*64 + l;
            int row = i >> 2, slot = i & 3;
            int ko = kt + ((slot ^ (row & 3)) << 3);
            gl16(A + (size_t)(bm + row) * Cc + ko, (char*)As + (w*128 + c*64) * 16);
            gl16(W + (size_t)(bn + row) * Cc + ko, (char*)Ws + (w*128 + c*64) * 16);
        }
        __syncthreads();
        bf16x8 af[4], wf[4];
        #pragma unroll
        for (int f = 0; f < 4; f++) {
            int r = wm + f*16 + lr;
            af[f] = *(const bf16x8*)((const char*)As + r*64 + ((lh ^ (r & 3)) << 4));
            int rn = wn + f*16 + lr;
            wf[f] = *(const bf16x8*)((const char*)Ws + rn*64 + ((lh ^ (rn & 3)) << 4));
        }
        #pragma unroll
        for (int fm = 0; fm < 4; fm++)
            #pragma unroll
            for (int fn = 0; fn < 4; fn++)
                acc[fm][fn] = __builtin_amdgcn_mfma_f32_16x16x32_bf16(af[fm], wf[fn], acc[fm][fn], 0, 0, 0);
    }

    #pragma unroll
    for (int fm = 0; fm < 4; fm++) {
        #pragma unroll
        for (int r = 0; r < 4; r++) {
            int row = bm + wm + fm*16 + lh*4 + r;
            #pragma unroll
            for (int fn = 0; fn < 4; fn++) {
                int col = bn + wn + fn*16 + lr;
                out[(size_t)row * Cc + col] = f2bf(acc[fm][fn][r] + bias[col]);
            }
        }
    }
}

// ---------------- fused SwiGLU MFMA GEMM, 64x128 tile ----------------
__global__ __launch_bounds__(256) void mswiglu64_k(const u16* __restrict__ A,
                                                   const u16* __restrict__ W1,
                                                   const u16* __restrict__ W2,
                                                   u16* __restrict__ out,
                                                   int N, int K) {
    __shared__ u16 As[64*32];
    __shared__ u16 W1s[128*32];
    __shared__ u16 W2s[128*32];
    int bm = blockIdx.y * 64, bn = blockIdx.x * 128;
    int tid = threadIdx.x, w = tid >> 6, l = tid & 63;
    int lr = l & 15, lh = l >> 4;
    int wm = (w >> 1) * 32, wn = (w & 1) * 64;
    f32x4 acc1[2][4] = {};
    f32x4 acc2[2][4] = {};

    for (int kt = 0; kt < K; kt += 32) {
        __syncthreads();
        {
            int row = tid >> 2, slot = tid & 3;
            int ko = kt + ((slot ^ (row & 3)) << 3);
            gl16(A + (size_t)(bm + row) * K + ko, (char*)As + tid * 16);
        }
        #pragma unroll
        for (int c = 0; c < 2; c++) {
            int i = c*256 + tid;
            int row = i >> 2, slot = i & 3;
            int ko = kt + ((slot ^ (row & 3)) << 3);
            gl16(W1 + (size_t)(bn + row) * K + ko, (char*)W1s + (c*256 + tid) * 16);
            gl16(W2 + (size_t)(bn + row) * K + ko, (char*)W2s + (c*256 + tid) * 16);
        }
        __syncthreads();
        bf16x8 af[2], w1f[4], w2f[4];
        #pragma unroll
        for (int f = 0; f < 2; f++) {
            int r = wm + f*16 + lr;
            af[f] = *(const bf16x8*)((const char*)As + r*64 + ((lh ^ (r & 3)) << 4));
        }
        #pragma unroll
        for (int f = 0; f < 4; f++) {
            int rn = wn + f*16 + lr;
            int offn = rn*64 + ((lh ^ (rn & 3)) << 4);
            w1f[f] = *(const bf16x8*)((const char*)W1s + offn);
            w2f[f] = *(const bf16x8*)((const char*)W2s + offn);
        }
        #pragma unroll
        for (int fm = 0; fm < 2; fm++)
            #pragma unroll
            for (int fn = 0; fn < 4; fn++) {
                acc1[fm][fn] = __builtin_amdgcn_mfma_f32_16x16x32_bf16(af[fm], w1f[fn], acc1[fm][fn], 0, 0, 0);
                acc2[fm][fn] = __builtin_amdgcn_mfma_f32_16x16x32_bf16(af[fm], w2f[fn], acc2[fm][fn], 0, 0, 0);
            }
    }

    #pragma unroll
    for (int fm = 0; fm < 2; fm++) {
        #pragma unroll
        for (int r = 0; r < 4; r++) {
            int row = bm + wm + fm*16 + lh*4 + r;
            #pragma unroll
            for (int fn = 0; fn < 4; fn++) {
                int col = bn + wn + fn*16 + lr;
                float a = acc1[fm][fn][r];
                float sig = 1.f / (1.f + __expf(-a));
                out[(size_t)row * N + col] = f2bf(a * sig * acc2[fm][fn][r]);
            }
        }
    }
}

// ---------------- V transpose (bf16): vp[B,T,C](head cols) -> vt[B*H, 64, T] ----------------
__global__ __launch_bounds__(256) void vt_k(const u16* __restrict__ vp,
                                            u16* __restrict__ vt) {
    int blk = blockIdx.x;             // bh*32 + kb
    int bh = blk >> 5, kb = blk & 31;
    int b = bh >> 4, h = bh & 15;
    __shared__ u16 t[64][65];
    int tid = threadIdx.x;
    size_t bc = (size_t)b*Tt*Cc + (size_t)h*HDi;
    #pragma unroll
    for (int i = 0; i < 16; i++) {
        int e = tid + i*256;
        int k = e >> 6, d = e & 63;
        t[d][k] = vp[bc + (size_t)(kb*64 + k)*Cc + d];
    }
    __syncthreads();
    #pragma unroll
    for (int i = 0; i < 16; i++) {
        int e = tid + i*256;
        int d = e >> 6, k = e & 63;
        vt[((size_t)bh*64 + d)*Tt + kb*64 + k] = t[d][k];
    }
}

// ---------------- MFMA flash attention: exp2-domain softmax, defer-max, cvt_pk ----------------
__global__ __launch_bounds__(256) void fattn_k(const u16* __restrict__ qp,
                                               const u16* __restrict__ kp,
                                               const u16* __restrict__ vt,
                                               const float* __restrict__ mr,
                                               u16* __restrict__ ctx) {
    __shared__ u16 Kt[4096];        // [64 k][64 d], swizzled
    __shared__ u16 Vts[4096];       // [64 d][64 k], swizzled
    __shared__ u16 Pt[4][1024];     // per-wave [16 q][64 k], swizzled
    __shared__ float mrw[2112];     // rel-bias window, pre-scaled by 8

    constexpr float C1 = 0.18033688011118324f;   // 0.125 * log2(e)

    int blk = blockIdx.x;
    int qt = blk & 31, h = (blk >> 5) & 15, b = blk >> 9;
    int q0 = qt * 64;
    int tid = threadIdx.x, w = tid >> 6, l = tid & 63;
    int lr = l & 15, lh = l >> 4;
    size_t bc = (size_t)b * Tt * Cc + (size_t)h * HDi;
    const u16* vtb = vt + (size_t)(b*Hh + h) * HDi * Tt;

    for (int i = tid; i < 2111; i += 256) mrw[i] = mr[q0 + i] * 8.f;

    bf16x8 qa[2];
    {
        const u16* qrow = qp + bc + (size_t)(q0 + w*16 + lr) * Cc;
        qa[0] = *(const bf16x8*)(qrow + lh*8);
        qa[1] = *(const bf16x8*)(qrow + 32 + lh*8);
    }

    f32x4 oacc[4] = {};
    float mrun = -1e30f, lrun = 0.f;

    int wb = (tid & 192) * 16;

    for (int kt = 0; kt < 32; kt++) {
        __syncthreads();
        #pragma unroll
        for (int ps = 0; ps < 2; ps++) {
            int i = ps*256 + tid;
            int kr = i >> 3, sl = i & 7;
            int so = (sl ^ (kr & 7)) << 3;
            gl16(kp + bc + (size_t)(kt*64 + kr) * Cc + so, (char*)Kt + ps*4096 + wb);
            gl16(vtb + (size_t)kr * Tt + kt*64 + so,       (char*)Vts + ps*4096 + wb);
        }
        __syncthreads();

        // QK^T swapped: s[f] = D[k = f*16+lh*4+r][q = lr]
        f32x4 s[4] = {};
        #pragma unroll
        for (int f = 0; f < 4; f++) {
            int kl = f*16 + lr, ksw = (kl & 7) << 4;
            #pragma unroll
            for (int c = 0; c < 2; c++) {
                bf16x8 kb = *(const bf16x8*)((const char*)Kt + ((kl*128 + c*64 + lh*16) ^ ksw));
                s[f] = __builtin_amdgcn_mfma_f32_16x16x32_bf16(kb, qa[c], s[f], 0, 0, 0);
            }
        }

        // v = s_raw + 8*mask; tile max
        int ib = w*16 + lr - kt*64 - lh*4 + 2047;
        float tm = -1e30f;
        #pragma unroll
        for (int f = 0; f < 4; f++)
            #pragma unroll
            for (int r = 0; r < 4; r++) {
                float v = s[f][r] + mrw[ib - f*16 - r];
                s[f][r] = v;
                tm = fmaxf(tm, v);
            }
        tm = fmaxf(tm, __shfl_xor(tm, 16));
        tm = fmaxf(tm, __shfl_xor(tm, 32));

        float pv[4][4];
        if (__all(tm <= mrun + 64.f)) {
            // defer-max: keep mn=mrun, corr=1, no rescale
            float mnc = mrun * C1;
            float ts = 0.f;
            #pragma unroll
            for (int f = 0; f < 4; f++)
                #pragma unroll
                for (int r = 0; r < 4; r++) {
                    float e = exp2f(s[f][r]*C1 - mnc);
                    pv[f][r] = e; ts += e;
                }
            ts += __shfl_xor(ts, 16);
            ts += __shfl_xor(ts, 32);
            lrun += ts;
        } else {
            float mn = fmaxf(mrun, tm);
            float corr = exp2f((mrun - mn) * C1);
            mrun = mn;
            float mnc = mn * C1;
            float ts = 0.f;
            #pragma unroll
            for (int f = 0; f < 4; f++)
                #pragma unroll
                for (int r = 0; r < 4; r++) {
                    float e = exp2f(s[f][r]*C1 - mnc);
                    pv[f][r] = e; ts += e;
                }
            ts += __shfl_xor(ts, 16);
            ts += __shfl_xor(ts, 32);
            lrun = lrun*corr + ts;
            float cr0 = __shfl(corr, lh*4 + 0);
            float cr1 = __shfl(corr, lh*4 + 1);
            float cr2 = __shfl(corr, lh*4 + 2);
            float cr3 = __shfl(corr, lh*4 + 3);
            #pragma unroll
            for (int f = 0; f < 4; f++) {
                oacc[f][0] *= cr0; oacc[f][1] *= cr1;
                oacc[f][2] *= cr2; oacc[f][3] *= cr3;
            }
        }

        // packed P write via cvt_pk: row q=lr, cols k = f*16+lh*4..+3
        #pragma unroll
        for (int f = 0; f < 4; f++) {
            uint2 p2 = { cvtpk(pv[f][0], pv[f][1]), cvtpk(pv[f][2], pv[f][3]) };
            *(uint2*)((char*)Pt[w] + ((lr*128 + f*32 + lh*8) ^ ((lr & 7) << 4))) = p2;
        }

        // PV
        bf16x8 pa[2];
        int psw = (lr & 7) << 4;
        pa[0] = *(const bf16x8*)((const char*)Pt[w] + ((lr*128 + lh*16) ^ psw));
        pa[1] = *(const bf16x8*)((const char*)Pt[w] + ((lr*128 + 64 + lh*16) ^ psw));
        #pragma unroll
        for (int f = 0; f < 4; f++) {
            int dl = f*16 + lr, dsw = (dl & 7) << 4;
            #pragma unroll
            for (int c = 0; c < 2; c++) {
                bf16x8 vb = *(const bf16x8*)((const char*)Vts + ((dl*128 + c*64 + lh*16) ^ dsw));
                oacc[f] = __builtin_amdgcn_mfma_f32_16x16x32_bf16(pa[c], vb, oacc[f], 0, 0, 0);
            }
        }
    }

    float li0 = __shfl(lrun, lh*4 + 0);
    float li1 = __shfl(lrun, lh*4 + 1);
    float li2 = __shfl(lrun, lh*4 + 2);
    float li3 = __shfl(lrun, lh*4 + 3);
    float iv[4] = { 1.f/li0, 1.f/li1, 1.f/li2, 1.f/li3 };
    #pragma unroll
    for (int r = 0; r < 4; r++) {
        int row = q0 + w*16 + lh*4 + r;
        #pragma unroll
        for (int f = 0; f < 4; f++)
            ctx[bc + (size_t)row * Cc + f*16 + lr] = f2bf(oacc[f][r] * iv[r]);
    }
}

extern "C" void kernel_launch(void* const* d_in, const int* in_sizes, int n_in,
                              void* d_out, int out_size, void* d_ws, size_t ws_size,
                              hipStream_t stream) {
    const float* query     = (const float*)d_in[0];
    const float* key       = (const float*)d_in[1];
    const float* g_q       = (const float*)d_in[2];
    const float* b_q       = (const float*)d_in[3];
    const float* g_k       = (const float*)d_in[4];
    const float* b_k       = (const float*)d_in[5];
    const float* in_proj_w = (const float*)d_in[6];
    const float* in_proj_b = (const float*)d_in[7];
    const float* out_w     = (const float*)d_in[8];
    const float* out_b     = (const float*)d_in[9];
    const float* proj_w    = (const float*)d_in[10];
    const float* proj_b    = (const float*)d_in[11];
    const float* rel_table = (const float*)d_in[12];
    const float* g_ffn     = (const float*)d_in[13];
    const float* b_ffn     = (const float*)d_in[14];
    const float* w1        = (const float*)d_in[15];
    const float* w2        = (const float*)d_in[16];
    const float* w3        = (const float*)d_in[17];
    const float* g_out     = (const float*)d_in[18];
    const float* b_out     = (const float*)d_in[19];

    char* p = (char*)d_ws;
    auto alloc = [&](size_t bytes) { char* r = p; p += bytes; return r; };
    const size_t MCb = (size_t)Mm * Cc * 2;
    u16* wA  = (u16*)alloc((size_t)3*Cc*Cc*2);
    u16* wPb = (u16*)alloc((size_t)Cc*Cc*2);
    u16* wOt = (u16*)alloc((size_t)Cc*Cc*2);
    u16* wCb = (u16*)alloc((size_t)Cc*Cc*2);
    u16* w1b = (u16*)alloc((size_t)HIDP*Cc*2);
    u16* w2b = (u16*)alloc((size_t)HIDP*Cc*2);
    u16* w3b = (u16*)alloc((size_t)Cc*HIDP*2);
    float* bc = (float*)alloc(Cc*4);
    float* mr = (float*)alloc(4096*4);
    u16* qn = (u16*)alloc(MCb);
    u16* kn = (u16*)alloc(MCb);
    u16* qp = (u16*)alloc(MCb);      // qp,kp,vp contiguous (mqkv out3)
    u16* kp = (u16*)alloc(MCb);
    u16* vp = (u16*)alloc(MCb);
    u16* vt = (u16*)alloc(MCb);
    float* x  = (float*)alloc((size_t)Mm*Cc*4);
    float* x2 = (float*)alloc((size_t)Mm*Cc*4);
    u16* ctx = qn;   // aliases (lifetimes disjoint)
    u16* h   = qp;
    u16* gf  = vp;   // [4096][1408] bf16 spans vp+part of vt

    dim3 blk(256);
    // ---- per-launch weight prep ----
    cvt_k<<<(3*Cc*Cc/8 + 255)/256, blk, 0, stream>>>(in_proj_w, wA, 3*Cc, Cc, Cc, 3*Cc*Cc/8);
    cvt_k<<<(Cc*Cc/8 + 255)/256,   blk, 0, stream>>>(proj_w, wPb, Cc, Cc, Cc, Cc*Cc/8);
    cvtT_k<<<dim3(16,16), blk, 0, stream>>>(out_w, wOt);
    cvt_k<<<(HIDP*Cc/8 + 255)/256, blk, 0, stream>>>(w1, w1b, HID, Cc, Cc, HIDP*Cc/8);
    cvt_k<<<(HIDP*Cc/8 + 255)/256, blk, 0, stream>>>(w2, w2b, HID, Cc, Cc, HIDP*Cc/8);
    cvt_k<<<(Cc*HIDP/8 + 255)/256, blk, 0, stream>>>(w3, w3b, Cc, HID, HIDP, Cc*HIDP/8);
    mgemm_k<1,0,0><<<dim3(Cc/128, Cc/128), blk, 0, stream>>>(wPb, wOt, nullptr, nullptr, wCb, Cc, Cc);
    bias_k<<<Cc, blk, 0, stream>>>(proj_w, out_b, proj_b, bc);
    meanrel_k<<<16, blk, 0, stream>>>(rel_table, mr);

    // ---- main chain ----
    ln2_k<<<2*Mm, blk, 0, stream>>>(query, key, g_q, b_q, g_k, b_k, qn, kn);

    dim3 gqkv(Cc/128, Mm/128, 3);
    mqkv_k<<<gqkv, blk, 0, stream>>>(qn, kn, wA, in_proj_b, qp);

    vt_k<<<Bb*Hh*32, blk, 0, stream>>>(vp, vt);
    fattn_k<<<Bb*Hh*32, blk, 0, stream>>>(qp, kp, vt, mr, ctx);

    dim3 g1(Cc/128, Mm/64);
    mgemm64_k<0,1,1><<<g1, blk, 0, stream>>>(ctx, wCb, bc, query, x, Cc, Cc);

    ln_k<1><<<Mm, blk, 0, stream>>>(x, g_ffn, b_ffn, h);
    dim3 g2(HIDP/128, Mm/64);
    mswiglu64_k<<<g2, blk, 0, stream>>>(h, w1b, w2b, gf, HIDP, Cc);
    dim3 g3(Cc/128, Mm/64);
    mgemm64_k<0,1,0><<<g3, blk, 0, stream>>>(gf, w3b, nullptr, x, x2, Cc, HIDP);

    ln_k<0><<<Mm, blk, 0, stream>>>(x2, g_out, b_out, d_out);
}

// Round 6
// 313.564 us; speedup vs baseline: 14.9975x; 1.0288x over previous
//
#include <hip/hip_runtime.h>
#include <hip/hip_bf16.h>

static constexpr int Bb  = 2;
static constexpr int Tt  = 2048;
static constexpr int Cc  = 1024;
static constexpr int Hh  = 16;
static constexpr int HDi = 64;
static constexpr int HID = 1365;
static constexpr int HIDP = 1408;      // HID padded to multiple of 128
static constexpr int Mm  = Bb * Tt;    // 4096 rows

typedef unsigned short u16;
typedef __attribute__((ext_vector_type(8))) short bf16x8;
typedef __attribute__((ext_vector_type(4))) float f32x4;
typedef __attribute__((ext_vector_type(8))) unsigned short u16x8;
typedef __attribute__((ext_vector_type(4))) unsigned short u16x4;

__device__ inline u16 f2bf(float f) {
    unsigned u = __builtin_bit_cast(unsigned, f);
    u += 0x7fffu + ((u >> 16) & 1u);
    return (u16)(u >> 16);
}

__device__ inline unsigned cvtpk(float lo, float hi) {
    unsigned r;
    asm("v_cvt_pk_bf16_f32 %0, %1, %2" : "=v"(r) : "v"(lo), "v"(hi));
    return r;
}

__device__ inline void gl16(const void* g, void* l) {
    __builtin_amdgcn_global_load_lds(
        (const __attribute__((address_space(1))) unsigned*)g,
        (__attribute__((address_space(3))) unsigned*)l, 16, 0, 0);
}

// ---------------- LayerNorm: one row (C=1024) per block; OUTBF: bf16 out ----------------
template<int OUTBF>
__global__ __launch_bounds__(256) void ln_k(const float* __restrict__ x,
                                            const float* __restrict__ g,
                                            const float* __restrict__ b,
                                            void* __restrict__ yv) {
    int row = blockIdx.x;
    int tid = threadIdx.x;
    const float4* xr = (const float4*)(x + (size_t)row * Cc);
    float4 v = xr[tid];
    float s  = v.x + v.y + v.z + v.w;
    float ss = v.x*v.x + v.y*v.y + v.z*v.z + v.w*v.w;
    __shared__ float rs[256], rq[256];
    rs[tid] = s; rq[tid] = ss;
    __syncthreads();
    for (int o = 128; o > 0; o >>= 1) {
        if (tid < o) { rs[tid] += rs[tid+o]; rq[tid] += rq[tid+o]; }
        __syncthreads();
    }
    float mean = rs[0] * (1.f/Cc);
    float var  = rq[0] * (1.f/Cc) - mean*mean;
    float inv  = rsqrtf(var + 1e-5f);
    float4 gv = ((const float4*)g)[tid];
    float4 bv = ((const float4*)b)[tid];
    float o0 = (v.x-mean)*inv*gv.x + bv.x;
    float o1 = (v.y-mean)*inv*gv.y + bv.y;
    float o2 = (v.z-mean)*inv*gv.z + bv.z;
    float o3 = (v.w-mean)*inv*gv.w + bv.w;
    if (OUTBF) {
        u16x4 o4 = { f2bf(o0), f2bf(o1), f2bf(o2), f2bf(o3) };
        ((u16x4*)((u16*)yv + (size_t)row * Cc))[tid] = o4;
    } else {
        float4 o4 = { o0, o1, o2, o3 };
        ((float4*)((float*)yv + (size_t)row * Cc))[tid] = o4;
    }
}

// ---------------- merged LN for query+key -> qn, kn (bf16) ----------------
__global__ __launch_bounds__(256) void ln2_k(const float* __restrict__ q,
                                             const float* __restrict__ k,
                                             const float* __restrict__ gq, const float* __restrict__ bq,
                                             const float* __restrict__ gk, const float* __restrict__ bk,
                                             u16* __restrict__ qn, u16* __restrict__ kn) {
    int row = blockIdx.x;
    const float* x; const float* g; const float* bb; u16* y; int r;
    if (row < Mm) { x = q; g = gq; bb = bq; y = qn; r = row; }
    else          { x = k; g = gk; bb = bk; y = kn; r = row - Mm; }
    int tid = threadIdx.x;
    float4 v = ((const float4*)(x + (size_t)r * Cc))[tid];
    float s  = v.x + v.y + v.z + v.w;
    float ss = v.x*v.x + v.y*v.y + v.z*v.z + v.w*v.w;
    __shared__ float rs[256], rq2[256];
    rs[tid] = s; rq2[tid] = ss;
    __syncthreads();
    for (int o = 128; o > 0; o >>= 1) {
        if (tid < o) { rs[tid] += rs[tid+o]; rq2[tid] += rq2[tid+o]; }
        __syncthreads();
    }
    float mean = rs[0] * (1.f/Cc);
    float var  = rq2[0] * (1.f/Cc) - mean*mean;
    float inv  = rsqrtf(var + 1e-5f);
    float4 gv = ((const float4*)g)[tid];
    float4 bv = ((const float4*)bb)[tid];
    u16x4 o4 = { f2bf((v.x-mean)*inv*gv.x + bv.x), f2bf((v.y-mean)*inv*gv.y + bv.y),
                 f2bf((v.z-mean)*inv*gv.z + bv.z), f2bf((v.w-mean)*inv*gv.w + bv.w) };
    ((u16x4*)(y + (size_t)r * Cc))[tid] = o4;
}

// ---------------- mean over heads of rel_table -> mr[4095] ----------------
__global__ __launch_bounds__(256) void meanrel_k(const float* __restrict__ rel,
                                                 float* __restrict__ mr) {
    int j = blockIdx.x * 256 + threadIdx.x;
    if (j < 2*Tt - 1) {
        float s = 0.f;
        #pragma unroll
        for (int h = 0; h < Hh; h++) s += rel[(size_t)h * (2*Tt - 1) + j];
        mr[j] = s * (1.f/Hh);
    }
}

// ---------------- f32 -> bf16 with zero padding ----------------
__global__ __launch_bounds__(256) void cvt_k(const float* __restrict__ src,
                                             u16* __restrict__ dst,
                                             int Rs, int Cs, int Cd, int total8) {
    int idx = blockIdx.x * 256 + threadIdx.x;
    if (idx >= total8) return;
    int e0 = idx * 8;
    int r = e0 / Cd, c0 = e0 - r * Cd;
    u16x8 o;
    #pragma unroll
    for (int j = 0; j < 8; j++) {
        int c = c0 + j;
        float v = (r < Rs && c < Cs) ? src[(size_t)r * Cs + c] : 0.f;
        o[j] = f2bf(v);
    }
    *(u16x8*)(dst + (size_t)e0) = o;
}

// ---------------- transposed cvt: dst[j][c] = src[c][j], 1024x1024 f32->bf16 ----------------
__global__ __launch_bounds__(256) void cvtT_k(const float* __restrict__ src,
                                              u16* __restrict__ dst) {
    __shared__ float t[64][65];
    int j0 = blockIdx.x * 64, c0 = blockIdx.y * 64;
    int tid = threadIdx.x;
    #pragma unroll
    for (int i = 0; i < 16; i++) {
        int e = tid + i*256;
        int c = e >> 6, j = e & 63;
        t[c][j] = src[(size_t)(c0 + c) * Cc + j0 + j];
    }
    __syncthreads();
    #pragma unroll
    for (int i = 0; i < 16; i++) {
        int e = tid + i*256;
        int j = e >> 6, c = e & 63;
        dst[(size_t)(j0 + j) * Cc + c0 + c] = f2bf(t[c][j]);
    }
}

// ---------------- combined bias: bc[i] = dot(proj_w[i,:], out_b) + proj_b[i] ----------------
__global__ __launch_bounds__(256) void bias_k(const float* __restrict__ wp,
                                              const float* __restrict__ bo,
                                              const float* __restrict__ bp,
                                              float* __restrict__ bc) {
    int i = blockIdx.x, tid = threadIdx.x;
    float4 w = ((const float4*)(wp + (size_t)i * Cc))[tid];
    float4 b = ((const float4*)bo)[tid];
    float s = w.x*b.x + w.y*b.y + w.z*b.z + w.w*b.w;
    __shared__ float red[256];
    red[tid] = s; __syncthreads();
    for (int o = 128; o > 0; o >>= 1) {
        if (tid < o) red[tid] += red[tid+o];
        __syncthreads();
    }
    if (tid == 0) bc[i] = red[0] + bp[i];
}

// ---------------- bf16 MFMA GEMM 128x128 tile, dbuf + 1 barrier/K-step ----------------
template<int OUTBF, int HASRES, int HASBIAS>
__global__ __launch_bounds__(256) void mgemm_k(const u16* __restrict__ A,
                                               const u16* __restrict__ W,
                                               const float* __restrict__ bias,
                                               const float* __restrict__ res,
                                               void* __restrict__ outv,
                                               int N, int K) {
    __shared__ u16 As[2][128*32];
    __shared__ u16 Ws[2][128*32];
    int bm = blockIdx.y * 128, bn = blockIdx.x * 128;
    int tid = threadIdx.x, w = tid >> 6, l = tid & 63;
    int lr = l & 15, lh = l >> 4;
    int wm = (w >> 1) * 64, wn = (w & 1) * 64;
    f32x4 acc[4][4] = {};

    auto stage = [&](int buf, int kt) {
        #pragma unroll
        for (int c = 0; c < 2; c++) {
            int i = w*128 + c*64 + l;
            int row = i >> 2, slot = i & 3;
            int ko = kt + ((slot ^ (row & 3)) << 3);
            gl16(A + (size_t)(bm + row) * K + ko, (char*)As[buf] + (w*128 + c*64) * 16);
            gl16(W + (size_t)(bn + row) * K + ko, (char*)Ws[buf] + (w*128 + c*64) * 16);
        }
    };
    stage(0, 0);
    for (int kt = 0; kt < K; kt += 32) {
        int buf = (kt >> 5) & 1;
        __syncthreads();
        if (kt + 32 < K) stage(buf ^ 1, kt + 32);
        bf16x8 af[4], wf[4];
        #pragma unroll
        for (int f = 0; f < 4; f++) {
            int r = wm + f*16 + lr;
            af[f] = *(const bf16x8*)((const char*)As[buf] + r*64 + ((lh ^ (r & 3)) << 4));
            int rn = wn + f*16 + lr;
            wf[f] = *(const bf16x8*)((const char*)Ws[buf] + rn*64 + ((lh ^ (rn & 3)) << 4));
        }
        #pragma unroll
        for (int fm = 0; fm < 4; fm++)
            #pragma unroll
            for (int fn = 0; fn < 4; fn++)
                acc[fm][fn] = __builtin_amdgcn_mfma_f32_16x16x32_bf16(af[fm], wf[fn], acc[fm][fn], 0, 0, 0);
    }

    #pragma unroll
    for (int fm = 0; fm < 4; fm++) {
        #pragma unroll
        for (int r = 0; r < 4; r++) {
            int row = bm + wm + fm*16 + lh*4 + r;
            #pragma unroll
            for (int fn = 0; fn < 4; fn++) {
                int col = bn + wn + fn*16 + lr;
                float v = acc[fm][fn][r];
                if (HASBIAS) v += bias[col];
                if (HASRES)  v += res[(size_t)row * N + col];
                if (OUTBF) ((u16*)outv)[(size_t)row * N + col] = f2bf(v);
                else       ((float*)outv)[(size_t)row * N + col] = v;
            }
        }
    }
}

// ---------------- bf16 MFMA GEMM 64x128 tile, dbuf + 1 barrier/K-step ----------------
template<int OUTBF, int HASRES, int HASBIAS>
__global__ __launch_bounds__(256) void mgemm64_k(const u16* __restrict__ A,
                                                 const u16* __restrict__ W,
                                                 const float* __restrict__ bias,
                                                 const float* __restrict__ res,
                                                 void* __restrict__ outv,
                                                 int N, int K) {
    __shared__ u16 As[2][64*32];
    __shared__ u16 Ws[2][128*32];
    int bm = blockIdx.y * 64, bn = blockIdx.x * 128;
    int tid = threadIdx.x, w = tid >> 6, l = tid & 63;
    int lr = l & 15, lh = l >> 4;
    int wm = (w >> 1) * 32, wn = (w & 1) * 64;
    f32x4 acc[2][4] = {};

    auto stage = [&](int buf, int kt) {
        {
            int row = tid >> 2, slot = tid & 3;
            int ko = kt + ((slot ^ (row & 3)) << 3);
            gl16(A + (size_t)(bm + row) * K + ko, (char*)As[buf] + tid * 16);
        }
        #pragma unroll
        for (int c = 0; c < 2; c++) {
            int i = c*256 + tid;
            int row = i >> 2, slot = i & 3;
            int ko = kt + ((slot ^ (row & 3)) << 3);
            gl16(W + (size_t)(bn + row) * K + ko, (char*)Ws[buf] + (c*256 + tid) * 16);
        }
    };
    stage(0, 0);
    for (int kt = 0; kt < K; kt += 32) {
        int buf = (kt >> 5) & 1;
        __syncthreads();
        if (kt + 32 < K) stage(buf ^ 1, kt + 32);
        bf16x8 af[2], wf[4];
        #pragma unroll
        for (int f = 0; f < 2; f++) {
            int r = wm + f*16 + lr;
            af[f] = *(const bf16x8*)((const char*)As[buf] + r*64 + ((lh ^ (r & 3)) << 4));
        }
        #pragma unroll
        for (int f = 0; f < 4; f++) {
            int rn = wn + f*16 + lr;
            wf[f] = *(const bf16x8*)((const char*)Ws[buf] + rn*64 + ((lh ^ (rn & 3)) << 4));
        }
        #pragma unroll
        for (int fm = 0; fm < 2; fm++)
            #pragma unroll
            for (int fn = 0; fn < 4; fn++)
                acc[fm][fn] = __builtin_amdgcn_mfma_f32_16x16x32_bf16(af[fm], wf[fn], acc[fm][fn], 0, 0, 0);
    }

    #pragma unroll
    for (int fm = 0; fm < 2; fm++) {
        #pragma unroll
        for (int r = 0; r < 4; r++) {
            int row = bm + wm + fm*16 + lh*4 + r;
            #pragma unroll
            for (int fn = 0; fn < 4; fn++) {
                int col = bn + wn + fn*16 + lr;
                float v = acc[fm][fn][r];
                if (HASBIAS) v += bias[col];
                if (HASRES)  v += res[(size_t)row * N + col];
                if (OUTBF) ((u16*)outv)[(size_t)row * N + col] = f2bf(v);
                else       ((float*)outv)[(size_t)row * N + col] = v;
            }
        }
    }
}

// ---------------- merged QKV projection, dbuf + 1 barrier/K-step ----------------
__global__ __launch_bounds__(256) void mqkv_k(const u16* __restrict__ qn,
                                              const u16* __restrict__ kn,
                                              const u16* __restrict__ wA,
                                              const float* __restrict__ bias3,
                                              u16* __restrict__ out3) {
    int z = blockIdx.z;
    const u16* A = z ? kn : qn;
    const u16* W = wA + (size_t)z * Cc * Cc;
    const float* bias = bias3 + z * Cc;
    u16* out = out3 + (size_t)z * Mm * Cc;

    __shared__ u16 As[2][128*32];
    __shared__ u16 Ws[2][128*32];
    int bm = blockIdx.y * 128, bn = blockIdx.x * 128;
    int tid = threadIdx.x, w = tid >> 6, l = tid & 63;
    int lr = l & 15, lh = l >> 4;
    int wm = (w >> 1) * 64, wn = (w & 1) * 64;
    f32x4 acc[4][4] = {};

    auto stage = [&](int buf, int kt) {
        #pragma unroll
        for (int c = 0; c < 2; c++) {
            int i = w*128 + c*64 + l;
            int row = i >> 2, slot = i & 3;
            int ko = kt + ((slot ^ (row & 3)) << 3);
            gl16(A + (size_t)(bm + row) * Cc + ko, (char*)As[buf] + (w*128 + c*64) * 16);
            gl16(W + (size_t)(bn + row) * Cc + ko, (char*)Ws[buf] + (w*128 + c*64) * 16);
        }
    };
    stage(0, 0);
    for (int kt = 0; kt < Cc; kt += 32) {
        int buf = (kt >> 5) & 1;
        __syncthreads();
        if (kt + 32 < Cc) stage(buf ^ 1, kt + 32);
        bf16x8 af[4], wf[4];
        #pragma unroll
        for (int f = 0; f < 4; f++) {
            int r = wm + f*16 + lr;
            af[f] = *(const bf16x8*)((const char*)As[buf] + r*64 + ((lh ^ (r & 3)) << 4));
            int rn = wn + f*16 + lr;
            wf[f] = *(const bf16x8*)((const char*)Ws[buf] + rn*64 + ((lh ^ (rn & 3)) << 4));
        }
        #pragma unroll
        for (int fm = 0; fm < 4; fm++)
            #pragma unroll
            for (int fn = 0; fn < 4; fn++)
                acc[fm][fn] = __builtin_amdgcn_mfma_f32_16x16x32_bf16(af[fm], wf[fn], acc[fm][fn], 0, 0, 0);
    }

    #pragma unroll
    for (int fm = 0; fm < 4; fm++) {
        #pragma unroll
        for (int r = 0; r < 4; r++) {
            int row = bm + wm + fm*16 + lh*4 + r;
            #pragma unroll
            for (int fn = 0; fn < 4; fn++) {
                int col = bn + wn + fn*16 + lr;
                out[(size_t)row * Cc + col] = f2bf(acc[fm][fn][r] + bias[col]);
            }
        }
    }
}

// ---------------- fused SwiGLU MFMA GEMM, 64x128 tile (single-buffered) ----------------
__global__ __launch_bounds__(256) void mswiglu64_k(const u16* __restrict__ A,
                                                   const u16* __restrict__ W1,
                                                   const u16* __restrict__ W2,
                                                   u16* __restrict__ out,
                                                   int N, int K) {
    __shared__ u16 As[64*32];
    __shared__ u16 W1s[128*32];
    __shared__ u16 W2s[128*32];
    int bm = blockIdx.y * 64, bn = blockIdx.x * 128;
    int tid = threadIdx.x, w = tid >> 6, l = tid & 63;
    int lr = l & 15, lh = l >> 4;
    int wm = (w >> 1) * 32, wn = (w & 1) * 64;
    f32x4 acc1[2][4] = {};
    f32x4 acc2[2][4] = {};

    for (int kt = 0; kt < K; kt += 32) {
        __syncthreads();
        {
            int row = tid >> 2, slot = tid & 3;
            int ko = kt + ((slot ^ (row & 3)) << 3);
            gl16(A + (size_t)(bm + row) * K + ko, (char*)As + tid * 16);
        }
        #pragma unroll
        for (int c = 0; c < 2; c++) {
            int i = c*256 + tid;
            int row = i >> 2, slot = i & 3;
            int ko = kt + ((slot ^ (row & 3)) << 3);
            gl16(W1 + (size_t)(bn + row) * K + ko, (char*)W1s + (c*256 + tid) * 16);
            gl16(W2 + (size_t)(bn + row) * K + ko, (char*)W2s + (c*256 + tid) * 16);
        }
        __syncthreads();
        bf16x8 af[2], w1f[4], w2f[4];
        #pragma unroll
        for (int f = 0; f < 2; f++) {
            int r = wm + f*16 + lr;
            af[f] = *(const bf16x8*)((const char*)As + r*64 + ((lh ^ (r & 3)) << 4));
        }
        #pragma unroll
        for (int f = 0; f < 4; f++) {
            int rn = wn + f*16 + lr;
            int offn = rn*64 + ((lh ^ (rn & 3)) << 4);
            w1f[f] = *(const bf16x8*)((const char*)W1s + offn);
            w2f[f] = *(const bf16x8*)((const char*)W2s + offn);
        }
        #pragma unroll
        for (int fm = 0; fm < 2; fm++)
            #pragma unroll
            for (int fn = 0; fn < 4; fn++) {
                acc1[fm][fn] = __builtin_amdgcn_mfma_f32_16x16x32_bf16(af[fm], w1f[fn], acc1[fm][fn], 0, 0, 0);
                acc2[fm][fn] = __builtin_amdgcn_mfma_f32_16x16x32_bf16(af[fm], w2f[fn], acc2[fm][fn], 0, 0, 0);
            }
    }

    #pragma unroll
    for (int fm = 0; fm < 2; fm++) {
        #pragma unroll
        for (int r = 0; r < 4; r++) {
            int row = bm + wm + fm*16 + lh*4 + r;
            #pragma unroll
            for (int fn = 0; fn < 4; fn++) {
                int col = bn + wn + fn*16 + lr;
                float a = acc1[fm][fn][r];
                float sig = 1.f / (1.f + __expf(-a));
                out[(size_t)row * N + col] = f2bf(a * sig * acc2[fm][fn][r]);
            }
        }
    }
}

// ---------------- V transpose (bf16): vp[B,T,C](head cols) -> vt[B*H, 64, T] ----------------
__global__ __launch_bounds__(256) void vt_k(const u16* __restrict__ vp,
                                            u16* __restrict__ vt) {
    int blk = blockIdx.x;             // bh*32 + kb
    int bh = blk >> 5, kb = blk & 31;
    int b = bh >> 4, h = bh & 15;
    __shared__ u16 t[64][65];
    int tid = threadIdx.x;
    size_t bc = (size_t)b*Tt*Cc + (size_t)h*HDi;
    #pragma unroll
    for (int i = 0; i < 16; i++) {
        int e = tid + i*256;
        int k = e >> 6, d = e & 63;
        t[d][k] = vp[bc + (size_t)(kb*64 + k)*Cc + d];
    }
    __syncthreads();
    #pragma unroll
    for (int i = 0; i < 16; i++) {
        int e = tid + i*256;
        int d = e >> 6, k = e & 63;
        vt[((size_t)bh*64 + d)*Tt + kb*64 + k] = t[d][k];
    }
}

// ---------------- MFMA flash attention: dbuf pipeline, mask-as-C-init, defer-max ----------------
__global__ __launch_bounds__(256) void fattn_k(const u16* __restrict__ qp,
                                               const u16* __restrict__ kp,
                                               const u16* __restrict__ vt,
                                               const float* __restrict__ mr,
                                               u16* __restrict__ ctx) {
    __shared__ u16 Kt[2*4096];      // dbuf [64 k][64 d], swizzled
    __shared__ u16 Vts[2*4096];     // dbuf [64 d][64 k], swizzled
    __shared__ u16 Pt[4][1024];     // per-wave [16 q][64 k], swizzled
    __shared__ float mrw[2112];     // rel-bias window, pre-scaled by 8

    constexpr float C1 = 0.18033688011118324f;   // 0.125 * log2(e)

    int blk = blockIdx.x;
    int qt = blk & 31, h = (blk >> 5) & 15, b = blk >> 9;
    int q0 = qt * 64;
    int tid = threadIdx.x, w = tid >> 6, l = tid & 63;
    int lr = l & 15, lh = l >> 4;
    size_t bc = (size_t)b * Tt * Cc + (size_t)h * HDi;
    const u16* vtb = vt + (size_t)(b*Hh + h) * HDi * Tt;

    for (int i = tid; i < 2111; i += 256) mrw[i] = mr[q0 + i] * 8.f;

    bf16x8 qa[2];
    {
        const u16* qrow = qp + bc + (size_t)(q0 + w*16 + lr) * Cc;
        qa[0] = *(const bf16x8*)(qrow + lh*8);
        qa[1] = *(const bf16x8*)(qrow + 32 + lh*8);
    }

    f32x4 oacc[4] = {};
    float mrun = -1e30f, lrun = 0.f;

    int wb = (tid & 192) * 16;

    auto stage = [&](int buf, int kt) {
        #pragma unroll
        for (int ps = 0; ps < 2; ps++) {
            int i = ps*256 + tid;
            int kr = i >> 3, sl = i & 7;
            int so = (sl ^ (kr & 7)) << 3;
            gl16(kp + bc + (size_t)(kt*64 + kr) * Cc + so, (char*)Kt + buf*8192 + ps*4096 + wb);
            gl16(vtb + (size_t)kr * Tt + kt*64 + so,       (char*)Vts + buf*8192 + ps*4096 + wb);
        }
    };
    stage(0, 0);

    for (int kt = 0; kt < 32; kt++) {
        int buf = kt & 1;
        __syncthreads();                 // drains vmcnt (buf ready) + prior lds reads
        if (kt < 31) stage(buf ^ 1, kt + 1);
        const char* Kb = (const char*)Kt + buf*8192;
        const char* Vb = (const char*)Vts + buf*8192;

        // C-init with 8*mask: s[f][r] = mrw[ib - f*16 - r]
        int ib = w*16 + lr - kt*64 - lh*4 + 2047;
        f32x4 s[4];
        #pragma unroll
        for (int f = 0; f < 4; f++) {
            int base = ib - f*16;
            s[f][0] = mrw[base];
            s[f][1] = mrw[base - 1];
            s[f][2] = mrw[base - 2];
            s[f][3] = mrw[base - 3];
        }
        // QK^T swapped: s[f] += D[k = f*16+lh*4+r][q = lr]
        #pragma unroll
        for (int f = 0; f < 4; f++) {
            int kl = f*16 + lr, ksw = (kl & 7) << 4;
            #pragma unroll
            for (int c = 0; c < 2; c++) {
                bf16x8 kb = *(const bf16x8*)(Kb + ((kl*128 + c*64 + lh*16) ^ ksw));
                s[f] = __builtin_amdgcn_mfma_f32_16x16x32_bf16(kb, qa[c], s[f], 0, 0, 0);
            }
        }

        // tile max
        float tm = -1e30f;
        #pragma unroll
        for (int f = 0; f < 4; f++)
            #pragma unroll
            for (int r = 0; r < 4; r++) tm = fmaxf(tm, s[f][r]);
        tm = fmaxf(tm, __shfl_xor(tm, 16));
        tm = fmaxf(tm, __shfl_xor(tm, 32));

        float corr = 1.f;
        bool nod = __all(tm <= mrun + 64.f);
        if (!nod) {
            float mn = fmaxf(mrun, tm);
            corr = exp2f((mrun - mn) * C1);
            mrun = mn;
        }
        // single exp pass (in place)
        float mnc = mrun * C1;
        float ts = 0.f;
        #pragma unroll
        for (int f = 0; f < 4; f++)
            #pragma unroll
            for (int r = 0; r < 4; r++) {
                float e = exp2f(s[f][r]*C1 - mnc);
                s[f][r] = e; ts += e;
            }
        ts += __shfl_xor(ts, 16);
        ts += __shfl_xor(ts, 32);
        if (nod) {
            lrun += ts;
        } else {
            lrun = lrun*corr + ts;
            float cr0 = __shfl(corr, lh*4 + 0);
            float cr1 = __shfl(corr, lh*4 + 1);
            float cr2 = __shfl(corr, lh*4 + 2);
            float cr3 = __shfl(corr, lh*4 + 3);
            #pragma unroll
            for (int f = 0; f < 4; f++) {
                oacc[f][0] *= cr0; oacc[f][1] *= cr1;
                oacc[f][2] *= cr2; oacc[f][3] *= cr3;
            }
        }

        // packed P write via cvt_pk: row q=lr, cols k = f*16+lh*4..+3
        #pragma unroll
        for (int f = 0; f < 4; f++) {
            uint2 p2 = { cvtpk(s[f][0], s[f][1]), cvtpk(s[f][2], s[f][3]) };
            *(uint2*)((char*)Pt[w] + ((lr*128 + f*32 + lh*8) ^ ((lr & 7) << 4))) = p2;
        }

        // PV
        bf16x8 pa[2];
        int psw = (lr & 7) << 4;
        pa[0] = *(const bf16x8*)((const char*)Pt[w] + ((lr*128 + lh*16) ^ psw));
        pa[1] = *(const bf16x8*)((const char*)Pt[w] + ((lr*128 + 64 + lh*16) ^ psw));
        #pragma unroll
        for (int f = 0; f < 4; f++) {
            int dl = f*16 + lr, dsw = (dl & 7) << 4;
            #pragma unroll
            for (int c = 0; c < 2; c++) {
                bf16x8 vb = *(const bf16x8*)(Vb + ((dl*128 + c*64 + lh*16) ^ dsw));
                oacc[f] = __builtin_amdgcn_mfma_f32_16x16x32_bf16(pa[c], vb, oacc[f], 0, 0, 0);
            }
        }
    }

    float li0 = __shfl(lrun, lh*4 + 0);
    float li1 = __shfl(lrun, lh*4 + 1);
    float li2 = __shfl(lrun, lh*4 + 2);
    float li3 = __shfl(lrun, lh*4 + 3);
    float iv[4] = { 1.f/li0, 1.f/li1, 1.f/li2, 1.f/li3 };
    #pragma unroll
    for (int r = 0; r < 4; r++) {
        int row = q0 + w*16 + lh*4 + r;
        #pragma unroll
        for (int f = 0; f < 4; f++)
            ctx[bc + (size_t)row * Cc + f*16 + lr] = f2bf(oacc[f][r] * iv[r]);
    }
}

extern "C" void kernel_launch(void* const* d_in, const int* in_sizes, int n_in,
                              void* d_out, int out_size, void* d_ws, size_t ws_size,
                              hipStream_t stream) {
    const float* query     = (const float*)d_in[0];
    const float* key       = (const float*)d_in[1];
    const float* g_q       = (const float*)d_in[2];
    const float* b_q       = (const float*)d_in[3];
    const float* g_k       = (const float*)d_in[4];
    const float* b_k       = (const float*)d_in[5];
    const float* in_proj_w = (const float*)d_in[6];
    const float* in_proj_b = (const float*)d_in[7];
    const float* out_w     = (const float*)d_in[8];
    const float* out_b     = (const float*)d_in[9];
    const float* proj_w    = (const float*)d_in[10];
    const float* proj_b    = (const float*)d_in[11];
    const float* rel_table = (const float*)d_in[12];
    const float* g_ffn     = (const float*)d_in[13];
    const float* b_ffn     = (const float*)d_in[14];
    const float* w1        = (const float*)d_in[15];
    const float* w2        = (const float*)d_in[16];
    const float* w3        = (const float*)d_in[17];
    const float* g_out     = (const float*)d_in[18];
    const float* b_out     = (const float*)d_in[19];

    char* p = (char*)d_ws;
    auto alloc = [&](size_t bytes) { char* r = p; p += bytes; return r; };
    const size_t MCb = (size_t)Mm * Cc * 2;
    u16* wA  = (u16*)alloc((size_t)3*Cc*Cc*2);
    u16* wPb = (u16*)alloc((size_t)Cc*Cc*2);
    u16* wOt = (u16*)alloc((size_t)Cc*Cc*2);
    u16* wCb = (u16*)alloc((size_t)Cc*Cc*2);
    u16* w1b = (u16*)alloc((size_t)HIDP*Cc*2);
    u16* w2b = (u16*)alloc((size_t)HIDP*Cc*2);
    u16* w3b = (u16*)alloc((size_t)Cc*HIDP*2);
    float* bc = (float*)alloc(Cc*4);
    float* mr = (float*)alloc(4096*4);
    u16* qn = (u16*)alloc(MCb);
    u16* kn = (u16*)alloc(MCb);
    u16* qp = (u16*)alloc(MCb);      // qp,kp,vp contiguous (mqkv out3)
    u16* kp = (u16*)alloc(MCb);
    u16* vp = (u16*)alloc(MCb);
    u16* vt = (u16*)alloc(MCb);
    float* x  = (float*)alloc((size_t)Mm*Cc*4);
    float* x2 = (float*)alloc((size_t)Mm*Cc*4);
    u16* ctx = qn;   // aliases (lifetimes disjoint)
    u16* h   = qp;
    u16* gf  = vp;   // [4096][1408] bf16 spans vp+part of vt

    dim3 blk(256);
    // ---- per-launch weight prep ----
    cvt_k<<<(3*Cc*Cc/8 + 255)/256, blk, 0, stream>>>(in_proj_w, wA, 3*Cc, Cc, Cc, 3*Cc*Cc/8);
    cvt_k<<<(Cc*Cc/8 + 255)/256,   blk, 0, stream>>>(proj_w, wPb, Cc, Cc, Cc, Cc*Cc/8);
    cvtT_k<<<dim3(16,16), blk, 0, stream>>>(out_w, wOt);
    cvt_k<<<(HIDP*Cc/8 + 255)/256, blk, 0, stream>>>(w1, w1b, HID, Cc, Cc, HIDP*Cc/8);
    cvt_k<<<(HIDP*Cc/8 + 255)/256, blk, 0, stream>>>(w2, w2b, HID, Cc, Cc, HIDP*Cc/8);
    cvt_k<<<(Cc*HIDP/8 + 255)/256, blk, 0, stream>>>(w3, w3b, Cc, HID, HIDP, Cc*HIDP/8);
    mgemm_k<1,0,0><<<dim3(Cc/128, Cc/128), blk, 0, stream>>>(wPb, wOt, nullptr, nullptr, wCb, Cc, Cc);
    bias_k<<<Cc, blk, 0, stream>>>(proj_w, out_b, proj_b, bc);
    meanrel_k<<<16, blk, 0, stream>>>(rel_table, mr);

    // ---- main chain ----
    ln2_k<<<2*Mm, blk, 0, stream>>>(query, key, g_q, b_q, g_k, b_k, qn, kn);

    dim3 gqkv(Cc/128, Mm/128, 3);
    mqkv_k<<<gqkv, blk, 0, stream>>>(qn, kn, wA, in_proj_b, qp);

    vt_k<<<Bb*Hh*32, blk, 0, stream>>>(vp, vt);
    fattn_k<<<Bb*Hh*32, blk, 0, stream>>>(qp, kp, vt, mr, ctx);

    dim3 g1(Cc/128, Mm/64);
    mgemm64_k<0,1,1><<<g1, blk, 0, stream>>>(ctx, wCb, bc, query, x, Cc, Cc);

    ln_k<1><<<Mm, blk, 0, stream>>>(x, g_ffn, b_ffn, h);
    dim3 g2(HIDP/128, Mm/64);
    mswiglu64_k<<<g2, blk, 0, stream>>>(h, w1b, w2b, gf, HIDP, Cc);
    dim3 g3(Cc/128, Mm/64);
    mgemm64_k<0,1,0><<<g3, blk, 0, stream>>>(gf, w3b, nullptr, x, x2, Cc, HIDP);

    ln_k<0><<<Mm, blk, 0, stream>>>(x2, g_out, b_out, d_out);
}

// Round 8
// 283.580 us; speedup vs baseline: 16.5832x; 1.1057x over previous
//
#include <hip/hip_runtime.h>
#include <hip/hip_bf16.h>

static constexpr int Bb  = 2;
static constexpr int Tt  = 2048;
static constexpr int Cc  = 1024;
static constexpr int Hh  = 16;
static constexpr int HDi = 64;
static constexpr int HID = 1365;
static constexpr int HIDP = 1408;      // HID padded to multiple of 128
static constexpr int Mm  = Bb * Tt;    // 4096 rows

typedef unsigned short u16;
typedef __attribute__((ext_vector_type(8))) short bf16x8;
typedef __attribute__((ext_vector_type(4))) float f32x4;
typedef __attribute__((ext_vector_type(8))) unsigned short u16x8;
typedef __attribute__((ext_vector_type(4))) unsigned short u16x4;

__device__ inline u16 f2bf(float f) {
    unsigned u = __builtin_bit_cast(unsigned, f);
    u += 0x7fffu + ((u >> 16) & 1u);
    return (u16)(u >> 16);
}

__device__ inline unsigned cvtpk(float lo, float hi) {
    unsigned r;
    asm("v_cvt_pk_bf16_f32 %0, %1, %2" : "=v"(r) : "v"(lo), "v"(hi));
    return r;
}

__device__ inline float vexp2(float x) {   // raw v_exp_f32 (2^x), no denorm guard
    float r;
    asm("v_exp_f32 %0, %1" : "=v"(r) : "v"(x));
    return r;
}

__device__ inline void gl16(const void* g, void* l) {
    __builtin_amdgcn_global_load_lds(
        (const __attribute__((address_space(1))) unsigned*)g,
        (__attribute__((address_space(3))) unsigned*)l, 16, 0, 0);
}

// ---------------- LayerNorm: one row (C=1024) per block; OUTBF: bf16 out ----------------
template<int OUTBF>
__global__ __launch_bounds__(256) void ln_k(const float* __restrict__ x,
                                            const float* __restrict__ g,
                                            const float* __restrict__ b,
                                            void* __restrict__ yv) {
    int row = blockIdx.x;
    int tid = threadIdx.x;
    const float4* xr = (const float4*)(x + (size_t)row * Cc);
    float4 v = xr[tid];
    float s  = v.x + v.y + v.z + v.w;
    float ss = v.x*v.x + v.y*v.y + v.z*v.z + v.w*v.w;
    __shared__ float rs[256], rq[256];
    rs[tid] = s; rq[tid] = ss;
    __syncthreads();
    for (int o = 128; o > 0; o >>= 1) {
        if (tid < o) { rs[tid] += rs[tid+o]; rq[tid] += rq[tid+o]; }
        __syncthreads();
    }
    float mean = rs[0] * (1.f/Cc);
    float var  = rq[0] * (1.f/Cc) - mean*mean;
    float inv  = rsqrtf(var + 1e-5f);
    float4 gv = ((const float4*)g)[tid];
    float4 bv = ((const float4*)b)[tid];
    float o0 = (v.x-mean)*inv*gv.x + bv.x;
    float o1 = (v.y-mean)*inv*gv.y + bv.y;
    float o2 = (v.z-mean)*inv*gv.z + bv.z;
    float o3 = (v.w-mean)*inv*gv.w + bv.w;
    if (OUTBF) {
        u16x4 o4 = { f2bf(o0), f2bf(o1), f2bf(o2), f2bf(o3) };
        ((u16x4*)((u16*)yv + (size_t)row * Cc))[tid] = o4;
    } else {
        float4 o4 = { o0, o1, o2, o3 };
        ((float4*)((float*)yv + (size_t)row * Cc))[tid] = o4;
    }
}

// ---------------- merged LN for query+key -> qn, kn (bf16) ----------------
__global__ __launch_bounds__(256) void ln2_k(const float* __restrict__ q,
                                             const float* __restrict__ k,
                                             const float* __restrict__ gq, const float* __restrict__ bq,
                                             const float* __restrict__ gk, const float* __restrict__ bk,
                                             u16* __restrict__ qn, u16* __restrict__ kn) {
    int row = blockIdx.x;
    const float* x; const float* g; const float* bb; u16* y; int r;
    if (row < Mm) { x = q; g = gq; bb = bq; y = qn; r = row; }
    else          { x = k; g = gk; bb = bk; y = kn; r = row - Mm; }
    int tid = threadIdx.x;
    float4 v = ((const float4*)(x + (size_t)r * Cc))[tid];
    float s  = v.x + v.y + v.z + v.w;
    float ss = v.x*v.x + v.y*v.y + v.z*v.z + v.w*v.w;
    __shared__ float rs[256], rq2[256];
    rs[tid] = s; rq2[tid] = ss;
    __syncthreads();
    for (int o = 128; o > 0; o >>= 1) {
        if (tid < o) { rs[tid] += rs[tid+o]; rq2[tid] += rq2[tid+o]; }
        __syncthreads();
    }
    float mean = rs[0] * (1.f/Cc);
    float var  = rq2[0] * (1.f/Cc) - mean*mean;
    float inv  = rsqrtf(var + 1e-5f);
    float4 gv = ((const float4*)g)[tid];
    float4 bv = ((const float4*)bb)[tid];
    u16x4 o4 = { f2bf((v.x-mean)*inv*gv.x + bv.x), f2bf((v.y-mean)*inv*gv.y + bv.y),
                 f2bf((v.z-mean)*inv*gv.z + bv.z), f2bf((v.w-mean)*inv*gv.w + bv.w) };
    ((u16x4*)(y + (size_t)r * Cc))[tid] = o4;
}

// ---------------- mean over heads of rel_table -> mr[4095] ----------------
__global__ __launch_bounds__(256) void meanrel_k(const float* __restrict__ rel,
                                                 float* __restrict__ mr) {
    int j = blockIdx.x * 256 + threadIdx.x;
    if (j < 2*Tt - 1) {
        float s = 0.f;
        #pragma unroll
        for (int h = 0; h < Hh; h++) s += rel[(size_t)h * (2*Tt - 1) + j];
        mr[j] = s * (1.f/Hh);
    }
}

// ---------------- merged linear f32->bf16 converts (4 segments, trailing zero-fill) ----------------
__global__ __launch_bounds__(256) void cvt4_k(const float* __restrict__ s0, u16* __restrict__ d0, int n0,
                                              const float* __restrict__ s1, u16* __restrict__ d1, int n1,
                                              const float* __restrict__ s2, u16* __restrict__ d2, int n2, int v2,
                                              const float* __restrict__ s3, u16* __restrict__ d3, int n3, int v3) {
    int u = blockIdx.x * 256 + threadIdx.x;
    const float* src; u16* dst; int valid;
    if (u < n0)              { src = s0; dst = d0; valid = n0*8; }
    else if ((u -= n0) < n1) { src = s1; dst = d1; valid = n1*8; }
    else if ((u -= n1) < n2) { src = s2; dst = d2; valid = v2; }
    else if ((u -= n2) < n3) { src = s3; dst = d3; valid = v3; }
    else return;
    int e0 = u * 8;
    u16x8 o;
    if (e0 + 8 <= valid) {
        float4 a = *(const float4*)(src + e0);
        float4 b = *(const float4*)(src + e0 + 4);
        o[0]=f2bf(a.x); o[1]=f2bf(a.y); o[2]=f2bf(a.z); o[3]=f2bf(a.w);
        o[4]=f2bf(b.x); o[5]=f2bf(b.y); o[6]=f2bf(b.z); o[7]=f2bf(b.w);
    } else {
        #pragma unroll
        for (int j = 0; j < 8; j++) {
            int e = e0 + j;
            o[j] = f2bf(e < valid ? src[e] : 0.f);
        }
    }
    *(u16x8*)(dst + (size_t)e0) = o;
}

// ---------------- f32 -> bf16 with column padding: src[Rs][Cs] -> dst[.][Cd] ----------------
__global__ __launch_bounds__(256) void cvt_k(const float* __restrict__ src,
                                             u16* __restrict__ dst,
                                             int Rs, int Cs, int Cd, int total8) {
    int idx = blockIdx.x * 256 + threadIdx.x;
    if (idx >= total8) return;
    int e0 = idx * 8;
    int r = e0 / Cd, c0 = e0 - r * Cd;
    u16x8 o;
    #pragma unroll
    for (int j = 0; j < 8; j++) {
        int c = c0 + j;
        float v = (r < Rs && c < Cs) ? src[(size_t)r * Cs + c] : 0.f;
        o[j] = f2bf(v);
    }
    *(u16x8*)(dst + (size_t)e0) = o;
}

// ---------------- transposed cvt: dst[j][c] = src[c][j], 1024x1024 f32->bf16 ----------------
__global__ __launch_bounds__(256) void cvtT_k(const float* __restrict__ src,
                                              u16* __restrict__ dst) {
    __shared__ float t[64][65];
    int j0 = blockIdx.x * 64, c0 = blockIdx.y * 64;
    int tid = threadIdx.x;
    #pragma unroll
    for (int i = 0; i < 16; i++) {
        int e = tid + i*256;
        int c = e >> 6, j = e & 63;
        t[c][j] = src[(size_t)(c0 + c) * Cc + j0 + j];
    }
    __syncthreads();
    #pragma unroll
    for (int i = 0; i < 16; i++) {
        int e = tid + i*256;
        int j = e >> 6, c = e & 63;
        dst[(size_t)(j0 + j) * Cc + c0 + c] = f2bf(t[c][j]);
    }
}

// ---------------- combined bias: bc[i] = dot(proj_w[i,:], out_b) + proj_b[i] ----------------
__global__ __launch_bounds__(256) void bias_k(const float* __restrict__ wp,
                                              const float* __restrict__ bo,
                                              const float* __restrict__ bp,
                                              float* __restrict__ bc) {
    int i = blockIdx.x, tid = threadIdx.x;
    float4 w = ((const float4*)(wp + (size_t)i * Cc))[tid];
    float4 b = ((const float4*)bo)[tid];
    float s = w.x*b.x + w.y*b.y + w.z*b.z + w.w*b.w;
    __shared__ float red[256];
    red[tid] = s; __syncthreads();
    for (int o = 128; o > 0; o >>= 1) {
        if (tid < o) red[tid] += red[tid+o];
        __syncthreads();
    }
    if (tid == 0) bc[i] = red[0] + bp[i];
}

// ---------------- bf16 MFMA GEMM 64x128 tile, dbuf + 1 barrier/K-step ----------------
template<int OUTBF, int HASRES, int HASBIAS>
__global__ __launch_bounds__(256) void mgemm64_k(const u16* __restrict__ A,
                                                 const u16* __restrict__ W,
                                                 const float* __restrict__ bias,
                                                 const float* __restrict__ res,
                                                 void* __restrict__ outv,
                                                 int N, int K) {
    __shared__ u16 As[2][64*32];
    __shared__ u16 Ws[2][128*32];
    int bm = blockIdx.y * 64, bn = blockIdx.x * 128;
    int tid = threadIdx.x, w = tid >> 6, l = tid & 63;
    int lr = l & 15, lh = l >> 4;
    int wm = (w >> 1) * 32, wn = (w & 1) * 64;
    f32x4 acc[2][4] = {};

    auto stage = [&](int buf, int kt) {
        {
            int row = tid >> 2, slot = tid & 3;
            int ko = kt + ((slot ^ (row & 3)) << 3);
            gl16(A + (size_t)(bm + row) * K + ko, (char*)As[buf] + tid * 16);
        }
        #pragma unroll
        for (int c = 0; c < 2; c++) {
            int i = c*256 + tid;
            int row = i >> 2, slot = i & 3;
            int ko = kt + ((slot ^ (row & 3)) << 3);
            gl16(W + (size_t)(bn + row) * K + ko, (char*)Ws[buf] + (c*256 + tid) * 16);
        }
    };
    stage(0, 0);
    for (int kt = 0; kt < K; kt += 32) {
        int buf = (kt >> 5) & 1;
        __syncthreads();
        if (kt + 32 < K) stage(buf ^ 1, kt + 32);
        bf16x8 af[2], wf[4];
        #pragma unroll
        for (int f = 0; f < 2; f++) {
            int r = wm + f*16 + lr;
            af[f] = *(const bf16x8*)((const char*)As[buf] + r*64 + ((lh ^ (r & 3)) << 4));
        }
        #pragma unroll
        for (int f = 0; f < 4; f++) {
            int rn = wn + f*16 + lr;
            wf[f] = *(const bf16x8*)((const char*)Ws[buf] + rn*64 + ((lh ^ (rn & 3)) << 4));
        }
        #pragma unroll
        for (int fm = 0; fm < 2; fm++)
            #pragma unroll
            for (int fn = 0; fn < 4; fn++)
                acc[fm][fn] = __builtin_amdgcn_mfma_f32_16x16x32_bf16(af[fm], wf[fn], acc[fm][fn], 0, 0, 0);
    }

    #pragma unroll
    for (int fm = 0; fm < 2; fm++) {
        #pragma unroll
        for (int r = 0; r < 4; r++) {
            int row = bm + wm + fm*16 + lh*4 + r;
            #pragma unroll
            for (int fn = 0; fn < 4; fn++) {
                int col = bn + wn + fn*16 + lr;
                float v = acc[fm][fn][r];
                if (HASBIAS) v += bias[col];
                if (HASRES)  v += res[(size_t)row * N + col];
                if (OUTBF) ((u16*)outv)[(size_t)row * N + col] = f2bf(v);
                else       ((float*)outv)[(size_t)row * N + col] = v;
            }
        }
    }
}

// ---------------- merged QKV projection, dbuf + 1 barrier/K-step ----------------
__global__ __launch_bounds__(256) void mqkv_k(const u16* __restrict__ qn,
                                              const u16* __restrict__ kn,
                                              const u16* __restrict__ wA,
                                              const float* __restrict__ bias3,
                                              u16* __restrict__ out3) {
    int z = blockIdx.z;
    const u16* A = z ? kn : qn;
    const u16* W = wA + (size_t)z * Cc * Cc;
    const float* bias = bias3 + z * Cc;
    u16* out = out3 + (size_t)z * Mm * Cc;

    __shared__ u16 As[2][128*32];
    __shared__ u16 Ws[2][128*32];
    int bm = blockIdx.y * 128, bn = blockIdx.x * 128;
    int tid = threadIdx.x, w = tid >> 6, l = tid & 63;
    int lr = l & 15, lh = l >> 4;
    int wm = (w >> 1) * 64, wn = (w & 1) * 64;
    f32x4 acc[4][4] = {};

    auto stage = [&](int buf, int kt) {
        #pragma unroll
        for (int c = 0; c < 2; c++) {
            int i = w*128 + c*64 + l;
            int row = i >> 2, slot = i & 3;
            int ko = kt + ((slot ^ (row & 3)) << 3);
            gl16(A + (size_t)(bm + row) * Cc + ko, (char*)As[buf] + (w*128 + c*64) * 16);
            gl16(W + (size_t)(bn + row) * Cc + ko, (char*)Ws[buf] + (w*128 + c*64) * 16);
        }
    };
    stage(0, 0);
    for (int kt = 0; kt < Cc; kt += 32) {
        int buf = (kt >> 5) & 1;
        __syncthreads();
        if (kt + 32 < Cc) stage(buf ^ 1, kt + 32);
        bf16x8 af[4], wf[4];
        #pragma unroll
        for (int f = 0; f < 4; f++) {
            int r = wm + f*16 + lr;
            af[f] = *(const bf16x8*)((const char*)As[buf] + r*64 + ((lh ^ (r & 3)) << 4));
            int rn = wn + f*16 + lr;
            wf[f] = *(const bf16x8*)((const char*)Ws[buf] + rn*64 + ((lh ^ (rn & 3)) << 4));
        }
        #pragma unroll
        for (int fm = 0; fm < 4; fm++)
            #pragma unroll
            for (int fn = 0; fn < 4; fn++)
                acc[fm][fn] = __builtin_amdgcn_mfma_f32_16x16x32_bf16(af[fm], wf[fn], acc[fm][fn], 0, 0, 0);
    }

    #pragma unroll
    for (int fm = 0; fm < 4; fm++) {
        #pragma unroll
        for (int r = 0; r < 4; r++) {
            int row = bm + wm + fm*16 + lh*4 + r;
            #pragma unroll
            for (int fn = 0; fn < 4; fn++) {
                int col = bn + wn + fn*16 + lr;
                out[(size_t)row * Cc + col] = f2bf(acc[fm][fn][r] + bias[col]);
            }
        }
    }
}

// ---------------- fused SwiGLU MFMA GEMM, 64x128 tile, dbuf ----------------
__global__ __launch_bounds__(256) void mswiglu64_k(const u16* __restrict__ A,
                                                   const u16* __restrict__ W1,
                                                   const u16* __restrict__ W2,
                                                   u16* __restrict__ out,
                                                   int N, int K) {
    __shared__ u16 As[2][64*32];
    __shared__ u16 W1s[2][128*32];
    __shared__ u16 W2s[2][128*32];
    int bm = blockIdx.y * 64, bn = blockIdx.x * 128;
    int tid = threadIdx.x, w = tid >> 6, l = tid & 63;
    int lr = l & 15, lh = l >> 4;
    int wm = (w >> 1) * 32, wn = (w & 1) * 64;
    f32x4 acc1[2][4] = {};
    f32x4 acc2[2][4] = {};

    auto stage = [&](int buf, int kt) {
        {
            int row = tid >> 2, slot = tid & 3;
            int ko = kt + ((slot ^ (row & 3)) << 3);
            gl16(A + (size_t)(bm + row) * K + ko, (char*)As[buf] + tid * 16);
        }
        #pragma unroll
        for (int c = 0; c < 2; c++) {
            int i = c*256 + tid;
            int row = i >> 2, slot = i & 3;
            int ko = kt + ((slot ^ (row & 3)) << 3);
            gl16(W1 + (size_t)(bn + row) * K + ko, (char*)W1s[buf] + (c*256 + tid) * 16);
            gl16(W2 + (size_t)(bn + row) * K + ko, (char*)W2s[buf] + (c*256 + tid) * 16);
        }
    };
    stage(0, 0);
    for (int kt = 0; kt < K; kt += 32) {
        int buf = (kt >> 5) & 1;
        __syncthreads();
        if (kt + 32 < K) stage(buf ^ 1, kt + 32);
        bf16x8 af[2], w1f[4], w2f[4];
        #pragma unroll
        for (int f = 0; f < 2; f++) {
            int r = wm + f*16 + lr;
            af[f] = *(const bf16x8*)((const char*)As[buf] + r*64 + ((lh ^ (r & 3)) << 4));
        }
        #pragma unroll
        for (int f = 0; f < 4; f++) {
            int rn = wn + f*16 + lr;
            int offn = rn*64 + ((lh ^ (rn & 3)) << 4);
            w1f[f] = *(const bf16x8*)((const char*)W1s[buf] + offn);
            w2f[f] = *(const bf16x8*)((const char*)W2s[buf] + offn);
        }
        #pragma unroll
        for (int fm = 0; fm < 2; fm++)
            #pragma unroll
            for (int fn = 0; fn < 4; fn++) {
                acc1[fm][fn] = __builtin_amdgcn_mfma_f32_16x16x32_bf16(af[fm], w1f[fn], acc1[fm][fn], 0, 0, 0);
                acc2[fm][fn] = __builtin_amdgcn_mfma_f32_16x16x32_bf16(af[fm], w2f[fn], acc2[fm][fn], 0, 0, 0);
            }
    }

    #pragma unroll
    for (int fm = 0; fm < 2; fm++) {
        #pragma unroll
        for (int r = 0; r < 4; r++) {
            int row = bm + wm + fm*16 + lh*4 + r;
            #pragma unroll
            for (int fn = 0; fn < 4; fn++) {
                int col = bn + wn + fn*16 + lr;
                float a = acc1[fm][fn][r];
                float sig = 1.f / (1.f + __expf(-a));
                out[(size_t)row * N + col] = f2bf(a * sig * acc2[fm][fn][r]);
            }
        }
    }
}

// ---------------- V transpose (bf16): vp[B,T,C](head cols) -> vt[B*H, 64, T] ----------------
__global__ __launch_bounds__(256) void vt_k(const u16* __restrict__ vp,
                                            u16* __restrict__ vt) {
    int blk = blockIdx.x;             // bh*32 + kb
    int bh = blk >> 5, kb = blk & 31;
    int b = bh >> 4, h = bh & 15;
    __shared__ u16 t[64][65];
    int tid = threadIdx.x;
    size_t bc = (size_t)b*Tt*Cc + (size_t)h*HDi;
    #pragma unroll
    for (int i = 0; i < 16; i++) {
        int e = tid + i*256;
        int k = e >> 6, d = e & 63;
        t[d][k] = vp[bc + (size_t)(kb*64 + k)*Cc + d];
    }
    __syncthreads();
    #pragma unroll
    for (int i = 0; i < 16; i++) {
        int e = tid + i*256;
        int d = e >> 6, k = e & 63;
        vt[((size_t)bh*64 + d)*Tt + kb*64 + k] = t[d][k];
    }
}

// ---------------- MFMA flash attention: hoisted addressing, raw v_exp, XCD swizzle ----------------
__global__ __launch_bounds__(256) void fattn_k(const u16* __restrict__ qp,
                                               const u16* __restrict__ kp,
                                               const u16* __restrict__ vt,
                                               const float* __restrict__ mr,
                                               u16* __restrict__ ctx) {
    __shared__ u16 Kt[2*4096];      // dbuf [64 k][64 d], swizzled
    __shared__ u16 Vts[2*4096];     // dbuf [64 d][64 k], swizzled
    __shared__ u16 Pt[4][1024];     // per-wave [16 q][64 k], swizzled
    __shared__ float mrw[2112];     // rel-bias window, pre-scaled by 8

    constexpr float C1 = 0.18033688011118324f;   // 0.125 * log2(e)

    // bijective XCD-chunk swizzle: 1024 blocks, 8 XCDs -> 128-block chunks share (b,h) panels
    int bid = blockIdx.x;
    int blk = ((bid & 7) << 7) | (bid >> 3);
    int qt = blk & 31, h = (blk >> 5) & 15, b = blk >> 9;
    int q0 = qt * 64;
    int tid = threadIdx.x, w = tid >> 6, l = tid & 63;
    int lr = l & 15, lh = l >> 4;
    size_t bc = (size_t)b * Tt * Cc + (size_t)h * HDi;
    const u16* vtb = vt + (size_t)(b*Hh + h) * HDi * Tt;

    for (int i = tid; i < 2111; i += 256) mrw[i] = mr[q0 + i] * 8.f;

    bf16x8 qa[2];
    {
        const u16* qrow = qp + bc + (size_t)(q0 + w*16 + lr) * Cc;
        qa[0] = *(const bf16x8*)(qrow + lh*8);
        qa[1] = *(const bf16x8*)(qrow + 32 + lh*8);
    }

    f32x4 oacc[4] = {};
    float mrun = -1e30f, lrun = 0.f;

    // ---- loop-invariant address precompute ----
    int ksw = (lr & 7) << 4;
    // K/V fragment read bases: offset(f,c) = f*2048 + lr*128 + ((c*64 + lh*16) ^ ksw)
    const char* pK0 = (const char*)Kt  + lr*128 + ((       lh*16) ^ ksw);
    const char* pK1 = (const char*)Kt  + lr*128 + ((64   + lh*16) ^ ksw);
    const char* pV0 = (const char*)Vts + lr*128 + ((       lh*16) ^ ksw);
    const char* pV1 = (const char*)Vts + lr*128 + ((64   + lh*16) ^ ksw);
    // P write: offset(f) = lr*128 + ((f*32 + lh*8) ^ ksw)
    char* pw0 = (char*)Pt[w] + lr*128 + ((      lh*8) ^ ksw);
    char* pw1 = (char*)Pt[w] + lr*128 + ((32  + lh*8) ^ ksw);
    char* pw2 = (char*)Pt[w] + lr*128 + ((64  + lh*8) ^ ksw);
    char* pw3 = (char*)Pt[w] + lr*128 + ((96  + lh*8) ^ ksw);
    // P read: offset(c) = lr*128 + ((c*64 + lh*16) ^ ksw)
    const char* pr0 = (const char*)Pt[w] + lr*128 + ((     lh*16) ^ ksw);
    const char* pr1 = (const char*)Pt[w] + lr*128 + ((64 + lh*16) ^ ksw);
    // sliding mask pointer: element (ib - f*16 - r) = base[51 - f*16 - r], base -= 64/tile
    const char* pm = (const char*)mrw + (w*16 + lr - lh*4 + 2047 - 51) * 4;

    // ---- staging pointers (advance 1 tile per stage call) ----
    int sl = tid & 7, kr0 = tid >> 3;
    int so = (sl ^ (kr0 & 7)) << 3;
    const u16* gK = kp + bc + (size_t)kr0 * Cc + so;     // +32*Cc for ps=1
    const u16* gV = vtb + (size_t)kr0 * Tt + so;         // +32*Tt for ps=1
    int wb = (tid & 192) * 16;
    char* dK0 = (char*)Kt  + wb;   // ps=0 dest; ps=1 at +4096
    char* dV0 = (char*)Vts + wb;

    auto stage = [&](int bufo) {
        gl16(gK,           dK0 + bufo);
        gl16(gK + 32*Cc,   dK0 + bufo + 4096);
        gl16(gV,           dV0 + bufo);
        gl16(gV + (size_t)32*Tt, dV0 + bufo + 4096);
        gK += 64*Cc;
        gV += 64;
    };

    auto tile = [&](int bufo) {
        // C-init with 8*mask
        f32x4 s[4];
        #pragma unroll
        for (int f = 0; f < 4; f++) {
            s[f][0] = *(const float*)(pm + (51 - f*16    ) * 4);
            s[f][1] = *(const float*)(pm + (51 - f*16 - 1) * 4);
            s[f][2] = *(const float*)(pm + (51 - f*16 - 2) * 4);
            s[f][3] = *(const float*)(pm + (51 - f*16 - 3) * 4);
        }
        pm -= 256;
        // QK^T swapped: s[f] += D[k][q]
        __builtin_amdgcn_s_setprio(1);
        #pragma unroll
        for (int f = 0; f < 4; f++) {
            bf16x8 kb0 = *(const bf16x8*)(pK0 + bufo + f*2048);
            s[f] = __builtin_amdgcn_mfma_f32_16x16x32_bf16(kb0, qa[0], s[f], 0, 0, 0);
            bf16x8 kb1 = *(const bf16x8*)(pK1 + bufo + f*2048);
            s[f] = __builtin_amdgcn_mfma_f32_16x16x32_bf16(kb1, qa[1], s[f], 0, 0, 0);
        }
        __builtin_amdgcn_s_setprio(0);

        // tile max
        float tm = -1e30f;
        #pragma unroll
        for (int f = 0; f < 4; f++)
            #pragma unroll
            for (int r = 0; r < 4; r++) tm = fmaxf(tm, s[f][r]);
        tm = fmaxf(tm, __shfl_xor(tm, 16));
        tm = fmaxf(tm, __shfl_xor(tm, 32));

        float corr = 1.f;
        bool nod = __all(tm <= mrun + 64.f);
        if (!nod) {
            float mn = fmaxf(mrun, tm);
            corr = vexp2((mrun - mn) * C1);
            mrun = mn;
        }
        float mnc = mrun * C1;
        float ts = 0.f;
        #pragma unroll
        for (int f = 0; f < 4; f++)
            #pragma unroll
            for (int r = 0; r < 4; r++) {
                float e = vexp2(fmaf(s[f][r], C1, -mnc));
                s[f][r] = e; ts += e;
            }
        ts += __shfl_xor(ts, 16);
        ts += __shfl_xor(ts, 32);
        if (nod) {
            lrun += ts;
        } else {
            lrun = lrun*corr + ts;
            float cr0 = __shfl(corr, lh*4 + 0);
            float cr1 = __shfl(corr, lh*4 + 1);
            float cr2 = __shfl(corr, lh*4 + 2);
            float cr3 = __shfl(corr, lh*4 + 3);
            #pragma unroll
            for (int f = 0; f < 4; f++) {
                oacc[f][0] *= cr0; oacc[f][1] *= cr1;
                oacc[f][2] *= cr2; oacc[f][3] *= cr3;
            }
        }

        // packed P write
        { uint2 p2 = { cvtpk(s[0][0], s[0][1]), cvtpk(s[0][2], s[0][3]) }; *(uint2*)pw0 = p2; }
        { uint2 p2 = { cvtpk(s[1][0], s[1][1]), cvtpk(s[1][2], s[1][3]) }; *(uint2*)pw1 = p2; }
        { uint2 p2 = { cvtpk(s[2][0], s[2][1]), cvtpk(s[2][2], s[2][3]) }; *(uint2*)pw2 = p2; }
        { uint2 p2 = { cvtpk(s[3][0], s[3][1]), cvtpk(s[3][2], s[3][3]) }; *(uint2*)pw3 = p2; }

        // PV
        bf16x8 pa0 = *(const bf16x8*)pr0;
        bf16x8 pa1 = *(const bf16x8*)pr1;
        __builtin_amdgcn_s_setprio(1);
        #pragma unroll
        for (int f = 0; f < 4; f++) {
            bf16x8 vb0 = *(const bf16x8*)(pV0 + bufo + f*2048);
            oacc[f] = __builtin_amdgcn_mfma_f32_16x16x32_bf16(pa0, vb0, oacc[f], 0, 0, 0);
            bf16x8 vb1 = *(const bf16x8*)(pV1 + bufo + f*2048);
            oacc[f] = __builtin_amdgcn_mfma_f32_16x16x32_bf16(pa1, vb1, oacc[f], 0, 0, 0);
        }
        __builtin_amdgcn_s_setprio(0);
    };

    stage(0);   // tile 0 -> buf0
    #pragma unroll 1
    for (int kt = 0; kt < 32; kt += 2) {
        __syncthreads();
        stage(8192);             // tile kt+1 -> buf1 (kt+1 <= 31 always)
        tile(0);
        __syncthreads();
        if (kt < 30) stage(0);   // tile kt+2 -> buf0
        tile(8192);
    }

    float li0 = __shfl(lrun, lh*4 + 0);
    float li1 = __shfl(lrun, lh*4 + 1);
    float li2 = __shfl(lrun, lh*4 + 2);
    float li3 = __shfl(lrun, lh*4 + 3);
    float iv[4] = { 1.f/li0, 1.f/li1, 1.f/li2, 1.f/li3 };
    #pragma unroll
    for (int r = 0; r < 4; r++) {
        int row = q0 + w*16 + lh*4 + r;
        #pragma unroll
        for (int f = 0; f < 4; f++)
            ctx[bc + (size_t)row * Cc + f*16 + lr] = f2bf(oacc[f][r] * iv[r]);
    }
}

extern "C" void kernel_launch(void* const* d_in, const int* in_sizes, int n_in,
                              void* d_out, int out_size, void* d_ws, size_t ws_size,
                              hipStream_t stream) {
    const float* query     = (const float*)d_in[0];
    const float* key       = (const float*)d_in[1];
    const float* g_q       = (const float*)d_in[2];
    const float* b_q       = (const float*)d_in[3];
    const float* g_k       = (const float*)d_in[4];
    const float* b_k       = (const float*)d_in[5];
    const float* in_proj_w = (const float*)d_in[6];
    const float* in_proj_b = (const float*)d_in[7];
    const float* out_w     = (const float*)d_in[8];
    const float* out_b     = (const float*)d_in[9];
    const float* proj_w    = (const float*)d_in[10];
    const float* proj_b    = (const float*)d_in[11];
    const float* rel_table = (const float*)d_in[12];
    const float* g_ffn     = (const float*)d_in[13];
    const float* b_ffn     = (const float*)d_in[14];
    const float* w1        = (const float*)d_in[15];
    const float* w2        = (const float*)d_in[16];
    const float* w3        = (const float*)d_in[17];
    const float* g_out     = (const float*)d_in[18];
    const float* b_out     = (const float*)d_in[19];

    char* p = (char*)d_ws;
    auto alloc = [&](size_t bytes) { char* r = p; p += bytes; return r; };
    const size_t MCb = (size_t)Mm * Cc * 2;
    u16* wA  = (u16*)alloc((size_t)3*Cc*Cc*2);
    u16* wPb = (u16*)alloc((size_t)Cc*Cc*2);
    u16* wOt = (u16*)alloc((size_t)Cc*Cc*2);
    u16* wCb = (u16*)alloc((size_t)Cc*Cc*2);
    u16* w1b = (u16*)alloc((size_t)HIDP*Cc*2);
    u16* w2b = (u16*)alloc((size_t)HIDP*Cc*2);
    u16* w3b = (u16*)alloc((size_t)Cc*HIDP*2);
    float* bc = (float*)alloc(Cc*4);
    float* mr = (float*)alloc(4096*4);
    u16* qn = (u16*)alloc(MCb);
    u16* kn = (u16*)alloc(MCb);
    u16* qp = (u16*)alloc(MCb);      // qp,kp,vp contiguous (mqkv out3)
    u16* kp = (u16*)alloc(MCb);
    u16* vp = (u16*)alloc(MCb);
    u16* vt = (u16*)alloc(MCb);
    float* x  = (float*)alloc((size_t)Mm*Cc*4);
    float* x2 = (float*)alloc((size_t)Mm*Cc*4);
    u16* ctx = qn;   // aliases (lifetimes disjoint)
    u16* h   = qp;
    u16* gf  = vp;   // [4096][1408] bf16 spans vp+part of vt

    dim3 blk(256);
    // ---- per-launch weight prep ----
    // merged linear converts: in_proj (3M elems), proj_w (1M), w1 (row-pad), w2 (row-pad)
    {
        int n0 = 3*Cc*Cc/8;           // 393216
        int n1 = Cc*Cc/8;             // 131072
        int n2 = HIDP*Cc/8;           // 180224 (valid = HID*Cc)
        int n3 = HIDP*Cc/8;
        int nblk = (n0 + n1 + n2 + n3) / 256;
        cvt4_k<<<nblk, blk, 0, stream>>>(in_proj_w, wA, n0,
                                         proj_w, wPb, n1,
                                         w1, w1b, n2, HID*Cc,
                                         w2, w2b, n3, HID*Cc);
    }
    cvt_k<<<(Cc*HIDP/8 + 255)/256, blk, 0, stream>>>(w3, w3b, Cc, HID, HIDP, Cc*HIDP/8);
    cvtT_k<<<dim3(16,16), blk, 0, stream>>>(out_w, wOt);
    mgemm64_k<1,0,0><<<dim3(Cc/128, Cc/64), blk, 0, stream>>>(wPb, wOt, nullptr, nullptr, wCb, Cc, Cc);
    bias_k<<<Cc, blk, 0, stream>>>(proj_w, out_b, proj_b, bc);
    meanrel_k<<<16, blk, 0, stream>>>(rel_table, mr);

    // ---- main chain ----
    ln2_k<<<2*Mm, blk, 0, stream>>>(query, key, g_q, b_q, g_k, b_k, qn, kn);

    dim3 gqkv(Cc/128, Mm/128, 3);
    mqkv_k<<<gqkv, blk, 0, stream>>>(qn, kn, wA, in_proj_b, qp);

    vt_k<<<Bb*Hh*32, blk, 0, stream>>>(vp, vt);
    fattn_k<<<Bb*Hh*32, blk, 0, stream>>>(qp, kp, vt, mr, ctx);

    dim3 g1(Cc/128, Mm/64);
    mgemm64_k<0,1,1><<<g1, blk, 0, stream>>>(ctx, wCb, bc, query, x, Cc, Cc);

    ln_k<1><<<Mm, blk, 0, stream>>>(x, g_ffn, b_ffn, h);
    dim3 g2(HIDP/128, Mm/64);
    mswiglu64_k<<<g2, blk, 0, stream>>>(h, w1b, w2b, gf, HIDP, Cc);
    dim3 g3(Cc/128, Mm/64);
    mgemm64_k<0,1,0><<<g3, blk, 0, stream>>>(gf, w3b, nullptr, x, x2, Cc, HIDP);

    ln_k<0><<<Mm, blk, 0, stream>>>(x2, g_out, b_out, d_out);
}

// Round 9
// 253.493 us; speedup vs baseline: 18.5515x; 1.1187x over previous
//
#include <hip/hip_runtime.h>
#include <hip/hip_bf16.h>

static constexpr int Bb  = 2;
static constexpr int Tt  = 2048;
static constexpr int Cc  = 1024;
static constexpr int Hh  = 16;
static constexpr int HDi = 64;
static constexpr int HID = 1365;
static constexpr int HIDP = 1408;      // HID padded to multiple of 128
static constexpr int Mm  = Bb * Tt;    // 4096 rows

typedef unsigned short u16;
typedef __attribute__((ext_vector_type(8))) short bf16x8;
typedef __attribute__((ext_vector_type(4))) float f32x4;
typedef __attribute__((ext_vector_type(8))) unsigned short u16x8;
typedef __attribute__((ext_vector_type(4))) unsigned short u16x4;

__device__ inline u16 f2bf(float f) {
    unsigned u = __builtin_bit_cast(unsigned, f);
    u += 0x7fffu + ((u >> 16) & 1u);
    return (u16)(u >> 16);
}

__device__ inline unsigned cvtpk(float lo, float hi) {
    unsigned r;
    asm("v_cvt_pk_bf16_f32 %0, %1, %2" : "=v"(r) : "v"(lo), "v"(hi));
    return r;
}

__device__ inline float vexp2(float x) {   // raw v_exp_f32 (2^x), no denorm guard
    float r;
    asm("v_exp_f32 %0, %1" : "=v"(r) : "v"(x));
    return r;
}

__device__ inline void gl16(const void* g, void* l) {
    __builtin_amdgcn_global_load_lds(
        (const __attribute__((address_space(1))) unsigned*)g,
        (__attribute__((address_space(3))) unsigned*)l, 16, 0, 0);
}

// ---------------- LayerNorm: one row (C=1024) per block; OUTBF: bf16 out ----------------
template<int OUTBF>
__global__ __launch_bounds__(256) void ln_k(const float* __restrict__ x,
                                            const float* __restrict__ g,
                                            const float* __restrict__ b,
                                            void* __restrict__ yv) {
    int row = blockIdx.x;
    int tid = threadIdx.x;
    const float4* xr = (const float4*)(x + (size_t)row * Cc);
    float4 v = xr[tid];
    float s  = v.x + v.y + v.z + v.w;
    float ss = v.x*v.x + v.y*v.y + v.z*v.z + v.w*v.w;
    __shared__ float rs[256], rq[256];
    rs[tid] = s; rq[tid] = ss;
    __syncthreads();
    for (int o = 128; o > 0; o >>= 1) {
        if (tid < o) { rs[tid] += rs[tid+o]; rq[tid] += rq[tid+o]; }
        __syncthreads();
    }
    float mean = rs[0] * (1.f/Cc);
    float var  = rq[0] * (1.f/Cc) - mean*mean;
    float inv  = rsqrtf(var + 1e-5f);
    float4 gv = ((const float4*)g)[tid];
    float4 bv = ((const float4*)b)[tid];
    float o0 = (v.x-mean)*inv*gv.x + bv.x;
    float o1 = (v.y-mean)*inv*gv.y + bv.y;
    float o2 = (v.z-mean)*inv*gv.z + bv.z;
    float o3 = (v.w-mean)*inv*gv.w + bv.w;
    if (OUTBF) {
        u16x4 o4 = { f2bf(o0), f2bf(o1), f2bf(o2), f2bf(o3) };
        ((u16x4*)((u16*)yv + (size_t)row * Cc))[tid] = o4;
    } else {
        float4 o4 = { o0, o1, o2, o3 };
        ((float4*)((float*)yv + (size_t)row * Cc))[tid] = o4;
    }
}

// ---------------- merged LN for query+key -> qn, kn (bf16) ----------------
__global__ __launch_bounds__(256) void ln2_k(const float* __restrict__ q,
                                             const float* __restrict__ k,
                                             const float* __restrict__ gq, const float* __restrict__ bq,
                                             const float* __restrict__ gk, const float* __restrict__ bk,
                                             u16* __restrict__ qn, u16* __restrict__ kn) {
    int row = blockIdx.x;
    const float* x; const float* g; const float* bb; u16* y; int r;
    if (row < Mm) { x = q; g = gq; bb = bq; y = qn; r = row; }
    else          { x = k; g = gk; bb = bk; y = kn; r = row - Mm; }
    int tid = threadIdx.x;
    float4 v = ((const float4*)(x + (size_t)r * Cc))[tid];
    float s  = v.x + v.y + v.z + v.w;
    float ss = v.x*v.x + v.y*v.y + v.z*v.z + v.w*v.w;
    __shared__ float rs[256], rq2[256];
    rs[tid] = s; rq2[tid] = ss;
    __syncthreads();
    for (int o = 128; o > 0; o >>= 1) {
        if (tid < o) { rs[tid] += rs[tid+o]; rq2[tid] += rq2[tid+o]; }
        __syncthreads();
    }
    float mean = rs[0] * (1.f/Cc);
    float var  = rq2[0] * (1.f/Cc) - mean*mean;
    float inv  = rsqrtf(var + 1e-5f);
    float4 gv = ((const float4*)g)[tid];
    float4 bv = ((const float4*)bb)[tid];
    u16x4 o4 = { f2bf((v.x-mean)*inv*gv.x + bv.x), f2bf((v.y-mean)*inv*gv.y + bv.y),
                 f2bf((v.z-mean)*inv*gv.z + bv.z), f2bf((v.w-mean)*inv*gv.w + bv.w) };
    ((u16x4*)(y + (size_t)r * Cc))[tid] = o4;
}

// ---------------- mean over heads of rel_table -> mr[4095] ----------------
__global__ __launch_bounds__(256) void meanrel_k(const float* __restrict__ rel,
                                                 float* __restrict__ mr) {
    int j = blockIdx.x * 256 + threadIdx.x;
    if (j < 2*Tt - 1) {
        float s = 0.f;
        #pragma unroll
        for (int h = 0; h < Hh; h++) s += rel[(size_t)h * (2*Tt - 1) + j];
        mr[j] = s * (1.f/Hh);
    }
}

// ---------------- merged linear f32->bf16 converts (4 segments, trailing zero-fill) ----------------
__global__ __launch_bounds__(256) void cvt4_k(const float* __restrict__ s0, u16* __restrict__ d0, int n0,
                                              const float* __restrict__ s1, u16* __restrict__ d1, int n1,
                                              const float* __restrict__ s2, u16* __restrict__ d2, int n2, int v2,
                                              const float* __restrict__ s3, u16* __restrict__ d3, int n3, int v3) {
    int u = blockIdx.x * 256 + threadIdx.x;
    const float* src; u16* dst; int valid;
    if (u < n0)              { src = s0; dst = d0; valid = n0*8; }
    else if ((u -= n0) < n1) { src = s1; dst = d1; valid = n1*8; }
    else if ((u -= n1) < n2) { src = s2; dst = d2; valid = v2; }
    else if ((u -= n2) < n3) { src = s3; dst = d3; valid = v3; }
    else return;
    int e0 = u * 8;
    u16x8 o;
    if (e0 + 8 <= valid) {
        float4 a = *(const float4*)(src + e0);
        float4 b = *(const float4*)(src + e0 + 4);
        o[0]=f2bf(a.x); o[1]=f2bf(a.y); o[2]=f2bf(a.z); o[3]=f2bf(a.w);
        o[4]=f2bf(b.x); o[5]=f2bf(b.y); o[6]=f2bf(b.z); o[7]=f2bf(b.w);
    } else {
        #pragma unroll
        for (int j = 0; j < 8; j++) {
            int e = e0 + j;
            o[j] = f2bf(e < valid ? src[e] : 0.f);
        }
    }
    *(u16x8*)(dst + (size_t)e0) = o;
}

// ---------------- f32 -> bf16 with column padding: src[Rs][Cs] -> dst[.][Cd] ----------------
__global__ __launch_bounds__(256) void cvt_k(const float* __restrict__ src,
                                             u16* __restrict__ dst,
                                             int Rs, int Cs, int Cd, int total8) {
    int idx = blockIdx.x * 256 + threadIdx.x;
    if (idx >= total8) return;
    int e0 = idx * 8;
    int r = e0 / Cd, c0 = e0 - r * Cd;
    u16x8 o;
    #pragma unroll
    for (int j = 0; j < 8; j++) {
        int c = c0 + j;
        float v = (r < Rs && c < Cs) ? src[(size_t)r * Cs + c] : 0.f;
        o[j] = f2bf(v);
    }
    *(u16x8*)(dst + (size_t)e0) = o;
}

// ---------------- transposed cvt: dst[j][c] = src[c][j], 1024x1024 f32->bf16 ----------------
__global__ __launch_bounds__(256) void cvtT_k(const float* __restrict__ src,
                                              u16* __restrict__ dst) {
    __shared__ float t[64][65];
    int j0 = blockIdx.x * 64, c0 = blockIdx.y * 64;
    int tid = threadIdx.x;
    #pragma unroll
    for (int i = 0; i < 16; i++) {
        int e = tid + i*256;
        int c = e >> 6, j = e & 63;
        t[c][j] = src[(size_t)(c0 + c) * Cc + j0 + j];
    }
    __syncthreads();
    #pragma unroll
    for (int i = 0; i < 16; i++) {
        int e = tid + i*256;
        int j = e >> 6, c = e & 63;
        dst[(size_t)(j0 + j) * Cc + c0 + c] = f2bf(t[c][j]);
    }
}

// ---------------- combined bias: bc[i] = dot(proj_w[i,:], out_b) + proj_b[i] ----------------
__global__ __launch_bounds__(256) void bias_k(const float* __restrict__ wp,
                                              const float* __restrict__ bo,
                                              const float* __restrict__ bp,
                                              float* __restrict__ bc) {
    int i = blockIdx.x, tid = threadIdx.x;
    float4 w = ((const float4*)(wp + (size_t)i * Cc))[tid];
    float4 b = ((const float4*)bo)[tid];
    float s = w.x*b.x + w.y*b.y + w.z*b.z + w.w*b.w;
    __shared__ float red[256];
    red[tid] = s; __syncthreads();
    for (int o = 128; o > 0; o >>= 1) {
        if (tid < o) red[tid] += red[tid+o];
        __syncthreads();
    }
    if (tid == 0) bc[i] = red[0] + bp[i];
}

// ---------------- bf16 MFMA GEMM 64x128 tile, dbuf + 1 barrier/K-step ----------------
template<int OUTBF, int HASRES, int HASBIAS>
__global__ __launch_bounds__(256) void mgemm64_k(const u16* __restrict__ A,
                                                 const u16* __restrict__ W,
                                                 const float* __restrict__ bias,
                                                 const float* __restrict__ res,
                                                 void* __restrict__ outv,
                                                 int N, int K) {
    __shared__ u16 As[2][64*32];
    __shared__ u16 Ws[2][128*32];
    int bm = blockIdx.y * 64, bn = blockIdx.x * 128;
    int tid = threadIdx.x, w = tid >> 6, l = tid & 63;
    int lr = l & 15, lh = l >> 4;
    int wm = (w >> 1) * 32, wn = (w & 1) * 64;
    f32x4 acc[2][4] = {};

    auto stage = [&](int buf, int kt) {
        {
            int row = tid >> 2, slot = tid & 3;
            int ko = kt + ((slot ^ (row & 3)) << 3);
            gl16(A + (size_t)(bm + row) * K + ko, (char*)As[buf] + tid * 16);
        }
        #pragma unroll
        for (int c = 0; c < 2; c++) {
            int i = c*256 + tid;
            int row = i >> 2, slot = i & 3;
            int ko = kt + ((slot ^ (row & 3)) << 3);
            gl16(W + (size_t)(bn + row) * K + ko, (char*)Ws[buf] + (c*256 + tid) * 16);
        }
    };
    stage(0, 0);
    for (int kt = 0; kt < K; kt += 32) {
        int buf = (kt >> 5) & 1;
        __syncthreads();
        if (kt + 32 < K) stage(buf ^ 1, kt + 32);
        bf16x8 af[2], wf[4];
        #pragma unroll
        for (int f = 0; f < 2; f++) {
            int r = wm + f*16 + lr;
            af[f] = *(const bf16x8*)((const char*)As[buf] + r*64 + ((lh ^ (r & 3)) << 4));
        }
        #pragma unroll
        for (int f = 0; f < 4; f++) {
            int rn = wn + f*16 + lr;
            wf[f] = *(const bf16x8*)((const char*)Ws[buf] + rn*64 + ((lh ^ (rn & 3)) << 4));
        }
        #pragma unroll
        for (int fm = 0; fm < 2; fm++)
            #pragma unroll
            for (int fn = 0; fn < 4; fn++)
                acc[fm][fn] = __builtin_amdgcn_mfma_f32_16x16x32_bf16(af[fm], wf[fn], acc[fm][fn], 0, 0, 0);
    }

    #pragma unroll
    for (int fm = 0; fm < 2; fm++) {
        #pragma unroll
        for (int r = 0; r < 4; r++) {
            int row = bm + wm + fm*16 + lh*4 + r;
            #pragma unroll
            for (int fn = 0; fn < 4; fn++) {
                int col = bn + wn + fn*16 + lr;
                float v = acc[fm][fn][r];
                if (HASBIAS) v += bias[col];
                if (HASRES)  v += res[(size_t)row * N + col];
                if (OUTBF) ((u16*)outv)[(size_t)row * N + col] = f2bf(v);
                else       ((float*)outv)[(size_t)row * N + col] = v;
            }
        }
    }
}

// ---------------- merged QKV projection, dbuf + 1 barrier/K-step ----------------
__global__ __launch_bounds__(256) void mqkv_k(const u16* __restrict__ qn,
                                              const u16* __restrict__ kn,
                                              const u16* __restrict__ wA,
                                              const float* __restrict__ bias3,
                                              u16* __restrict__ out3) {
    int z = blockIdx.z;
    const u16* A = z ? kn : qn;
    const u16* W = wA + (size_t)z * Cc * Cc;
    const float* bias = bias3 + z * Cc;
    u16* out = out3 + (size_t)z * Mm * Cc;

    __shared__ u16 As[2][128*32];
    __shared__ u16 Ws[2][128*32];
    int bm = blockIdx.y * 128, bn = blockIdx.x * 128;
    int tid = threadIdx.x, w = tid >> 6, l = tid & 63;
    int lr = l & 15, lh = l >> 4;
    int wm = (w >> 1) * 64, wn = (w & 1) * 64;
    f32x4 acc[4][4] = {};

    auto stage = [&](int buf, int kt) {
        #pragma unroll
        for (int c = 0; c < 2; c++) {
            int i = w*128 + c*64 + l;
            int row = i >> 2, slot = i & 3;
            int ko = kt + ((slot ^ (row & 3)) << 3);
            gl16(A + (size_t)(bm + row) * Cc + ko, (char*)As[buf] + (w*128 + c*64) * 16);
            gl16(W + (size_t)(bn + row) * Cc + ko, (char*)Ws[buf] + (w*128 + c*64) * 16);
        }
    };
    stage(0, 0);
    for (int kt = 0; kt < Cc; kt += 32) {
        int buf = (kt >> 5) & 1;
        __syncthreads();
        if (kt + 32 < Cc) stage(buf ^ 1, kt + 32);
        bf16x8 af[4], wf[4];
        #pragma unroll
        for (int f = 0; f < 4; f++) {
            int r = wm + f*16 + lr;
            af[f] = *(const bf16x8*)((const char*)As[buf] + r*64 + ((lh ^ (r & 3)) << 4));
            int rn = wn + f*16 + lr;
            wf[f] = *(const bf16x8*)((const char*)Ws[buf] + rn*64 + ((lh ^ (rn & 3)) << 4));
        }
        #pragma unroll
        for (int fm = 0; fm < 4; fm++)
            #pragma unroll
            for (int fn = 0; fn < 4; fn++)
                acc[fm][fn] = __builtin_amdgcn_mfma_f32_16x16x32_bf16(af[fm], wf[fn], acc[fm][fn], 0, 0, 0);
    }

    #pragma unroll
    for (int fm = 0; fm < 4; fm++) {
        #pragma unroll
        for (int r = 0; r < 4; r++) {
            int row = bm + wm + fm*16 + lh*4 + r;
            #pragma unroll
            for (int fn = 0; fn < 4; fn++) {
                int col = bn + wn + fn*16 + lr;
                out[(size_t)row * Cc + col] = f2bf(acc[fm][fn][r] + bias[col]);
            }
        }
    }
}

// ---------------- fused SwiGLU MFMA GEMM, 64x128 tile, dbuf ----------------
__global__ __launch_bounds__(256) void mswiglu64_k(const u16* __restrict__ A,
                                                   const u16* __restrict__ W1,
                                                   const u16* __restrict__ W2,
                                                   u16* __restrict__ out,
                                                   int N, int K) {
    __shared__ u16 As[2][64*32];
    __shared__ u16 W1s[2][128*32];
    __shared__ u16 W2s[2][128*32];
    int bm = blockIdx.y * 64, bn = blockIdx.x * 128;
    int tid = threadIdx.x, w = tid >> 6, l = tid & 63;
    int lr = l & 15, lh = l >> 4;
    int wm = (w >> 1) * 32, wn = (w & 1) * 64;
    f32x4 acc1[2][4] = {};
    f32x4 acc2[2][4] = {};

    auto stage = [&](int buf, int kt) {
        {
            int row = tid >> 2, slot = tid & 3;
            int ko = kt + ((slot ^ (row & 3)) << 3);
            gl16(A + (size_t)(bm + row) * K + ko, (char*)As[buf] + tid * 16);
        }
        #pragma unroll
        for (int c = 0; c < 2; c++) {
            int i = c*256 + tid;
            int row = i >> 2, slot = i & 3;
            int ko = kt + ((slot ^ (row & 3)) << 3);
            gl16(W1 + (size_t)(bn + row) * K + ko, (char*)W1s[buf] + (c*256 + tid) * 16);
            gl16(W2 + (size_t)(bn + row) * K + ko, (char*)W2s[buf] + (c*256 + tid) * 16);
        }
    };
    stage(0, 0);
    for (int kt = 0; kt < K; kt += 32) {
        int buf = (kt >> 5) & 1;
        __syncthreads();
        if (kt + 32 < K) stage(buf ^ 1, kt + 32);
        bf16x8 af[2], w1f[4], w2f[4];
        #pragma unroll
        for (int f = 0; f < 2; f++) {
            int r = wm + f*16 + lr;
            af[f] = *(const bf16x8*)((const char*)As[buf] + r*64 + ((lh ^ (r & 3)) << 4));
        }
        #pragma unroll
        for (int f = 0; f < 4; f++) {
            int rn = wn + f*16 + lr;
            int offn = rn*64 + ((lh ^ (rn & 3)) << 4);
            w1f[f] = *(const bf16x8*)((const char*)W1s[buf] + offn);
            w2f[f] = *(const bf16x8*)((const char*)W2s[buf] + offn);
        }
        #pragma unroll
        for (int fm = 0; fm < 2; fm++)
            #pragma unroll
            for (int fn = 0; fn < 4; fn++) {
                acc1[fm][fn] = __builtin_amdgcn_mfma_f32_16x16x32_bf16(af[fm], w1f[fn], acc1[fm][fn], 0, 0, 0);
                acc2[fm][fn] = __builtin_amdgcn_mfma_f32_16x16x32_bf16(af[fm], w2f[fn], acc2[fm][fn], 0, 0, 0);
            }
    }

    #pragma unroll
    for (int fm = 0; fm < 2; fm++) {
        #pragma unroll
        for (int r = 0; r < 4; r++) {
            int row = bm + wm + fm*16 + lh*4 + r;
            #pragma unroll
            for (int fn = 0; fn < 4; fn++) {
                int col = bn + wn + fn*16 + lr;
                float a = acc1[fm][fn][r];
                float sig = 1.f / (1.f + __expf(-a));
                out[(size_t)row * N + col] = f2bf(a * sig * acc2[fm][fn][r]);
            }
        }
    }
}

// ---------------- V transpose (bf16): vp[B,T,C](head cols) -> vt[B*H, 64, T] ----------------
__global__ __launch_bounds__(256) void vt_k(const u16* __restrict__ vp,
                                            u16* __restrict__ vt) {
    int blk = blockIdx.x;             // bh*32 + kb
    int bh = blk >> 5, kb = blk & 31;
    int b = bh >> 4, h = bh & 15;
    __shared__ u16 t[64][65];
    int tid = threadIdx.x;
    size_t bc = (size_t)b*Tt*Cc + (size_t)h*HDi;
    #pragma unroll
    for (int i = 0; i < 16; i++) {
        int e = tid + i*256;
        int k = e >> 6, d = e & 63;
        t[d][k] = vp[bc + (size_t)(kb*64 + k)*Cc + d];
    }
    __syncthreads();
    #pragma unroll
    for (int i = 0; i < 16; i++) {
        int e = tid + i*256;
        int d = e >> 6, k = e & 63;
        vt[((size_t)bh*64 + d)*Tt + kb*64 + k] = t[d][k];
    }
}

// ---------------- MFMA flash attention: QBLK=128, 8 waves, dbuf, XCD swizzle ----------------
__global__ __launch_bounds__(512) void fattn_k(const u16* __restrict__ qp,
                                               const u16* __restrict__ kp,
                                               const u16* __restrict__ vt,
                                               const float* __restrict__ mr,
                                               u16* __restrict__ ctx) {
    __shared__ u16 Kt[2*4096];      // dbuf [64 k][64 d], swizzled
    __shared__ u16 Vts[2*4096];     // dbuf [64 d][64 k], swizzled
    __shared__ u16 Pt[8][1024];     // per-wave [16 q][64 k], swizzled
    __shared__ float mrw[2176];     // rel-bias window, pre-scaled by 8

    constexpr float C1 = 0.18033688011118324f;   // 0.125 * log2(e)

    // bijective XCD-chunk swizzle: 512 blocks, 8 XCDs -> 64-block chunks share (b,h) panels
    int bid = blockIdx.x;
    int blk = ((bid & 7) << 6) | (bid >> 3);
    int qt = blk & 15, h = (blk >> 4) & 15, b = blk >> 8;
    int q0 = qt * 128;
    int tid = threadIdx.x, w = tid >> 6, l = tid & 63;
    int lr = l & 15, lh = l >> 4;
    size_t bc = (size_t)b * Tt * Cc + (size_t)h * HDi;
    const u16* vtb = vt + (size_t)(b*Hh + h) * HDi * Tt;

    for (int i = tid; i < 2175; i += 512) mrw[i] = mr[q0 + i] * 8.f;

    bf16x8 qa[2];
    {
        const u16* qrow = qp + bc + (size_t)(q0 + w*16 + lr) * Cc;
        qa[0] = *(const bf16x8*)(qrow + lh*8);
        qa[1] = *(const bf16x8*)(qrow + 32 + lh*8);
    }

    f32x4 oacc[4] = {};
    float mrun = -1e30f, lrun = 0.f;

    // ---- loop-invariant address precompute ----
    int ksw = (lr & 7) << 4;
    const char* pK0 = (const char*)Kt  + lr*128 + ((       lh*16) ^ ksw);
    const char* pK1 = (const char*)Kt  + lr*128 + ((64   + lh*16) ^ ksw);
    const char* pV0 = (const char*)Vts + lr*128 + ((       lh*16) ^ ksw);
    const char* pV1 = (const char*)Vts + lr*128 + ((64   + lh*16) ^ ksw);
    char* pw0 = (char*)Pt[w] + lr*128 + ((      lh*8) ^ ksw);
    char* pw1 = (char*)Pt[w] + lr*128 + ((32  + lh*8) ^ ksw);
    char* pw2 = (char*)Pt[w] + lr*128 + ((64  + lh*8) ^ ksw);
    char* pw3 = (char*)Pt[w] + lr*128 + ((96  + lh*8) ^ ksw);
    const char* pr0 = (const char*)Pt[w] + lr*128 + ((     lh*16) ^ ksw);
    const char* pr1 = (const char*)Pt[w] + lr*128 + ((64 + lh*16) ^ ksw);
    // sliding mask pointer: element (ib - f*16 - r) = base[51 - f*16 - r], base -= 64/tile
    const char* pm = (const char*)mrw + (w*16 + lr - lh*4 + 2047 - 51) * 4;

    // ---- staging pointers: 512 threads stage one 64x128B tile per operand ----
    int sl = tid & 7, kr0 = tid >> 3;            // kr0: 0..63
    int so = (sl ^ (kr0 & 7)) << 3;
    const u16* gK = kp + bc + (size_t)kr0 * Cc + so;
    const u16* gV = vtb + (size_t)kr0 * Tt + so;
    int wb = (tid & 448) * 16;                   // w*1024 bytes
    char* dK0 = (char*)Kt  + wb;
    char* dV0 = (char*)Vts + wb;

    auto stage = [&](int bufo) {
        gl16(gK, dK0 + bufo);
        gl16(gV, dV0 + bufo);
        gK += 64*Cc;
        gV += 64;
    };

    auto tile = [&](int bufo) {
        // C-init with 8*mask
        f32x4 s[4];
        #pragma unroll
        for (int f = 0; f < 4; f++) {
            s[f][0] = *(const float*)(pm + (51 - f*16    ) * 4);
            s[f][1] = *(const float*)(pm + (51 - f*16 - 1) * 4);
            s[f][2] = *(const float*)(pm + (51 - f*16 - 2) * 4);
            s[f][3] = *(const float*)(pm + (51 - f*16 - 3) * 4);
        }
        pm -= 256;
        // QK^T swapped: s[f] += D[k][q]
        __builtin_amdgcn_s_setprio(1);
        #pragma unroll
        for (int f = 0; f < 4; f++) {
            bf16x8 kb0 = *(const bf16x8*)(pK0 + bufo + f*2048);
            s[f] = __builtin_amdgcn_mfma_f32_16x16x32_bf16(kb0, qa[0], s[f], 0, 0, 0);
            bf16x8 kb1 = *(const bf16x8*)(pK1 + bufo + f*2048);
            s[f] = __builtin_amdgcn_mfma_f32_16x16x32_bf16(kb1, qa[1], s[f], 0, 0, 0);
        }
        __builtin_amdgcn_s_setprio(0);

        // tile max
        float tm = -1e30f;
        #pragma unroll
        for (int f = 0; f < 4; f++)
            #pragma unroll
            for (int r = 0; r < 4; r++) tm = fmaxf(tm, s[f][r]);
        tm = fmaxf(tm, __shfl_xor(tm, 16));
        tm = fmaxf(tm, __shfl_xor(tm, 32));

        float corr = 1.f;
        bool nod = __all(tm <= mrun + 64.f);
        if (!nod) {
            float mn = fmaxf(mrun, tm);
            corr = vexp2((mrun - mn) * C1);
            mrun = mn;
        }
        float mnc = mrun * C1;
        float ts = 0.f;
        #pragma unroll
        for (int f = 0; f < 4; f++)
            #pragma unroll
            for (int r = 0; r < 4; r++) {
                float e = vexp2(fmaf(s[f][r], C1, -mnc));
                s[f][r] = e; ts += e;
            }
        ts += __shfl_xor(ts, 16);
        ts += __shfl_xor(ts, 32);
        if (nod) {
            lrun += ts;
        } else {
            lrun = lrun*corr + ts;
            float cr0 = __shfl(corr, lh*4 + 0);
            float cr1 = __shfl(corr, lh*4 + 1);
            float cr2 = __shfl(corr, lh*4 + 2);
            float cr3 = __shfl(corr, lh*4 + 3);
            #pragma unroll
            for (int f = 0; f < 4; f++) {
                oacc[f][0] *= cr0; oacc[f][1] *= cr1;
                oacc[f][2] *= cr2; oacc[f][3] *= cr3;
            }
        }

        // packed P write
        { uint2 p2 = { cvtpk(s[0][0], s[0][1]), cvtpk(s[0][2], s[0][3]) }; *(uint2*)pw0 = p2; }
        { uint2 p2 = { cvtpk(s[1][0], s[1][1]), cvtpk(s[1][2], s[1][3]) }; *(uint2*)pw1 = p2; }
        { uint2 p2 = { cvtpk(s[2][0], s[2][1]), cvtpk(s[2][2], s[2][3]) }; *(uint2*)pw2 = p2; }
        { uint2 p2 = { cvtpk(s[3][0], s[3][1]), cvtpk(s[3][2], s[3][3]) }; *(uint2*)pw3 = p2; }

        // PV
        bf16x8 pa0 = *(const bf16x8*)pr0;
        bf16x8 pa1 = *(const bf16x8*)pr1;
        __builtin_amdgcn_s_setprio(1);
        #pragma unroll
        for (int f = 0; f < 4; f++) {
            bf16x8 vb0 = *(const bf16x8*)(pV0 + bufo + f*2048);
            oacc[f] = __builtin_amdgcn_mfma_f32_16x16x32_bf16(pa0, vb0, oacc[f], 0, 0, 0);
            bf16x8 vb1 = *(const bf16x8*)(pV1 + bufo + f*2048);
            oacc[f] = __builtin_amdgcn_mfma_f32_16x16x32_bf16(pa1, vb1, oacc[f], 0, 0, 0);
        }
        __builtin_amdgcn_s_setprio(0);
    };

    stage(0);   // tile 0 -> buf0
    #pragma unroll 1
    for (int kt = 0; kt < 32; kt += 2) {
        __syncthreads();
        stage(8192);             // tile kt+1 -> buf1 (kt+1 <= 31 always)
        tile(0);
        __syncthreads();
        if (kt < 30) stage(0);   // tile kt+2 -> buf0
        tile(8192);
    }

    float li0 = __shfl(lrun, lh*4 + 0);
    float li1 = __shfl(lrun, lh*4 + 1);
    float li2 = __shfl(lrun, lh*4 + 2);
    float li3 = __shfl(lrun, lh*4 + 3);
    float iv[4] = { 1.f/li0, 1.f/li1, 1.f/li2, 1.f/li3 };
    #pragma unroll
    for (int r = 0; r < 4; r++) {
        int row = q0 + w*16 + lh*4 + r;
        #pragma unroll
        for (int f = 0; f < 4; f++)
            ctx[bc + (size_t)row * Cc + f*16 + lr] = f2bf(oacc[f][r] * iv[r]);
    }
}

extern "C" void kernel_launch(void* const* d_in, const int* in_sizes, int n_in,
                              void* d_out, int out_size, void* d_ws, size_t ws_size,
                              hipStream_t stream) {
    const float* query     = (const float*)d_in[0];
    const float* key       = (const float*)d_in[1];
    const float* g_q       = (const float*)d_in[2];
    const float* b_q       = (const float*)d_in[3];
    const float* g_k       = (const float*)d_in[4];
    const float* b_k       = (const float*)d_in[5];
    const float* in_proj_w = (const float*)d_in[6];
    const float* in_proj_b = (const float*)d_in[7];
    const float* out_w     = (const float*)d_in[8];
    const float* out_b     = (const float*)d_in[9];
    const float* proj_w    = (const float*)d_in[10];
    const float* proj_b    = (const float*)d_in[11];
    const float* rel_table = (const float*)d_in[12];
    const float* g_ffn     = (const float*)d_in[13];
    const float* b_ffn     = (const float*)d_in[14];
    const float* w1        = (const float*)d_in[15];
    const float* w2        = (const float*)d_in[16];
    const float* w3        = (const float*)d_in[17];
    const float* g_out     = (const float*)d_in[18];
    const float* b_out     = (const float*)d_in[19];

    char* p = (char*)d_ws;
    auto alloc = [&](size_t bytes) { char* r = p; p += bytes; return r; };
    const size_t MCb = (size_t)Mm * Cc * 2;
    u16* wA  = (u16*)alloc((size_t)3*Cc*Cc*2);
    u16* wPb = (u16*)alloc((size_t)Cc*Cc*2);
    u16* wOt = (u16*)alloc((size_t)Cc*Cc*2);
    u16* wCb = (u16*)alloc((size_t)Cc*Cc*2);
    u16* w1b = (u16*)alloc((size_t)HIDP*Cc*2);
    u16* w2b = (u16*)alloc((size_t)HIDP*Cc*2);
    u16* w3b = (u16*)alloc((size_t)Cc*HIDP*2);
    float* bc = (float*)alloc(Cc*4);
    float* mr = (float*)alloc(4096*4);
    u16* qn = (u16*)alloc(MCb);
    u16* kn = (u16*)alloc(MCb);
    u16* qp = (u16*)alloc(MCb);      // qp,kp,vp contiguous (mqkv out3)
    u16* kp = (u16*)alloc(MCb);
    u16* vp = (u16*)alloc(MCb);
    u16* vt = (u16*)alloc(MCb);
    float* x  = (float*)alloc((size_t)Mm*Cc*4);
    float* x2 = (float*)alloc((size_t)Mm*Cc*4);
    u16* ctx = qn;   // aliases (lifetimes disjoint)
    u16* h   = qp;
    u16* gf  = vp;   // [4096][1408] bf16 spans vp+part of vt

    dim3 blk(256);
    // ---- per-launch weight prep ----
    {
        int n0 = 3*Cc*Cc/8;           // 393216
        int n1 = Cc*Cc/8;             // 131072
        int n2 = HIDP*Cc/8;           // 180224 (valid = HID*Cc)
        int n3 = HIDP*Cc/8;
        int nblk = (n0 + n1 + n2 + n3) / 256;
        cvt4_k<<<nblk, blk, 0, stream>>>(in_proj_w, wA, n0,
                                         proj_w, wPb, n1,
                                         w1, w1b, n2, HID*Cc,
                                         w2, w2b, n3, HID*Cc);
    }
    cvt_k<<<(Cc*HIDP/8 + 255)/256, blk, 0, stream>>>(w3, w3b, Cc, HID, HIDP, Cc*HIDP/8);
    cvtT_k<<<dim3(16,16), blk, 0, stream>>>(out_w, wOt);
    mgemm64_k<1,0,0><<<dim3(Cc/128, Cc/64), blk, 0, stream>>>(wPb, wOt, nullptr, nullptr, wCb, Cc, Cc);
    bias_k<<<Cc, blk, 0, stream>>>(proj_w, out_b, proj_b, bc);
    meanrel_k<<<16, blk, 0, stream>>>(rel_table, mr);

    // ---- main chain ----
    ln2_k<<<2*Mm, blk, 0, stream>>>(query, key, g_q, b_q, g_k, b_k, qn, kn);

    dim3 gqkv(Cc/128, Mm/128, 3);
    mqkv_k<<<gqkv, blk, 0, stream>>>(qn, kn, wA, in_proj_b, qp);

    vt_k<<<Bb*Hh*32, blk, 0, stream>>>(vp, vt);
    fattn_k<<<Bb*Hh*16, dim3(512), 0, stream>>>(qp, kp, vt, mr, ctx);

    dim3 g1(Cc/128, Mm/64);
    mgemm64_k<0,1,1><<<g1, blk, 0, stream>>>(ctx, wCb, bc, query, x, Cc, Cc);

    ln_k<1><<<Mm, blk, 0, stream>>>(x, g_ffn, b_ffn, h);
    dim3 g2(HIDP/128, Mm/64);
    mswiglu64_k<<<g2, blk, 0, stream>>>(h, w1b, w2b, gf, HIDP, Cc);
    dim3 g3(Cc/128, Mm/64);
    mgemm64_k<0,1,0><<<g3, blk, 0, stream>>>(gf, w3b, nullptr, x, x2, Cc, HIDP);

    ln_k<0><<<Mm, blk, 0, stream>>>(x2, g_out, b_out, d_out);
}